// Round 3
// baseline (327.355 us; speedup 1.0000x reference)
//
#include <hip/hip_runtime.h>
#include <math.h>

// TreeMambaLayer: B=4, N=2048, D_MODEL=768, D_INNER=1536, DT_RANK=48
// Round 12: gemm256 -> full 2-tile-ahead staging (A+B of t+2 staged in
// ph2/ph3 into current buf after last read; vmcnt(8) at tile end waits only
// on loads issued a full tile earlier). Drop sched_barrier(0) pinning.

#define ROWS 8192
#define DIN 1536
#define DMOD 768
#define NSEQ 2048
#define DTR 48
#define NSPLIT 8

typedef __bf16 bfrag __attribute__((ext_vector_type(8)));
typedef float f4 __attribute__((ext_vector_type(4)));

__device__ __forceinline__ unsigned short f2bf(float f) {
  unsigned int u = __float_as_uint(f);
  unsigned int r = (u + 0x7fffu + ((u >> 16) & 1u)) >> 16;
  return (unsigned short)r;
}
__device__ __forceinline__ float bf2f(unsigned short h) {
  return __uint_as_float(((unsigned int)h) << 16);
}

__device__ __forceinline__ void gld_lds16(const void* g, void* l) {
  __builtin_amdgcn_global_load_lds((const __attribute__((address_space(1))) void*)g,
                                   (__attribute__((address_space(3))) void*)l, 16, 0, 0);
}

// raw barrier: no vmcnt drain; compiler-level memory fence only (no
// sched_barrier order-pinning -- m141: that defeats the scheduler).
__device__ __forceinline__ void barx() {
  asm volatile("" ::: "memory");
  __builtin_amdgcn_s_barrier();
  asm volatile("" ::: "memory");
}

// ---------------- 256x256 8-phase bf16 GEMM, C = A(MxK) * Bt(NxK)^T
// cols < DIN -> XI bf16; cols >= DIN -> Z = silu, bf16.
// 8 waves (2M x 4N), per-wave 128x64 out. BK=64, LDS 128KB dbuf.
// Staging: quarters of 64 rows (8KB = 512 thr x 16B), linear LDS dest,
// source pre-swizzled chunk = (c ^ (row&7)); reads XOR the same way.
// Deep pipeline: during tile t, ph2/ph3 stage tile t+2 (A and B) into the
// CURRENT buffer b, each quarter strictly after its last ds_read:
//   A-Q0,Q2 last read ph0 -> staged ph2;  B (all Q) last read ph1 ->
//   B-Q0,Q1 staged ph2, B-Q2,Q3 staged ph3;  A-Q1,Q3 last read ph2 ->
//   staged ph3.  vmcnt(8) at tile end waits only on tile t+1's 8 loads
//   (issued one full tile earlier) while t+2's 8 stay in flight.
__global__ __launch_bounds__(512, 1) void gemm256_silu(
    const unsigned short* __restrict__ A, const unsigned short* __restrict__ Bt,
    unsigned short* __restrict__ XI, unsigned short* __restrict__ Z, int K) {
  __shared__ unsigned short lds[2][2][256 * 64];  // [buf][A/B][row*64+col] 128KB
  const int tid = threadIdx.x;
  const int w = tid >> 6, l = tid & 63;
  const int quad = l >> 4, l16 = l & 15;
  const int wr = w >> 2, wc = w & 3;
  const int row0 = blockIdx.y * 256, col0 = blockIdx.x * 256;
  const int nt = K >> 6;

  // staging source: thread t covers LDS bytes [t*16,+16) of an 8KB quarter:
  // row_local = t>>3, chunk c = t&7; content swizzle c ^= row&7.
  const int srow = tid >> 3;
  const int schunk = ((tid & 7) ^ (srow & 7)) * 8;
  const unsigned short* aS = A + (size_t)(row0 + srow) * K + schunk;
  const unsigned short* bS = Bt + (size_t)(col0 + srow) * K + schunk;

#define STG(bufi, isb, q, kt)                                               \
  gld_lds16(((isb) ? bS : aS) + (size_t)((q) * 64) * K + (size_t)(kt) * 64, \
            (char*)&lds[bufi][isb][(q) * 4096] + w * 1024)

  // fragment read bases (swizzled chunk per k-slice)
  const int arow = (wr * 128 + l16) * 64;
  const int brow = (wc * 64 + l16) * 64;
  int cs[2];
  cs[0] = (quad ^ (l16 & 7)) * 8;
  cs[1] = ((4 + quad) ^ (l16 & 7)) * 8;

#define RDA(m, ks) (*(const bfrag*)(const void*)(LA + arow + (m) * 1024 + cs[ks]))
#define RDB(n, ks) (*(const bfrag*)(const void*)(LB + brow + (n) * 1024 + cs[ks]))

  f4 acc[8][4];
#pragma unroll
  for (int m = 0; m < 8; m++)
#pragma unroll
    for (int n = 0; n < 4; n++) acc[m][n] = (f4){0.f, 0.f, 0.f, 0.f};

  // prologue: stage t0 (A,B) and t1 (A,B); wait until t0's 8 landed.
  const int kt1 = (nt > 1) ? 1 : 0;
#pragma unroll
  for (int q = 0; q < 4; q++) STG(0, 0, q, 0);
#pragma unroll
  for (int q = 0; q < 4; q++) STG(0, 1, q, 0);
#pragma unroll
  for (int q = 0; q < 4; q++) STG(1, 0, q, kt1);
#pragma unroll
  for (int q = 0; q < 4; q++) STG(1, 1, q, kt1);
  asm volatile("s_waitcnt vmcnt(8)" ::: "memory");
  barx();

  for (int t = 0; t < nt; ++t) {
    const int b = t & 1;
    const unsigned short* LA = &lds[b][0][0];
    const unsigned short* LB = &lds[b][1][0];
    const int kA = (t + 2 < nt) ? (t + 2) : (nt - 1);  // tile t+2 -> buf b
    bfrag af[4][2], bfr[4][2];

    // ---- ph0: read A m0-3 + B n0-1; MFMA (m-lo, n-lo)
#pragma unroll
    for (int m = 0; m < 4; m++) {
      af[m][0] = RDA(m, 0);
      af[m][1] = RDA(m, 1);
    }
#pragma unroll
    for (int n = 0; n < 2; n++) {
      bfr[n][0] = RDB(n, 0);
      bfr[n][1] = RDB(n, 1);
    }
    barx();
    __builtin_amdgcn_s_setprio(1);
#pragma unroll
    for (int m = 0; m < 4; m++)
#pragma unroll
      for (int n = 0; n < 2; n++) {
        acc[m][n] = __builtin_amdgcn_mfma_f32_16x16x32_bf16(af[m][0], bfr[n][0], acc[m][n], 0, 0, 0);
        acc[m][n] = __builtin_amdgcn_mfma_f32_16x16x32_bf16(af[m][1], bfr[n][1], acc[m][n], 0, 0, 0);
      }
    __builtin_amdgcn_s_setprio(0);
    barx();

    // ---- ph1: read B n2-3; MFMA (m-lo, n-hi)
#pragma unroll
    for (int n = 2; n < 4; n++) {
      bfr[n][0] = RDB(n, 0);
      bfr[n][1] = RDB(n, 1);
    }
    barx();
    __builtin_amdgcn_s_setprio(1);
#pragma unroll
    for (int m = 0; m < 4; m++)
#pragma unroll
      for (int n = 2; n < 4; n++) {
        acc[m][n] = __builtin_amdgcn_mfma_f32_16x16x32_bf16(af[m][0], bfr[n][0], acc[m][n], 0, 0, 0);
        acc[m][n] = __builtin_amdgcn_mfma_f32_16x16x32_bf16(af[m][1], bfr[n][1], acc[m][n], 0, 0, 0);
      }
    __builtin_amdgcn_s_setprio(0);
    barx();

    // ---- ph2: stage t+2 A-Q0,Q2 + B-Q0,Q1; read A m4-7; MFMA (m-hi, n-lo)
    STG(b, 0, 0, kA);
    STG(b, 0, 2, kA);
    STG(b, 1, 0, kA);
    STG(b, 1, 1, kA);
#pragma unroll
    for (int m = 0; m < 4; m++) {
      af[m][0] = RDA(m + 4, 0);
      af[m][1] = RDA(m + 4, 1);
    }
    barx();
    __builtin_amdgcn_s_setprio(1);
#pragma unroll
    for (int m = 0; m < 4; m++)
#pragma unroll
      for (int n = 0; n < 2; n++) {
        acc[m + 4][n] = __builtin_amdgcn_mfma_f32_16x16x32_bf16(af[m][0], bfr[n][0], acc[m + 4][n], 0, 0, 0);
        acc[m + 4][n] = __builtin_amdgcn_mfma_f32_16x16x32_bf16(af[m][1], bfr[n][1], acc[m + 4][n], 0, 0, 0);
      }
    __builtin_amdgcn_s_setprio(0);
    barx();

    // ---- ph3: stage t+2 A-Q1,Q3 + B-Q2,Q3; MFMA (m-hi, n-hi); vmcnt(8)
    STG(b, 0, 1, kA);
    STG(b, 0, 3, kA);
    STG(b, 1, 2, kA);
    STG(b, 1, 3, kA);
    barx();
    __builtin_amdgcn_s_setprio(1);
#pragma unroll
    for (int m = 0; m < 4; m++)
#pragma unroll
      for (int n = 2; n < 4; n++) {
        acc[m + 4][n] = __builtin_amdgcn_mfma_f32_16x16x32_bf16(af[m][0], bfr[n][0], acc[m + 4][n], 0, 0, 0);
        acc[m + 4][n] = __builtin_amdgcn_mfma_f32_16x16x32_bf16(af[m][1], bfr[n][1], acc[m + 4][n], 0, 0, 0);
      }
    __builtin_amdgcn_s_setprio(0);
    // tile t+1's 8 loads (issued one full tile ago) must be landed;
    // t+2's 8 (issued this tile) stay in flight.
    asm volatile("s_waitcnt vmcnt(8)" ::: "memory");
    barx();
  }
  asm volatile("s_waitcnt vmcnt(0)" ::: "memory");

#undef STG
#undef RDA
#undef RDB

  // epilogue: 256-wide col tiles are entirely XI or entirely Z (1536%256==0)
  const bool is_z = (col0 >= DIN);
  unsigned short* dst = is_z ? Z : XI;
  const int cb = col0 + wc * 64 + l16 - (is_z ? DIN : 0);
#pragma unroll
  for (int m = 0; m < 8; m++) {
    const int rb = row0 + wr * 128 + m * 16 + quad * 4;
#pragma unroll
    for (int n = 0; n < 4; n++)
#pragma unroll
      for (int r = 0; r < 4; r++) {
        float v = acc[m][n][r];
        if (is_z) v = v / (1.f + __expf(-v));
        dst[(size_t)(rb + r) * DIN + cb + n * 16] = f2bf(v);
      }
  }
}

// ------------------------------------------------------------- bf16 MFMA GEMM
// BK=32, 128x128 tile, swizzled LDS. MODE 0: fp32 C.
template <int MODE>
__global__ __launch_bounds__(256) void mfma_gemm(
    const unsigned short* __restrict__ A, const unsigned short* __restrict__ Bt,
    void* __restrict__ C0v, void* __restrict__ C1v, int K, int ldc) {
  __shared__ unsigned short As[128 * 32];
  __shared__ unsigned short Bs[128 * 32];
  const int tid = threadIdx.x;
  const int w = tid >> 6, l = tid & 63;
  const int quad = l >> 4, l16 = l & 15;
  const int wrow = (w >> 1) * 64, wcol = (w & 1) * 64;
  const int row0 = blockIdx.y * 128, col0 = blockIdx.x * 128;

  f4 acc[4][4];
#pragma unroll
  for (int i = 0; i < 4; i++)
#pragma unroll
    for (int j = 0; j < 4; j++) acc[i][j] = (f4){0.f, 0.f, 0.f, 0.f};

  const int arow = row0 + w * 16 + (l >> 2);
  const int brow = col0 + w * 16 + (l >> 2);
  const int kcol = (((l & 3) ^ ((l >> 2) & 3)) * 8);  // swizzled chunk
  const int qs = (quad ^ (l16 & 3)) * 8;              // fragment chunk

  for (int k0 = 0; k0 < K; k0 += 32) {
#pragma unroll
    for (int r = 0; r < 2; r++) {
      gld_lds16(A + (size_t)(arow + r * 64) * K + k0 + kcol,
                (char*)As + r * 4096 + w * 1024);
      gld_lds16(Bt + (size_t)(brow + r * 64) * K + k0 + kcol,
                (char*)Bs + r * 4096 + w * 1024);
    }
    __syncthreads();
    bfrag af[4], bf[4];
#pragma unroll
    for (int i = 0; i < 4; i++)
      af[i] = *(const bfrag*)(const void*)(As + (wrow + i * 16 + l16) * 32 + qs);
#pragma unroll
    for (int j = 0; j < 4; j++)
      bf[j] = *(const bfrag*)(const void*)(Bs + (wcol + j * 16 + l16) * 32 + qs);
#pragma unroll
    for (int i = 0; i < 4; i++)
#pragma unroll
      for (int j = 0; j < 4; j++)
        acc[i][j] = __builtin_amdgcn_mfma_f32_16x16x32_bf16(af[i], bf[j], acc[i][j], 0, 0, 0);
    __syncthreads();
  }

  if (MODE == 0) {
    float* C0 = (float*)C0v;
    const int ccol = col0 + wcol + l16;
#pragma unroll
    for (int i = 0; i < 4; i++) {
      const int rb = row0 + wrow + i * 16 + quad * 4;
#pragma unroll
      for (int j = 0; j < 4; j++)
#pragma unroll
        for (int r = 0; r < 4; r++)
          C0[(size_t)(rb + r) * ldc + ccol + j * 16] = acc[i][j][r];
    }
  } else {
    const bool is_z = (col0 >= DIN);
    unsigned short* dst = is_z ? (unsigned short*)C1v : (unsigned short*)C0v;
    const int cbase = col0 + wcol + l16 - (is_z ? DIN : 0);
#pragma unroll
    for (int i = 0; i < 4; i++) {
      const int rb = row0 + wrow + i * 16 + quad * 4;
#pragma unroll
      for (int j = 0; j < 4; j++)
#pragma unroll
        for (int r = 0; r < 4; r++) {
          float v = acc[i][j][r];
          if (is_z) v = v / (1.f + __expf(-v));
          dst[(size_t)(rb + r) * DIN + cbase + j * 16] = f2bf(v);
        }
    }
  }
}

// ------------------- prep1 (1024 thr): sched (block 0) + all flat casts
// SLOT_PACK[slot] = node | ((pnode+1)<<12); SLOTINV[node] = slot.
__global__ __launch_bounds__(1024) void prep1_kernel(
    const int* __restrict__ sidx, const int* __restrict__ spar,
    int* __restrict__ SLOT_PACK, int* __restrict__ SLOTINV,
    int* __restrict__ LSTART, int* __restrict__ NLEV,
    const float* __restrict__ x, unsigned short* __restrict__ Xbf,
    const float* __restrict__ xpw, unsigned short* __restrict__ XPW,
    const float* __restrict__ dtw, unsigned short* __restrict__ DTWb,
    const float* __restrict__ A_log, float* __restrict__ negA) {
  const int bi = blockIdx.x;
  const int tid = threadIdx.x;
  if (bi == 0) {
    __shared__ int par[2048], idx[2048], ancA[2048], ancB[2048], rnkA[2048], rnkB[2048];
    __shared__ int dmax;
    for (int i = tid; i < 2048; i += 1024) {
      const int p = spar[i];
      par[i] = p;
      idx[i] = sidx[i];
      ancA[i] = (p < 0) ? -1 : p;
      rnkA[i] = (p < 0) ? 0 : 1;
    }
    if (tid == 0) dmax = 0;
    __syncthreads();
    for (int r = 0; r < 11; r++) {
      int* ca = (r & 1) ? ancB : ancA;
      int* cr = (r & 1) ? rnkB : rnkA;
      int* na = (r & 1) ? ancA : ancB;
      int* nr = (r & 1) ? rnkA : rnkB;
      for (int i = tid; i < 2048; i += 1024) {
        const int a = ca[i], rv = cr[i];
        if (a >= 0) {
          nr[i] = rv + cr[a];
          na[i] = ca[a];
        } else {
          nr[i] = rv;
          na[i] = a;
        }
      }
      __syncthreads();
    }
    for (int i = tid; i < 2048; i += 1024) ancA[i] = 0;
    __syncthreads();
    for (int i = tid; i < 2048; i += 1024) {
      atomicAdd(&ancA[rnkB[i]], 1);
      atomicMax(&dmax, rnkB[i]);
    }
    __syncthreads();
    for (int s = 0; s < 11; s++) {
      const int off = 1 << s;
      int* cur = (s & 1) ? ancB : ancA;
      int* nxt = (s & 1) ? ancA : ancB;
      for (int i = tid; i < 2048; i += 1024) {
        int v = cur[i];
        if (i >= off) v += cur[i - off];
        nxt[i] = v;
      }
      __syncthreads();
    }
    for (int i = tid; i < 2049; i += 1024) {
      const int v = (i == 0) ? 0 : ancB[i - 1];
      LSTART[i] = v;
      if (i < 2048) rnkA[i] = v;
    }
    if (tid == 0) NLEV[0] = dmax + 1;
    __syncthreads();
    for (int i = tid; i < 2048; i += 1024) {
      const int d = rnkB[i];
      const int slot = atomicAdd(&rnkA[d], 1);
      const int node = idx[i];
      const int p = par[i];
      const int pn = (p < 0) ? -1 : idx[p];
      SLOT_PACK[slot] = node | ((pn + 1) << 12);
      SLOTINV[node] = slot;
    }
  } else if (bi < 1 + 1536) {
    const int i = ((bi - 1) * 1024 + tid) * 4;
    const float4 v = *(const float4*)(x + i);
    union { unsigned short h[4]; uint2 u; } pk;
    pk.h[0] = f2bf(v.x);
    pk.h[1] = f2bf(v.y);
    pk.h[2] = f2bf(v.z);
    pk.h[3] = f2bf(v.w);
    *(uint2*)(Xbf + i) = pk.u;
  } else if (bi < 1 + 1536 + 96) {
    const int i = (bi - 1537) * 1024 + tid;  // 64*1536
    const int c = i / 1536, k = i % 1536;
    XPW[i] = (c < 50) ? f2bf(xpw[(size_t)k * 50 + c]) : (unsigned short)0;
  } else if (bi < 1 + 1536 + 96 + 96) {
    const int i = (bi - 1633) * 1024 + tid;  // 1536*64
    const int d = i >> 6, k = i & 63;
    DTWb[i] = (k < 48) ? f2bf(dtw[(size_t)k * DIN + d]) : (unsigned short)0;
  } else {
    const int i = (bi - 1729) * 1024 + tid;
    if (i < DIN) negA[i] = -__expf(A_log[i]);
  }
}

// ------------------- prep2 (256 thr): both weight transposes, fp32 -> bf16^T
__global__ __launch_bounds__(256) void prep2_kernel(
    const float* __restrict__ W1, unsigned short* __restrict__ W1t,
    const float* __restrict__ W2, unsigned short* __restrict__ W2t) {
  __shared__ float t[32][33];
  int idx = blockIdx.x;
  const float* W;
  unsigned short* Wt;
  int K, N, n0, k0;
  if (idx < 2304) {  // in_proj: K=768, N=3072 -> 96x24 tiles
    W = W1; Wt = W1t; K = DMOD; N = 2 * DIN;
    n0 = (idx % 96) * 32; k0 = (idx / 96) * 32;
  } else {           // out_proj: K=1536, N=768 -> 24x48 tiles
    idx -= 2304;
    W = W2; Wt = W2t; K = DIN; N = DMOD;
    n0 = (idx % 24) * 32; k0 = (idx / 24) * 32;
  }
  const int tx = threadIdx.x & 31, ty = threadIdx.x >> 5;
  for (int i = ty; i < 32; i += 8) t[i][tx] = W[(size_t)(k0 + i) * N + n0 + tx];
  __syncthreads();
  for (int i = ty; i < 32; i += 8)
    Wt[(size_t)(n0 + i) * K + k0 + tx] = f2bf(t[tx][i]);
}

// ------------------------------------------------- x_dbl: split-K bf16 MFMA
__global__ __launch_bounds__(256) void xdbl_mfma(
    const unsigned short* __restrict__ XI, const unsigned short* __restrict__ XPW,
    float* __restrict__ XP) {
  __shared__ unsigned short As[128 * 32];
  __shared__ unsigned short Bs[64 * 32];
  const int tid = threadIdx.x;
  const int w = tid >> 6, l = tid & 63;
  const int quad = l >> 4, l16 = l & 15;
  const int split = blockIdx.x;
  const int row0 = blockIdx.y * 128;
  const int kbase = split * (DIN / NSPLIT);  // 192

  f4 acc[2][4];
#pragma unroll
  for (int i = 0; i < 2; i++)
#pragma unroll
    for (int j = 0; j < 4; j++) acc[i][j] = (f4){0.f, 0.f, 0.f, 0.f};

  const int srow = w * 16 + (l >> 2);
  const int kcol = (((l & 3) ^ ((l >> 2) & 3)) * 8);
  const int qs = (quad ^ (l16 & 3)) * 8;

  for (int c = 0; c < 6; c++) {
    const int k0 = kbase + c * 32;
#pragma unroll
    for (int r = 0; r < 2; r++) {
      gld_lds16(XI + (size_t)(row0 + srow + r * 64) * DIN + k0 + kcol,
                (char*)As + r * 4096 + w * 1024);
    }
    gld_lds16(XPW + (size_t)srow * DIN + k0 + kcol, (char*)Bs + w * 1024);
    __syncthreads();
    bfrag af[2], bf[4];
#pragma unroll
    for (int i = 0; i < 2; i++)
      af[i] = *(const bfrag*)(const void*)(As + (w * 32 + i * 16 + l16) * 32 + qs);
#pragma unroll
    for (int j = 0; j < 4; j++)
      bf[j] = *(const bfrag*)(const void*)(Bs + (j * 16 + l16) * 32 + qs);
#pragma unroll
    for (int i = 0; i < 2; i++)
#pragma unroll
      for (int j = 0; j < 4; j++)
        acc[i][j] = __builtin_amdgcn_mfma_f32_16x16x32_bf16(af[i], bf[j], acc[i][j], 0, 0, 0);
    __syncthreads();
  }

  float* dst = XP + (size_t)split * ROWS * 64 + (size_t)row0 * 64;
#pragma unroll
  for (int i = 0; i < 2; i++) {
    const int rb = w * 32 + i * 16 + quad * 4;
#pragma unroll
    for (int j = 0; j < 4; j++) {
      const int col = j * 16 + l16;
#pragma unroll
      for (int r = 0; r < 4; r++) dst[(size_t)(rb + r) * 64 + col] = acc[i][j][r];
    }
  }
}

// -------------------------- reduce XP partials -> DTLRb bf16 + BC/CC fp32
__global__ __launch_bounds__(256) void xp_reduce(
    const float* __restrict__ XP, unsigned short* __restrict__ DTLRb,
    float* __restrict__ BCv, float* __restrict__ CCv) {
  const int i = blockIdx.x * 256 + threadIdx.x;  // 8192*16
  const int row = i >> 4, c4 = (i & 15) * 4;
  const float* p = XP + (size_t)row * 64 + c4;
  float4 s = make_float4(0.f, 0.f, 0.f, 0.f);
#pragma unroll
  for (int sp = 0; sp < NSPLIT; sp++) {
    const float4 v = *(const float4*)(p + (size_t)sp * ROWS * 64);
    s.x += v.x;
    s.y += v.y;
    s.z += v.z;
    s.w += v.w;
  }
  if (c4 == 48) {
    BCv[row] = s.x;
    CCv[row] = s.y;
  }
  union { unsigned short h[4]; uint2 u; } pk;
  pk.h[0] = f2bf(s.x);
  pk.h[1] = f2bf(s.y);
  pk.h[2] = f2bf(s.z);
  pk.h[3] = f2bf(s.w);
  *(uint2*)(DTLRb + (size_t)row * 64 + c4) = pk.u;
}

// ------- dt GEMM (K=64) -> dA/dBx bf16, rows permuted to slot order.
// grid (12, 128). 64 rows x 128 cols per block.
__global__ __launch_bounds__(256) void dt_gemm(
    const unsigned short* __restrict__ DTLRb, const unsigned short* __restrict__ DTWb,
    const float* __restrict__ bias, const float* __restrict__ negA,
    const float* __restrict__ BCv, const unsigned short* __restrict__ XI,
    const int* __restrict__ SLOTINV,
    unsigned short* __restrict__ DAp, unsigned short* __restrict__ DBXp) {
  __shared__ unsigned short As[2][64 * 32];
  __shared__ unsigned short Bs[2][128 * 32];
  __shared__ int sinv[64];
  __shared__ float bcs[64];
  const int tid = threadIdx.x;
  const int w = tid >> 6, l = tid & 63;
  const int quad = l >> 4, l16 = l & 15;
  const int wrow = (w >> 1) * 32, wcol = (w & 1) * 64;
  const int row0 = blockIdx.y * 64, col0 = blockIdx.x * 128;
  const int p0 = row0 & (NSEQ - 1);       // position base (batch-local)
  const int bbase = row0 & ~(NSEQ - 1);   // b*2048
  const int srow = w * 16 + (l >> 2);
  const int koff = (((l & 3) ^ ((l >> 2) & 3)) * 8);
  const int qs = (quad ^ (l16 & 3)) * 8;

#pragma unroll
  for (int c = 0; c < 2; c++) {
    gld_lds16(DTLRb + (size_t)(row0 + srow) * 64 + c * 32 + koff,
              (char*)As[c] + w * 1024);
#pragma unroll
    for (int r = 0; r < 2; r++)
      gld_lds16(DTWb + (size_t)(col0 + srow + r * 64) * 64 + c * 32 + koff,
                (char*)Bs[c] + r * 4096 + w * 1024);
  }
  if (tid < 64) {
    sinv[tid] = SLOTINV[p0 + tid];
    bcs[tid] = BCv[row0 + tid];
  }
  __syncthreads();

  f4 acc[2][4];
#pragma unroll
  for (int i = 0; i < 2; i++)
#pragma unroll
    for (int j = 0; j < 4; j++) acc[i][j] = (f4){0.f, 0.f, 0.f, 0.f};

#pragma unroll
  for (int c = 0; c < 2; c++) {
    bfrag af[2], bf[4];
#pragma unroll
    for (int i = 0; i < 2; i++)
      af[i] = *(const bfrag*)(const void*)(As[c] + (wrow + i * 16 + l16) * 32 + qs);
#pragma unroll
    for (int j = 0; j < 4; j++)
      bf[j] = *(const bfrag*)(const void*)(Bs[c] + (wcol + j * 16 + l16) * 32 + qs);
#pragma unroll
    for (int i = 0; i < 2; i++)
#pragma unroll
      for (int j = 0; j < 4; j++)
        acc[i][j] = __builtin_amdgcn_mfma_f32_16x16x32_bf16(af[i], bf[j], acc[i][j], 0, 0, 0);
  }

  float bj[4], aj[4];
#pragma unroll
  for (int j = 0; j < 4; j++) {
    const int d = col0 + wcol + j * 16 + l16;
    bj[j] = bias[d];
    aj[j] = negA[d];
  }
#pragma unroll
  for (int i = 0; i < 2; i++) {
#pragma unroll
    for (int r = 0; r < 4; r++) {
      const int row_l = wrow + i * 16 + quad * 4 + r;
      const int row = row0 + row_l;
      const float bc = bcs[row_l];
      const size_t rp = (size_t)(bbase + sinv[row_l]) * DIN;
#pragma unroll
      for (int j = 0; j < 4; j++) {
        const int d = col0 + wcol + j * 16 + l16;
        const float s = acc[i][j][r] + bj[j];
        const float sp = fmaxf(s, 0.f) + __logf(1.f + __expf(-fabsf(s)));
        const float xi = bf2f(XI[(size_t)row * DIN + d]);
        DAp[rp + d] = f2bf(__expf(sp * aj[j]));
        DBXp[rp + d] = f2bf(sp * bc * xi);
      }
    }
  }
}

// ----------------- tree recurrence: h resident in LDS, slot-ordered loads
// block owns 16 bf16 columns (2 chunks of 8); h[node][16] in LDS (64KB).
__global__ __launch_bounds__(256) void recur_kernel(
    const unsigned short* __restrict__ DAp, const unsigned short* __restrict__ DBXp,
    unsigned short* __restrict__ Hb,
    const int* __restrict__ SLOT_PACK, const int* __restrict__ LSTART,
    const int* __restrict__ NLEV) {
  __shared__ unsigned short hl[NSEQ * 16];  // 64 KB
  __shared__ int spack[NSEQ];               // 8 KB
  __shared__ int lst[258];                  // ~1 KB
  const int tid = threadIdx.x;
  const int c8a = blockIdx.x * 2;           // both chunks in same batch
  const int b = c8a / 192;
  const int d8a = c8a % 192;
  const int nlev = NLEV[0];
  for (int i = tid; i < NSEQ; i += 256) spack[i] = SLOT_PACK[i];
  const int nl = (nlev + 1 < 258) ? nlev + 1 : 258;
  for (int i = tid; i < nl; i += 256) lst[i] = LSTART[i];
  __syncthreads();

  for (int L = 0; L < nlev; L++) {
    const int s0 = (L < 257) ? lst[L] : LSTART[L];
    const int s1 = (L + 1 < 258) ? lst[L + 1] : LSTART[L + 1];
    const int items = (s1 - s0) * 2;
    for (int it = tid; it < items; it += 256) {
      const int s = s0 + (it >> 1);
      const int ch = it & 1;
      const size_t goff = (size_t)(b * NSEQ + s) * DIN + (d8a + ch) * 8;
      union { uint4 u; unsigned short h[8]; } da, dbx, hpu, hvu;
      da.u = *(const uint4*)(DAp + goff);
      dbx.u = *(const uint4*)(DBXp + goff);
      const int pk = spack[s];
      const int node = pk & 4095;
      const int pn = (pk >> 12) - 1;
      float hp[8];
      if (pn >= 0) {
        hpu.u = *(const uint4*)(hl + pn * 16 + ch * 8);
#pragma unroll
        for (int e = 0; e < 8; e++) hp[e] = bf2f(hpu.h[e]);
      } else {
#pragma unroll
        for (int e = 0; e < 8; e++) hp[e] = 0.f;
      }
#pragma unroll
      for (int e = 0; e < 8; e++) {
        const float hv = fmaf(bf2f(da.h[e]), hp[e], bf2f(dbx.h[e]));
        hvu.h[e] = f2bf(hv);
      }
      *(uint4*)(hl + node * 16 + ch * 8) = hvu.u;
    }
    __syncthreads();
  }

  // flush h to global (node-major for ln)
  for (int i = tid; i < NSEQ * 2; i += 256) {
    const int node = i >> 1, ch = i & 1;
    *(uint4*)(Hb + (size_t)(b * NSEQ + node) * DIN + (d8a + ch) * 8) =
        *(const uint4*)(hl + node * 16 + ch * 8);
  }
}

// --------------------------------------------- y, layernorm, z-gate -> bf16
__global__ __launch_bounds__(256) void ln_kernel(
    const unsigned short* __restrict__ Hb, const float* __restrict__ CCv,
    const unsigned short* __restrict__ XI, const float* __restrict__ Dp,
    const float* __restrict__ gamma, const float* __restrict__ beta,
    const unsigned short* __restrict__ Z, unsigned short* __restrict__ YLN) {
  const int row = blockIdx.x;
  const int tid = threadIdx.x;
  const float C = CCv[row];
  const unsigned short* hrow = Hb + (size_t)row * DIN;
  const unsigned short* xrow = XI + (size_t)row * DIN;
  float y[6];
  float s = 0.f, s2 = 0.f;
#pragma unroll
  for (int i = 0; i < 6; i++) {
    const int d = tid + i * 256;
    const float v = fmaf(bf2f(hrow[d]), C, Dp[d] * bf2f(xrow[d]));
    y[i] = v;
    s += v;
    s2 = fmaf(v, v, s2);
  }
#pragma unroll
  for (int off = 32; off >= 1; off >>= 1) {
    s += __shfl_down(s, off);
    s2 += __shfl_down(s2, off);
  }
  __shared__ float rs[4], rs2[4];
  const int w = tid >> 6;
  if ((tid & 63) == 0) {
    rs[w] = s;
    rs2[w] = s2;
  }
  __syncthreads();
  const float ts = rs[0] + rs[1] + rs[2] + rs[3];
  const float ts2 = rs2[0] + rs2[1] + rs2[2] + rs2[3];
  const float mu = ts * (1.f / 1536.f);
  const float var = ts2 * (1.f / 1536.f) - mu * mu;
  const float inv = rsqrtf(var + 1e-5f);
  unsigned short* yrow = YLN + (size_t)row * DIN;
  const unsigned short* zrow = Z + (size_t)row * DIN;
#pragma unroll
  for (int i = 0; i < 6; i++) {
    const int d = tid + i * 256;
    const float o = (y[i] - mu) * inv * gamma[d] + beta[d];
    yrow[d] = f2bf(o * bf2f(zrow[d]));
  }
}

// ---------------------------------------------------------------------- launch
extern "C" void kernel_launch(void* const* d_in, const int* in_sizes, int n_in,
                              void* d_out, int out_size, void* d_ws, size_t ws_size,
                              hipStream_t stream) {
  const float* x = (const float*)d_in[0];
  const int* sidx = (const int*)d_in[1];
  const int* spar = (const int*)d_in[2];
  const float* in_proj = (const float*)d_in[3];
  const float* x_proj = (const float*)d_in[4];
  const float* dt_proj = (const float*)d_in[5];
  const float* dt_b = (const float*)d_in[6];
  const float* A_log = (const float*)d_in[7];
  const float* Dp = (const float*)d_in[8];
  const float* gamma = (const float*)d_in[9];
  const float* beta = (const float*)d_in[10];
  const float* out_proj = (const float*)d_in[11];
  float* out = (float*)d_out;

  char* p = (char*)d_ws;
  const size_t RC = (size_t)ROWS * DIN;
  unsigned short* XI = (unsigned short*)p;   p += RC * 2;   // 25.2 MB
  unsigned short* Z = (unsigned short*)p;    p += RC * 2;   // 25.2 MB
  unsigned short* DAp = (unsigned short*)p;  p += RC * 2;   // 25.2 MB
  unsigned short* DBXp = (unsigned short*)p; p += RC * 2;   // 25.2 MB
  unsigned short* Hb = (unsigned short*)p;   p += RC * 2;   // 25.2 MB
  float* XP = (float*)p;                     p += (size_t)NSPLIT * ROWS * 64 * 4;  // 16.8 MB
  unsigned short* DTLRb = (unsigned short*)p; p += (size_t)ROWS * 64 * 2;          // 1 MB
  float* BCv = (float*)p;                    p += ROWS * 4;
  float* CCv = (float*)p;                    p += ROWS * 4;
  float* negA = (float*)p;                   p += DIN * 4;
  unsigned short* Xbf = (unsigned short*)p;  p += (size_t)ROWS * DMOD * 2;         // 12.6 MB
  unsigned short* W1t = (unsigned short*)p;  p += (size_t)2 * DIN * DMOD * 2;      // 4.7 MB
  unsigned short* W2t = (unsigned short*)p;  p += (size_t)DMOD * DIN * 2;          // 2.4 MB
  unsigned short* XPW = (unsigned short*)p;  p += (size_t)64 * DIN * 2;
  unsigned short* DTWb = (unsigned short*)p; p += (size_t)DIN * 64 * 2;
  int* ipart = (int*)p;
  int* SLOT_PACK = ipart;
  int* SLOTINV = ipart + 2048;
  int* LSTART = ipart + 4096;
  int* NLEV = ipart + 4096 + 2049;
  unsigned short* YLN = DAp;  // DAp dead after recur; reuse for LN output

  prep1_kernel<<<1731, 1024, 0, stream>>>(sidx, spar, SLOT_PACK, SLOTINV,
                                          LSTART, NLEV, x, Xbf, x_proj, XPW,
                                          dt_proj, DTWb, A_log, negA);
  prep2_kernel<<<3456, 256, 0, stream>>>(in_proj, W1t, out_proj, W2t);
  gemm256_silu<<<dim3(12, 32), 512, 0, stream>>>(Xbf, W1t, XI, Z, DMOD);
  xdbl_mfma<<<dim3(NSPLIT, 64), 256, 0, stream>>>(XI, XPW, XP);
  xp_reduce<<<ROWS * 16 / 256, 256, 0, stream>>>(XP, DTLRb, BCv, CCv);
  dt_gemm<<<dim3(12, 128), 256, 0, stream>>>(DTLRb, DTWb, dt_b, negA, BCv, XI,
                                             SLOTINV, DAp, DBXp);
  recur_kernel<<<384, 256, 0, stream>>>(DAp, DBXp, Hb, SLOT_PACK, LSTART, NLEV);
  ln_kernel<<<ROWS, 256, 0, stream>>>(Hb, CCv, XI, Dp, gamma, beta, Z, YLN);
  mfma_gemm<0><<<dim3(6, 64), 256, 0, stream>>>(YLN, W2t, out, nullptr, DIN, DMOD);
}

// Round 4
// 317.320 us; speedup vs baseline: 1.0316x; 1.0316x over previous
//
#include <hip/hip_runtime.h>
#include <math.h>

// TreeMambaLayer: B=4, N=2048, D_MODEL=768, D_INNER=1536, DT_RANK=48
// Round 13: gemm256 -> 256x192 tile, grid 16x32 = 512 blocks = exactly
// 2 rounds at 1 block/CU (perfect balance vs 75%). Same 4-phase schedule,
// 7 staged quarters/tile, vmcnt(7). xdbl: NSPLIT 8->4, grid 256 exact,
// XP halved.

#define ROWS 8192
#define DIN 1536
#define DMOD 768
#define NSEQ 2048
#define DTR 48
#define NSPLIT 4

typedef __bf16 bfrag __attribute__((ext_vector_type(8)));
typedef float f4 __attribute__((ext_vector_type(4)));

__device__ __forceinline__ unsigned short f2bf(float f) {
  unsigned int u = __float_as_uint(f);
  unsigned int r = (u + 0x7fffu + ((u >> 16) & 1u)) >> 16;
  return (unsigned short)r;
}
__device__ __forceinline__ float bf2f(unsigned short h) {
  return __uint_as_float(((unsigned int)h) << 16);
}

__device__ __forceinline__ void gld_lds16(const void* g, void* l) {
  __builtin_amdgcn_global_load_lds((const __attribute__((address_space(1))) void*)g,
                                   (__attribute__((address_space(3))) void*)l, 16, 0, 0);
}

// raw barrier: no vmcnt drain; compiler-level memory fence only.
__device__ __forceinline__ void barx() {
  asm volatile("" ::: "memory");
  __builtin_amdgcn_s_barrier();
  asm volatile("" ::: "memory");
}

// ---------------- 256x192 4-phase bf16 GEMM, C = A(MxK) * Bt(NxK)^T
// cols < DIN -> XI bf16; cols >= DIN -> Z = silu, bf16.
// 8 waves (2M x 4N), per-wave 128x48 out. BK=64, LDS 112KB dbuf.
// A quarters q0-3 (64 rows each), B quarters q0-2. 7 loads/tile staged
// 2 tiles ahead into the current buffer after each quarter's last read.
__global__ __launch_bounds__(512, 1) void gemm256_silu(
    const unsigned short* __restrict__ A, const unsigned short* __restrict__ Bt,
    unsigned short* __restrict__ XI, unsigned short* __restrict__ Z, int K) {
  __shared__ unsigned short lds[2][(256 + 192) * 64];  // 112KB
  const int tid = threadIdx.x;
  const int w = tid >> 6, l = tid & 63;
  const int quad = l >> 4, l16 = l & 15;
  const int wr = w >> 2, wc = w & 3;
  const int row0 = blockIdx.y * 256, col0 = blockIdx.x * 192;
  const int nt = K >> 6;

  // staging source: thread t covers LDS bytes [t*16,+16) of an 8KB quarter:
  // row_local = t>>3, chunk slot = t&7; content swizzle slot^(row&7).
  const int srow = tid >> 3;
  const int schunk = ((tid & 7) ^ (srow & 7)) * 8;
  const unsigned short* aS = A + (size_t)(row0 + srow) * K + schunk;
  const unsigned short* bS = Bt + (size_t)(col0 + srow) * K + schunk;

#define STG_A(bufi, q, kt)                                     \
  gld_lds16(aS + (size_t)((q) * 64) * K + (size_t)(kt) * 64,   \
            (char*)&lds[bufi][(q) * 4096] + w * 1024)
#define STG_B(bufi, q, kt)                                     \
  gld_lds16(bS + (size_t)((q) * 64) * K + (size_t)(kt) * 64,   \
            (char*)&lds[bufi][16384 + (q) * 4096] + w * 1024)

  // fragment read bases (swizzled chunk per k-slice)
  const int arow = (wr * 128 + l16) * 64;
  const int brow = (wc * 48 + l16) * 64;
  int cs[2];
  cs[0] = (quad ^ (l16 & 7)) * 8;
  cs[1] = ((4 + quad) ^ (l16 & 7)) * 8;

#define RDA(m, ks) (*(const bfrag*)(const void*)(LA + arow + (m) * 1024 + cs[ks]))
#define RDB(n, ks) (*(const bfrag*)(const void*)(LB + brow + (n) * 1024 + cs[ks]))

  f4 acc[8][3];
#pragma unroll
  for (int m = 0; m < 8; m++)
#pragma unroll
    for (int n = 0; n < 3; n++) acc[m][n] = (f4){0.f, 0.f, 0.f, 0.f};

  // prologue: stage t0 (7) and t1 (7); wait until t0's 7 landed.
  const int kt1 = (nt > 1) ? 1 : 0;
#pragma unroll
  for (int q = 0; q < 4; q++) STG_A(0, q, 0);
#pragma unroll
  for (int q = 0; q < 3; q++) STG_B(0, q, 0);
#pragma unroll
  for (int q = 0; q < 4; q++) STG_A(1, q, kt1);
#pragma unroll
  for (int q = 0; q < 3; q++) STG_B(1, q, kt1);
  asm volatile("s_waitcnt vmcnt(7)" ::: "memory");
  barx();

  for (int t = 0; t < nt; ++t) {
    const int b = t & 1;
    const unsigned short* LA = &lds[b][0];
    const unsigned short* LB = &lds[b][16384];
    const int kA = (t + 2 < nt) ? (t + 2) : (nt - 1);  // tile t+2 -> buf b
    bfrag af[4][2], bfr[3][2];

    // ---- ph0: read A m0-3 + B n0-1; MFMA (m-lo, n0-1)
#pragma unroll
    for (int m = 0; m < 4; m++) {
      af[m][0] = RDA(m, 0);
      af[m][1] = RDA(m, 1);
    }
#pragma unroll
    for (int n = 0; n < 2; n++) {
      bfr[n][0] = RDB(n, 0);
      bfr[n][1] = RDB(n, 1);
    }
    barx();
    __builtin_amdgcn_s_setprio(1);
#pragma unroll
    for (int m = 0; m < 4; m++)
#pragma unroll
      for (int n = 0; n < 2; n++) {
        acc[m][n] = __builtin_amdgcn_mfma_f32_16x16x32_bf16(af[m][0], bfr[n][0], acc[m][n], 0, 0, 0);
        acc[m][n] = __builtin_amdgcn_mfma_f32_16x16x32_bf16(af[m][1], bfr[n][1], acc[m][n], 0, 0, 0);
      }
    __builtin_amdgcn_s_setprio(0);
    barx();

    // ---- ph1: read B n2; MFMA (m-lo, n2)
    bfr[2][0] = RDB(2, 0);
    bfr[2][1] = RDB(2, 1);
    barx();
    __builtin_amdgcn_s_setprio(1);
#pragma unroll
    for (int m = 0; m < 4; m++) {
      acc[m][2] = __builtin_amdgcn_mfma_f32_16x16x32_bf16(af[m][0], bfr[2][0], acc[m][2], 0, 0, 0);
      acc[m][2] = __builtin_amdgcn_mfma_f32_16x16x32_bf16(af[m][1], bfr[2][1], acc[m][2], 0, 0, 0);
    }
    __builtin_amdgcn_s_setprio(0);
    barx();

    // ---- ph2: stage t+2 A-Q0,Q2 + B-Q0,Q1; read A m4-7; MFMA (m-hi, n0-1)
    STG_A(b, 0, kA);
    STG_A(b, 2, kA);
    STG_B(b, 0, kA);
    STG_B(b, 1, kA);
#pragma unroll
    for (int m = 0; m < 4; m++) {
      af[m][0] = RDA(m + 4, 0);
      af[m][1] = RDA(m + 4, 1);
    }
    barx();
    __builtin_amdgcn_s_setprio(1);
#pragma unroll
    for (int m = 0; m < 4; m++)
#pragma unroll
      for (int n = 0; n < 2; n++) {
        acc[m + 4][n] = __builtin_amdgcn_mfma_f32_16x16x32_bf16(af[m][0], bfr[n][0], acc[m + 4][n], 0, 0, 0);
        acc[m + 4][n] = __builtin_amdgcn_mfma_f32_16x16x32_bf16(af[m][1], bfr[n][1], acc[m + 4][n], 0, 0, 0);
      }
    __builtin_amdgcn_s_setprio(0);
    barx();

    // ---- ph3: stage t+2 A-Q1,Q3 + B-Q2; MFMA (m-hi, n2); counted vmcnt
    STG_A(b, 1, kA);
    STG_A(b, 3, kA);
    STG_B(b, 2, kA);
    barx();
    __builtin_amdgcn_s_setprio(1);
#pragma unroll
    for (int m = 0; m < 4; m++) {
      acc[m + 4][2] = __builtin_amdgcn_mfma_f32_16x16x32_bf16(af[m][0], bfr[2][0], acc[m + 4][2], 0, 0, 0);
      acc[m + 4][2] = __builtin_amdgcn_mfma_f32_16x16x32_bf16(af[m][1], bfr[2][1], acc[m + 4][2], 0, 0, 0);
    }
    __builtin_amdgcn_s_setprio(0);
    // tile t+1's 7 loads (issued one full tile ago) must be landed;
    // tile t+2's 7 (issued this tile) stay in flight.
    asm volatile("s_waitcnt vmcnt(7)" ::: "memory");
    barx();
  }
  asm volatile("s_waitcnt vmcnt(0)" ::: "memory");

#undef STG_A
#undef STG_B
#undef RDA
#undef RDB

  // epilogue: 192-wide col tiles are entirely XI or entirely Z (1536%192==0)
  const bool is_z = (col0 >= DIN);
  unsigned short* dst = is_z ? Z : XI;
  const int cb = col0 + wc * 48 + l16 - (is_z ? DIN : 0);
#pragma unroll
  for (int m = 0; m < 8; m++) {
    const int rb = row0 + wr * 128 + m * 16 + quad * 4;
#pragma unroll
    for (int n = 0; n < 3; n++)
#pragma unroll
      for (int r = 0; r < 4; r++) {
        float v = acc[m][n][r];
        if (is_z) v = v / (1.f + __expf(-v));
        dst[(size_t)(rb + r) * DIN + cb + n * 16] = f2bf(v);
      }
  }
}

// ------------------------------------------------------------- bf16 MFMA GEMM
// BK=32, 128x128 tile, swizzled LDS. MODE 0: fp32 C.
template <int MODE>
__global__ __launch_bounds__(256) void mfma_gemm(
    const unsigned short* __restrict__ A, const unsigned short* __restrict__ Bt,
    void* __restrict__ C0v, void* __restrict__ C1v, int K, int ldc) {
  __shared__ unsigned short As[128 * 32];
  __shared__ unsigned short Bs[128 * 32];
  const int tid = threadIdx.x;
  const int w = tid >> 6, l = tid & 63;
  const int quad = l >> 4, l16 = l & 15;
  const int wrow = (w >> 1) * 64, wcol = (w & 1) * 64;
  const int row0 = blockIdx.y * 128, col0 = blockIdx.x * 128;

  f4 acc[4][4];
#pragma unroll
  for (int i = 0; i < 4; i++)
#pragma unroll
    for (int j = 0; j < 4; j++) acc[i][j] = (f4){0.f, 0.f, 0.f, 0.f};

  const int arow = row0 + w * 16 + (l >> 2);
  const int brow = col0 + w * 16 + (l >> 2);
  const int kcol = (((l & 3) ^ ((l >> 2) & 3)) * 8);  // swizzled chunk
  const int qs = (quad ^ (l16 & 3)) * 8;              // fragment chunk

  for (int k0 = 0; k0 < K; k0 += 32) {
#pragma unroll
    for (int r = 0; r < 2; r++) {
      gld_lds16(A + (size_t)(arow + r * 64) * K + k0 + kcol,
                (char*)As + r * 4096 + w * 1024);
      gld_lds16(Bt + (size_t)(brow + r * 64) * K + k0 + kcol,
                (char*)Bs + r * 4096 + w * 1024);
    }
    __syncthreads();
    bfrag af[4], bf[4];
#pragma unroll
    for (int i = 0; i < 4; i++)
      af[i] = *(const bfrag*)(const void*)(As + (wrow + i * 16 + l16) * 32 + qs);
#pragma unroll
    for (int j = 0; j < 4; j++)
      bf[j] = *(const bfrag*)(const void*)(Bs + (wcol + j * 16 + l16) * 32 + qs);
#pragma unroll
    for (int i = 0; i < 4; i++)
#pragma unroll
      for (int j = 0; j < 4; j++)
        acc[i][j] = __builtin_amdgcn_mfma_f32_16x16x32_bf16(af[i], bf[j], acc[i][j], 0, 0, 0);
    __syncthreads();
  }

  if (MODE == 0) {
    float* C0 = (float*)C0v;
    const int ccol = col0 + wcol + l16;
#pragma unroll
    for (int i = 0; i < 4; i++) {
      const int rb = row0 + wrow + i * 16 + quad * 4;
#pragma unroll
      for (int j = 0; j < 4; j++)
#pragma unroll
        for (int r = 0; r < 4; r++)
          C0[(size_t)(rb + r) * ldc + ccol + j * 16] = acc[i][j][r];
    }
  } else {
    const bool is_z = (col0 >= DIN);
    unsigned short* dst = is_z ? (unsigned short*)C1v : (unsigned short*)C0v;
    const int cbase = col0 + wcol + l16 - (is_z ? DIN : 0);
#pragma unroll
    for (int i = 0; i < 4; i++) {
      const int rb = row0 + wrow + i * 16 + quad * 4;
#pragma unroll
      for (int j = 0; j < 4; j++)
#pragma unroll
        for (int r = 0; r < 4; r++) {
          float v = acc[i][j][r];
          if (is_z) v = v / (1.f + __expf(-v));
          dst[(size_t)(rb + r) * DIN + cbase + j * 16] = f2bf(v);
        }
    }
  }
}

// ------------------- prep1 (1024 thr): sched (block 0) + all flat casts
// SLOT_PACK[slot] = node | ((pnode+1)<<12); SLOTINV[node] = slot.
__global__ __launch_bounds__(1024) void prep1_kernel(
    const int* __restrict__ sidx, const int* __restrict__ spar,
    int* __restrict__ SLOT_PACK, int* __restrict__ SLOTINV,
    int* __restrict__ LSTART, int* __restrict__ NLEV,
    const float* __restrict__ x, unsigned short* __restrict__ Xbf,
    const float* __restrict__ xpw, unsigned short* __restrict__ XPW,
    const float* __restrict__ dtw, unsigned short* __restrict__ DTWb,
    const float* __restrict__ A_log, float* __restrict__ negA) {
  const int bi = blockIdx.x;
  const int tid = threadIdx.x;
  if (bi == 0) {
    __shared__ int par[2048], idx[2048], ancA[2048], ancB[2048], rnkA[2048], rnkB[2048];
    __shared__ int dmax;
    for (int i = tid; i < 2048; i += 1024) {
      const int p = spar[i];
      par[i] = p;
      idx[i] = sidx[i];
      ancA[i] = (p < 0) ? -1 : p;
      rnkA[i] = (p < 0) ? 0 : 1;
    }
    if (tid == 0) dmax = 0;
    __syncthreads();
    for (int r = 0; r < 11; r++) {
      int* ca = (r & 1) ? ancB : ancA;
      int* cr = (r & 1) ? rnkB : rnkA;
      int* na = (r & 1) ? ancA : ancB;
      int* nr = (r & 1) ? rnkA : rnkB;
      for (int i = tid; i < 2048; i += 1024) {
        const int a = ca[i], rv = cr[i];
        if (a >= 0) {
          nr[i] = rv + cr[a];
          na[i] = ca[a];
        } else {
          nr[i] = rv;
          na[i] = a;
        }
      }
      __syncthreads();
    }
    for (int i = tid; i < 2048; i += 1024) ancA[i] = 0;
    __syncthreads();
    for (int i = tid; i < 2048; i += 1024) {
      atomicAdd(&ancA[rnkB[i]], 1);
      atomicMax(&dmax, rnkB[i]);
    }
    __syncthreads();
    for (int s = 0; s < 11; s++) {
      const int off = 1 << s;
      int* cur = (s & 1) ? ancB : ancA;
      int* nxt = (s & 1) ? ancA : ancB;
      for (int i = tid; i < 2048; i += 1024) {
        int v = cur[i];
        if (i >= off) v += cur[i - off];
        nxt[i] = v;
      }
      __syncthreads();
    }
    for (int i = tid; i < 2049; i += 1024) {
      const int v = (i == 0) ? 0 : ancB[i - 1];
      LSTART[i] = v;
      if (i < 2048) rnkA[i] = v;
    }
    if (tid == 0) NLEV[0] = dmax + 1;
    __syncthreads();
    for (int i = tid; i < 2048; i += 1024) {
      const int d = rnkB[i];
      const int slot = atomicAdd(&rnkA[d], 1);
      const int node = idx[i];
      const int p = par[i];
      const int pn = (p < 0) ? -1 : idx[p];
      SLOT_PACK[slot] = node | ((pn + 1) << 12);
      SLOTINV[node] = slot;
    }
  } else if (bi < 1 + 1536) {
    const int i = ((bi - 1) * 1024 + tid) * 4;
    const float4 v = *(const float4*)(x + i);
    union { unsigned short h[4]; uint2 u; } pk;
    pk.h[0] = f2bf(v.x);
    pk.h[1] = f2bf(v.y);
    pk.h[2] = f2bf(v.z);
    pk.h[3] = f2bf(v.w);
    *(uint2*)(Xbf + i) = pk.u;
  } else if (bi < 1 + 1536 + 96) {
    const int i = (bi - 1537) * 1024 + tid;  // 64*1536
    const int c = i / 1536, k = i % 1536;
    XPW[i] = (c < 50) ? f2bf(xpw[(size_t)k * 50 + c]) : (unsigned short)0;
  } else if (bi < 1 + 1536 + 96 + 96) {
    const int i = (bi - 1633) * 1024 + tid;  // 1536*64
    const int d = i >> 6, k = i & 63;
    DTWb[i] = (k < 48) ? f2bf(dtw[(size_t)k * DIN + d]) : (unsigned short)0;
  } else {
    const int i = (bi - 1729) * 1024 + tid;
    if (i < DIN) negA[i] = -__expf(A_log[i]);
  }
}

// ------------------- prep2 (256 thr): both weight transposes, fp32 -> bf16^T
__global__ __launch_bounds__(256) void prep2_kernel(
    const float* __restrict__ W1, unsigned short* __restrict__ W1t,
    const float* __restrict__ W2, unsigned short* __restrict__ W2t) {
  __shared__ float t[32][33];
  int idx = blockIdx.x;
  const float* W;
  unsigned short* Wt;
  int K, N, n0, k0;
  if (idx < 2304) {  // in_proj: K=768, N=3072 -> 96x24 tiles
    W = W1; Wt = W1t; K = DMOD; N = 2 * DIN;
    n0 = (idx % 96) * 32; k0 = (idx / 96) * 32;
  } else {           // out_proj: K=1536, N=768 -> 24x48 tiles
    idx -= 2304;
    W = W2; Wt = W2t; K = DIN; N = DMOD;
    n0 = (idx % 24) * 32; k0 = (idx / 24) * 32;
  }
  const int tx = threadIdx.x & 31, ty = threadIdx.x >> 5;
  for (int i = ty; i < 32; i += 8) t[i][tx] = W[(size_t)(k0 + i) * N + n0 + tx];
  __syncthreads();
  for (int i = ty; i < 32; i += 8)
    Wt[(size_t)(n0 + i) * K + k0 + tx] = f2bf(t[tx][i]);
}

// ------------------------------------------------- x_dbl: split-K bf16 MFMA
__global__ __launch_bounds__(256) void xdbl_mfma(
    const unsigned short* __restrict__ XI, const unsigned short* __restrict__ XPW,
    float* __restrict__ XP) {
  __shared__ unsigned short As[128 * 32];
  __shared__ unsigned short Bs[64 * 32];
  const int tid = threadIdx.x;
  const int w = tid >> 6, l = tid & 63;
  const int quad = l >> 4, l16 = l & 15;
  const int split = blockIdx.x;
  const int row0 = blockIdx.y * 128;
  const int kbase = split * (DIN / NSPLIT);  // 384

  f4 acc[2][4];
#pragma unroll
  for (int i = 0; i < 2; i++)
#pragma unroll
    for (int j = 0; j < 4; j++) acc[i][j] = (f4){0.f, 0.f, 0.f, 0.f};

  const int srow = w * 16 + (l >> 2);
  const int kcol = (((l & 3) ^ ((l >> 2) & 3)) * 8);
  const int qs = (quad ^ (l16 & 3)) * 8;

  for (int c = 0; c < 12; c++) {
    const int k0 = kbase + c * 32;
#pragma unroll
    for (int r = 0; r < 2; r++) {
      gld_lds16(XI + (size_t)(row0 + srow + r * 64) * DIN + k0 + kcol,
                (char*)As + r * 4096 + w * 1024);
    }
    gld_lds16(XPW + (size_t)srow * DIN + k0 + kcol, (char*)Bs + w * 1024);
    __syncthreads();
    bfrag af[2], bf[4];
#pragma unroll
    for (int i = 0; i < 2; i++)
      af[i] = *(const bfrag*)(const void*)(As + (w * 32 + i * 16 + l16) * 32 + qs);
#pragma unroll
    for (int j = 0; j < 4; j++)
      bf[j] = *(const bfrag*)(const void*)(Bs + (j * 16 + l16) * 32 + qs);
#pragma unroll
    for (int i = 0; i < 2; i++)
#pragma unroll
      for (int j = 0; j < 4; j++)
        acc[i][j] = __builtin_amdgcn_mfma_f32_16x16x32_bf16(af[i], bf[j], acc[i][j], 0, 0, 0);
    __syncthreads();
  }

  float* dst = XP + (size_t)split * ROWS * 64 + (size_t)row0 * 64;
#pragma unroll
  for (int i = 0; i < 2; i++) {
    const int rb = w * 32 + i * 16 + quad * 4;
#pragma unroll
    for (int j = 0; j < 4; j++) {
      const int col = j * 16 + l16;
#pragma unroll
      for (int r = 0; r < 4; r++) dst[(size_t)(rb + r) * 64 + col] = acc[i][j][r];
    }
  }
}

// -------------------------- reduce XP partials -> DTLRb bf16 + BC/CC fp32
__global__ __launch_bounds__(256) void xp_reduce(
    const float* __restrict__ XP, unsigned short* __restrict__ DTLRb,
    float* __restrict__ BCv, float* __restrict__ CCv) {
  const int i = blockIdx.x * 256 + threadIdx.x;  // 8192*16
  const int row = i >> 4, c4 = (i & 15) * 4;
  const float* p = XP + (size_t)row * 64 + c4;
  float4 s = make_float4(0.f, 0.f, 0.f, 0.f);
#pragma unroll
  for (int sp = 0; sp < NSPLIT; sp++) {
    const float4 v = *(const float4*)(p + (size_t)sp * ROWS * 64);
    s.x += v.x;
    s.y += v.y;
    s.z += v.z;
    s.w += v.w;
  }
  if (c4 == 48) {
    BCv[row] = s.x;
    CCv[row] = s.y;
  }
  union { unsigned short h[4]; uint2 u; } pk;
  pk.h[0] = f2bf(s.x);
  pk.h[1] = f2bf(s.y);
  pk.h[2] = f2bf(s.z);
  pk.h[3] = f2bf(s.w);
  *(uint2*)(DTLRb + (size_t)row * 64 + c4) = pk.u;
}

// ------- dt GEMM (K=64) -> dA/dBx bf16, rows permuted to slot order.
// grid (12, 128). 64 rows x 128 cols per block.
__global__ __launch_bounds__(256) void dt_gemm(
    const unsigned short* __restrict__ DTLRb, const unsigned short* __restrict__ DTWb,
    const float* __restrict__ bias, const float* __restrict__ negA,
    const float* __restrict__ BCv, const unsigned short* __restrict__ XI,
    const int* __restrict__ SLOTINV,
    unsigned short* __restrict__ DAp, unsigned short* __restrict__ DBXp) {
  __shared__ unsigned short As[2][64 * 32];
  __shared__ unsigned short Bs[2][128 * 32];
  __shared__ int sinv[64];
  __shared__ float bcs[64];
  const int tid = threadIdx.x;
  const int w = tid >> 6, l = tid & 63;
  const int quad = l >> 4, l16 = l & 15;
  const int wrow = (w >> 1) * 32, wcol = (w & 1) * 64;
  const int row0 = blockIdx.y * 64, col0 = blockIdx.x * 128;
  const int p0 = row0 & (NSEQ - 1);       // position base (batch-local)
  const int bbase = row0 & ~(NSEQ - 1);   // b*2048
  const int srow = w * 16 + (l >> 2);
  const int koff = (((l & 3) ^ ((l >> 2) & 3)) * 8);
  const int qs = (quad ^ (l16 & 3)) * 8;

#pragma unroll
  for (int c = 0; c < 2; c++) {
    gld_lds16(DTLRb + (size_t)(row0 + srow) * 64 + c * 32 + koff,
              (char*)As[c] + w * 1024);
#pragma unroll
    for (int r = 0; r < 2; r++)
      gld_lds16(DTWb + (size_t)(col0 + srow + r * 64) * 64 + c * 32 + koff,
                (char*)Bs[c] + r * 4096 + w * 1024);
  }
  if (tid < 64) {
    sinv[tid] = SLOTINV[p0 + tid];
    bcs[tid] = BCv[row0 + tid];
  }
  __syncthreads();

  f4 acc[2][4];
#pragma unroll
  for (int i = 0; i < 2; i++)
#pragma unroll
    for (int j = 0; j < 4; j++) acc[i][j] = (f4){0.f, 0.f, 0.f, 0.f};

#pragma unroll
  for (int c = 0; c < 2; c++) {
    bfrag af[2], bf[4];
#pragma unroll
    for (int i = 0; i < 2; i++)
      af[i] = *(const bfrag*)(const void*)(As[c] + (wrow + i * 16 + l16) * 32 + qs);
#pragma unroll
    for (int j = 0; j < 4; j++)
      bf[j] = *(const bfrag*)(const void*)(Bs[c] + (wcol + j * 16 + l16) * 32 + qs);
#pragma unroll
    for (int i = 0; i < 2; i++)
#pragma unroll
      for (int j = 0; j < 4; j++)
        acc[i][j] = __builtin_amdgcn_mfma_f32_16x16x32_bf16(af[i], bf[j], acc[i][j], 0, 0, 0);
  }

  float bj[4], aj[4];
#pragma unroll
  for (int j = 0; j < 4; j++) {
    const int d = col0 + wcol + j * 16 + l16;
    bj[j] = bias[d];
    aj[j] = negA[d];
  }
#pragma unroll
  for (int i = 0; i < 2; i++) {
#pragma unroll
    for (int r = 0; r < 4; r++) {
      const int row_l = wrow + i * 16 + quad * 4 + r;
      const int row = row0 + row_l;
      const float bc = bcs[row_l];
      const size_t rp = (size_t)(bbase + sinv[row_l]) * DIN;
#pragma unroll
      for (int j = 0; j < 4; j++) {
        const int d = col0 + wcol + j * 16 + l16;
        const float s = acc[i][j][r] + bj[j];
        const float sp = fmaxf(s, 0.f) + __logf(1.f + __expf(-fabsf(s)));
        const float xi = bf2f(XI[(size_t)row * DIN + d]);
        DAp[rp + d] = f2bf(__expf(sp * aj[j]));
        DBXp[rp + d] = f2bf(sp * bc * xi);
      }
    }
  }
}

// ----------------- tree recurrence: h resident in LDS, slot-ordered loads
// block owns 16 bf16 columns (2 chunks of 8); h[node][16] in LDS (64KB).
__global__ __launch_bounds__(256) void recur_kernel(
    const unsigned short* __restrict__ DAp, const unsigned short* __restrict__ DBXp,
    unsigned short* __restrict__ Hb,
    const int* __restrict__ SLOT_PACK, const int* __restrict__ LSTART,
    const int* __restrict__ NLEV) {
  __shared__ unsigned short hl[NSEQ * 16];  // 64 KB
  __shared__ int spack[NSEQ];               // 8 KB
  __shared__ int lst[258];                  // ~1 KB
  const int tid = threadIdx.x;
  const int c8a = blockIdx.x * 2;           // both chunks in same batch
  const int b = c8a / 192;
  const int d8a = c8a % 192;
  const int nlev = NLEV[0];
  for (int i = tid; i < NSEQ; i += 256) spack[i] = SLOT_PACK[i];
  const int nl = (nlev + 1 < 258) ? nlev + 1 : 258;
  for (int i = tid; i < nl; i += 256) lst[i] = LSTART[i];
  __syncthreads();

  for (int L = 0; L < nlev; L++) {
    const int s0 = (L < 257) ? lst[L] : LSTART[L];
    const int s1 = (L + 1 < 258) ? lst[L + 1] : LSTART[L + 1];
    const int items = (s1 - s0) * 2;
    for (int it = tid; it < items; it += 256) {
      const int s = s0 + (it >> 1);
      const int ch = it & 1;
      const size_t goff = (size_t)(b * NSEQ + s) * DIN + (d8a + ch) * 8;
      union { uint4 u; unsigned short h[8]; } da, dbx, hpu, hvu;
      da.u = *(const uint4*)(DAp + goff);
      dbx.u = *(const uint4*)(DBXp + goff);
      const int pk = spack[s];
      const int node = pk & 4095;
      const int pn = (pk >> 12) - 1;
      float hp[8];
      if (pn >= 0) {
        hpu.u = *(const uint4*)(hl + pn * 16 + ch * 8);
#pragma unroll
        for (int e = 0; e < 8; e++) hp[e] = bf2f(hpu.h[e]);
      } else {
#pragma unroll
        for (int e = 0; e < 8; e++) hp[e] = 0.f;
      }
#pragma unroll
      for (int e = 0; e < 8; e++) {
        const float hv = fmaf(bf2f(da.h[e]), hp[e], bf2f(dbx.h[e]));
        hvu.h[e] = f2bf(hv);
      }
      *(uint4*)(hl + node * 16 + ch * 8) = hvu.u;
    }
    __syncthreads();
  }

  // flush h to global (node-major for ln)
  for (int i = tid; i < NSEQ * 2; i += 256) {
    const int node = i >> 1, ch = i & 1;
    *(uint4*)(Hb + (size_t)(b * NSEQ + node) * DIN + (d8a + ch) * 8) =
        *(const uint4*)(hl + node * 16 + ch * 8);
  }
}

// --------------------------------------------- y, layernorm, z-gate -> bf16
__global__ __launch_bounds__(256) void ln_kernel(
    const unsigned short* __restrict__ Hb, const float* __restrict__ CCv,
    const unsigned short* __restrict__ XI, const float* __restrict__ Dp,
    const float* __restrict__ gamma, const float* __restrict__ beta,
    const unsigned short* __restrict__ Z, unsigned short* __restrict__ YLN) {
  const int row = blockIdx.x;
  const int tid = threadIdx.x;
  const float C = CCv[row];
  const unsigned short* hrow = Hb + (size_t)row * DIN;
  const unsigned short* xrow = XI + (size_t)row * DIN;
  float y[6];
  float s = 0.f, s2 = 0.f;
#pragma unroll
  for (int i = 0; i < 6; i++) {
    const int d = tid + i * 256;
    const float v = fmaf(bf2f(hrow[d]), C, Dp[d] * bf2f(xrow[d]));
    y[i] = v;
    s += v;
    s2 = fmaf(v, v, s2);
  }
#pragma unroll
  for (int off = 32; off >= 1; off >>= 1) {
    s += __shfl_down(s, off);
    s2 += __shfl_down(s2, off);
  }
  __shared__ float rs[4], rs2[4];
  const int w = tid >> 6;
  if ((tid & 63) == 0) {
    rs[w] = s;
    rs2[w] = s2;
  }
  __syncthreads();
  const float ts = rs[0] + rs[1] + rs[2] + rs[3];
  const float ts2 = rs2[0] + rs2[1] + rs2[2] + rs2[3];
  const float mu = ts * (1.f / 1536.f);
  const float var = ts2 * (1.f / 1536.f) - mu * mu;
  const float inv = rsqrtf(var + 1e-5f);
  unsigned short* yrow = YLN + (size_t)row * DIN;
  const unsigned short* zrow = Z + (size_t)row * DIN;
#pragma unroll
  for (int i = 0; i < 6; i++) {
    const int d = tid + i * 256;
    const float o = (y[i] - mu) * inv * gamma[d] + beta[d];
    yrow[d] = f2bf(o * bf2f(zrow[d]));
  }
}

// ---------------------------------------------------------------------- launch
extern "C" void kernel_launch(void* const* d_in, const int* in_sizes, int n_in,
                              void* d_out, int out_size, void* d_ws, size_t ws_size,
                              hipStream_t stream) {
  const float* x = (const float*)d_in[0];
  const int* sidx = (const int*)d_in[1];
  const int* spar = (const int*)d_in[2];
  const float* in_proj = (const float*)d_in[3];
  const float* x_proj = (const float*)d_in[4];
  const float* dt_proj = (const float*)d_in[5];
  const float* dt_b = (const float*)d_in[6];
  const float* A_log = (const float*)d_in[7];
  const float* Dp = (const float*)d_in[8];
  const float* gamma = (const float*)d_in[9];
  const float* beta = (const float*)d_in[10];
  const float* out_proj = (const float*)d_in[11];
  float* out = (float*)d_out;

  char* p = (char*)d_ws;
  const size_t RC = (size_t)ROWS * DIN;
  unsigned short* XI = (unsigned short*)p;   p += RC * 2;   // 25.2 MB
  unsigned short* Z = (unsigned short*)p;    p += RC * 2;   // 25.2 MB
  unsigned short* DAp = (unsigned short*)p;  p += RC * 2;   // 25.2 MB
  unsigned short* DBXp = (unsigned short*)p; p += RC * 2;   // 25.2 MB
  unsigned short* Hb = (unsigned short*)p;   p += RC * 2;   // 25.2 MB
  float* XP = (float*)p;                     p += (size_t)NSPLIT * ROWS * 64 * 4;  // 8.4 MB
  unsigned short* DTLRb = (unsigned short*)p; p += (size_t)ROWS * 64 * 2;          // 1 MB
  float* BCv = (float*)p;                    p += ROWS * 4;
  float* CCv = (float*)p;                    p += ROWS * 4;
  float* negA = (float*)p;                   p += DIN * 4;
  unsigned short* Xbf = (unsigned short*)p;  p += (size_t)ROWS * DMOD * 2;         // 12.6 MB
  unsigned short* W1t = (unsigned short*)p;  p += (size_t)2 * DIN * DMOD * 2;      // 4.7 MB
  unsigned short* W2t = (unsigned short*)p;  p += (size_t)DMOD * DIN * 2;          // 2.4 MB
  unsigned short* XPW = (unsigned short*)p;  p += (size_t)64 * DIN * 2;
  unsigned short* DTWb = (unsigned short*)p; p += (size_t)DIN * 64 * 2;
  int* ipart = (int*)p;
  int* SLOT_PACK = ipart;
  int* SLOTINV = ipart + 2048;
  int* LSTART = ipart + 4096;
  int* NLEV = ipart + 4096 + 2049;
  unsigned short* YLN = DAp;  // DAp dead after recur; reuse for LN output

  prep1_kernel<<<1731, 1024, 0, stream>>>(sidx, spar, SLOT_PACK, SLOTINV,
                                          LSTART, NLEV, x, Xbf, x_proj, XPW,
                                          dt_proj, DTWb, A_log, negA);
  prep2_kernel<<<3456, 256, 0, stream>>>(in_proj, W1t, out_proj, W2t);
  gemm256_silu<<<dim3(16, 32), 512, 0, stream>>>(Xbf, W1t, XI, Z, DMOD);
  xdbl_mfma<<<dim3(NSPLIT, 64), 256, 0, stream>>>(XI, XPW, XP);
  xp_reduce<<<ROWS * 16 / 256, 256, 0, stream>>>(XP, DTLRb, BCv, CCv);
  dt_gemm<<<dim3(12, 128), 256, 0, stream>>>(DTLRb, DTWb, dt_b, negA, BCv, XI,
                                             SLOTINV, DAp, DBXp);
  recur_kernel<<<384, 256, 0, stream>>>(DAp, DBXp, Hb, SLOT_PACK, LSTART, NLEV);
  ln_kernel<<<ROWS, 256, 0, stream>>>(Hb, CCv, XI, Dp, gamma, beta, Z, YLN);
  mfma_gemm<0><<<dim3(6, 64), 256, 0, stream>>>(YLN, W2t, out, nullptr, DIN, DMOD);
}

// Round 6
// 310.021 us; speedup vs baseline: 1.0559x; 1.0235x over previous
//
#include <hip/hip_runtime.h>
#include <math.h>

// TreeMambaLayer: B=4, N=2048, D_MODEL=768, D_INNER=1536, DT_RANK=48
// Round 14 (resubmit): (a) XCD-aware block swizzle on gemm256/mfma_gemm/xdbl
// (A-panel sharers -> same XCD L2); (b) gemm256 epilogue via LDS-staged bf16
// tile -> coalesced 16B/lane row writes (kills 2x write amplification).
// Schedule frozen from R13.

#define ROWS 8192
#define DIN 1536
#define DMOD 768
#define NSEQ 2048
#define DTR 48
#define NSPLIT 4

typedef __bf16 bfrag __attribute__((ext_vector_type(8)));
typedef float f4 __attribute__((ext_vector_type(4)));

__device__ __forceinline__ unsigned short f2bf(float f) {
  unsigned int u = __float_as_uint(f);
  unsigned int r = (u + 0x7fffu + ((u >> 16) & 1u)) >> 16;
  return (unsigned short)r;
}
__device__ __forceinline__ float bf2f(unsigned short h) {
  return __uint_as_float(((unsigned int)h) << 16);
}

__device__ __forceinline__ void gld_lds16(const void* g, void* l) {
  __builtin_amdgcn_global_load_lds((const __attribute__((address_space(1))) void*)g,
                                   (__attribute__((address_space(3))) void*)l, 16, 0, 0);
}

// raw barrier: no vmcnt drain; compiler-level memory fence only.
__device__ __forceinline__ void barx() {
  asm volatile("" ::: "memory");
  __builtin_amdgcn_s_barrier();
  asm volatile("" ::: "memory");
}

// ---------------- 256x192 4-phase bf16 GEMM, C = A(MxK) * Bt(NxK)^T
// cols < DIN -> XI bf16; cols >= DIN -> Z = silu, bf16.
// 8 waves (2M x 4N), per-wave 128x48 out. BK=64, LDS 112KB dbuf.
// Deep pipeline (R12/R13) + XCD swizzle + LDS-staged coalesced epilogue.
__global__ __launch_bounds__(512, 1) void gemm256_silu(
    const unsigned short* __restrict__ A, const unsigned short* __restrict__ Bt,
    unsigned short* __restrict__ XI, unsigned short* __restrict__ Z, int K) {
  __shared__ unsigned short lds[2][(256 + 192) * 64];  // 112KB
  const int tid = threadIdx.x;
  const int w = tid >> 6, l = tid & 63;
  const int quad = l >> 4, l16 = l & 15;
  const int wr = w >> 2, wc = w & 3;
  // XCD swizzle: 512 blocks, XCD k owns logical ids [64k,64k+64) = 4 full
  // A-row-panels (16 col-sharers each -> same XCD L2).
  const int h = blockIdx.x + 16 * blockIdx.y;
  const int swz = (h & 7) * 64 + (h >> 3);
  const int row0 = (swz >> 4) * 256, col0 = (swz & 15) * 192;
  const int nt = K >> 6;

  const int srow = tid >> 3;
  const int schunk = ((tid & 7) ^ (srow & 7)) * 8;
  const unsigned short* aS = A + (size_t)(row0 + srow) * K + schunk;
  const unsigned short* bS = Bt + (size_t)(col0 + srow) * K + schunk;

#define STG_A(bufi, q, kt)                                     \
  gld_lds16(aS + (size_t)((q) * 64) * K + (size_t)(kt) * 64,   \
            (char*)&lds[bufi][(q) * 4096] + w * 1024)
#define STG_B(bufi, q, kt)                                     \
  gld_lds16(bS + (size_t)((q) * 64) * K + (size_t)(kt) * 64,   \
            (char*)&lds[bufi][16384 + (q) * 4096] + w * 1024)

  const int arow = (wr * 128 + l16) * 64;
  const int brow = (wc * 48 + l16) * 64;
  int cs[2];
  cs[0] = (quad ^ (l16 & 7)) * 8;
  cs[1] = ((4 + quad) ^ (l16 & 7)) * 8;

#define RDA(m, ks) (*(const bfrag*)(const void*)(LA + arow + (m) * 1024 + cs[ks]))
#define RDB(n, ks) (*(const bfrag*)(const void*)(LB + brow + (n) * 1024 + cs[ks]))

  f4 acc[8][3];
#pragma unroll
  for (int m = 0; m < 8; m++)
#pragma unroll
    for (int n = 0; n < 3; n++) acc[m][n] = (f4){0.f, 0.f, 0.f, 0.f};

  const int kt1 = (nt > 1) ? 1 : 0;
#pragma unroll
  for (int q = 0; q < 4; q++) STG_A(0, q, 0);
#pragma unroll
  for (int q = 0; q < 3; q++) STG_B(0, q, 0);
#pragma unroll
  for (int q = 0; q < 4; q++) STG_A(1, q, kt1);
#pragma unroll
  for (int q = 0; q < 3; q++) STG_B(1, q, kt1);
  asm volatile("s_waitcnt vmcnt(7)" ::: "memory");
  barx();

  for (int t = 0; t < nt; ++t) {
    const int b = t & 1;
    const unsigned short* LA = &lds[b][0];
    const unsigned short* LB = &lds[b][16384];
    const int kA = (t + 2 < nt) ? (t + 2) : (nt - 1);
    bfrag af[4][2], bfr[3][2];

    // ---- ph0: read A m0-3 + B n0-1; MFMA (m-lo, n0-1)
#pragma unroll
    for (int m = 0; m < 4; m++) {
      af[m][0] = RDA(m, 0);
      af[m][1] = RDA(m, 1);
    }
#pragma unroll
    for (int n = 0; n < 2; n++) {
      bfr[n][0] = RDB(n, 0);
      bfr[n][1] = RDB(n, 1);
    }
    barx();
    __builtin_amdgcn_s_setprio(1);
#pragma unroll
    for (int m = 0; m < 4; m++)
#pragma unroll
      for (int n = 0; n < 2; n++) {
        acc[m][n] = __builtin_amdgcn_mfma_f32_16x16x32_bf16(af[m][0], bfr[n][0], acc[m][n], 0, 0, 0);
        acc[m][n] = __builtin_amdgcn_mfma_f32_16x16x32_bf16(af[m][1], bfr[n][1], acc[m][n], 0, 0, 0);
      }
    __builtin_amdgcn_s_setprio(0);
    barx();

    // ---- ph1: read B n2; MFMA (m-lo, n2)
    bfr[2][0] = RDB(2, 0);
    bfr[2][1] = RDB(2, 1);
    barx();
    __builtin_amdgcn_s_setprio(1);
#pragma unroll
    for (int m = 0; m < 4; m++) {
      acc[m][2] = __builtin_amdgcn_mfma_f32_16x16x32_bf16(af[m][0], bfr[2][0], acc[m][2], 0, 0, 0);
      acc[m][2] = __builtin_amdgcn_mfma_f32_16x16x32_bf16(af[m][1], bfr[2][1], acc[m][2], 0, 0, 0);
    }
    __builtin_amdgcn_s_setprio(0);
    barx();

    // ---- ph2: stage t+2 A-Q0,Q2 + B-Q0,Q1; read A m4-7; MFMA (m-hi, n0-1)
    STG_A(b, 0, kA);
    STG_A(b, 2, kA);
    STG_B(b, 0, kA);
    STG_B(b, 1, kA);
#pragma unroll
    for (int m = 0; m < 4; m++) {
      af[m][0] = RDA(m + 4, 0);
      af[m][1] = RDA(m + 4, 1);
    }
    barx();
    __builtin_amdgcn_s_setprio(1);
#pragma unroll
    for (int m = 0; m < 4; m++)
#pragma unroll
      for (int n = 0; n < 2; n++) {
        acc[m + 4][n] = __builtin_amdgcn_mfma_f32_16x16x32_bf16(af[m][0], bfr[n][0], acc[m + 4][n], 0, 0, 0);
        acc[m + 4][n] = __builtin_amdgcn_mfma_f32_16x16x32_bf16(af[m][1], bfr[n][1], acc[m + 4][n], 0, 0, 0);
      }
    __builtin_amdgcn_s_setprio(0);
    barx();

    // ---- ph3: stage t+2 A-Q1,Q3 + B-Q2; MFMA (m-hi, n2); counted vmcnt
    STG_A(b, 1, kA);
    STG_A(b, 3, kA);
    STG_B(b, 2, kA);
    barx();
    __builtin_amdgcn_s_setprio(1);
#pragma unroll
    for (int m = 0; m < 4; m++) {
      acc[m + 4][2] = __builtin_amdgcn_mfma_f32_16x16x32_bf16(af[m][0], bfr[2][0], acc[m + 4][2], 0, 0, 0);
      acc[m + 4][2] = __builtin_amdgcn_mfma_f32_16x16x32_bf16(af[m][1], bfr[2][1], acc[m + 4][2], 0, 0, 0);
    }
    __builtin_amdgcn_s_setprio(0);
    asm volatile("s_waitcnt vmcnt(7)" ::: "memory");
    barx();
  }
  asm volatile("s_waitcnt vmcnt(0)" ::: "memory");

#undef STG_A
#undef STG_B
#undef RDA
#undef RDB

  // ---------- epilogue: stage C bf16 in LDS (stride 200), write coalesced
  const bool is_z = (col0 >= DIN);
  unsigned short* cl = (unsigned short*)&lds[0][0];  // 256*200*2 = 100KB
  barx();  // all fragment reads + stale DMA done (vmcnt(0) above)
#pragma unroll
  for (int m = 0; m < 8; m++) {
    const int rb = wr * 128 + m * 16 + quad * 4;
#pragma unroll
    for (int n = 0; n < 3; n++) {
      const int cc = wc * 48 + n * 16 + l16;
#pragma unroll
      for (int r = 0; r < 4; r++) {
        float v = acc[m][n][r];
        if (is_z) v = v / (1.f + __expf(-v));
        cl[(rb + r) * 200 + cc] = f2bf(v);
      }
    }
  }
  barx();
  unsigned short* dstbase =
      (is_z ? Z : XI) + (size_t)row0 * DIN + (col0 - (is_z ? DIN : 0));
#pragma unroll
  for (int i = 0; i < 12; i++) {
    const int c = tid + i * 512;         // 6144 chunks of 16B
    const int row = c / 24, off = (c % 24) * 8;
    *(uint4*)(dstbase + (size_t)row * DIN + off) =
        *(const uint4*)(cl + row * 200 + off);
  }
}

// ------------------------------------------------------------- bf16 MFMA GEMM
// BK=32, 128x128 tile, swizzled LDS. MODE 0: fp32 C. XCD-swizzled grid.
template <int MODE>
__global__ __launch_bounds__(256) void mfma_gemm(
    const unsigned short* __restrict__ A, const unsigned short* __restrict__ Bt,
    void* __restrict__ C0v, void* __restrict__ C1v, int K, int ldc) {
  __shared__ unsigned short As[128 * 32];
  __shared__ unsigned short Bs[128 * 32];
  const int tid = threadIdx.x;
  const int w = tid >> 6, l = tid & 63;
  const int quad = l >> 4, l16 = l & 15;
  const int wrow = (w >> 1) * 64, wcol = (w & 1) * 64;
  const int h = blockIdx.x + gridDim.x * blockIdx.y;
  const int nb = gridDim.x * gridDim.y;
  int swz = h;
  if ((nb & 7) == 0) swz = (h & 7) * (nb >> 3) + (h >> 3);
  const int row0 = (swz / gridDim.x) * 128, col0 = (swz % gridDim.x) * 128;

  f4 acc[4][4];
#pragma unroll
  for (int i = 0; i < 4; i++)
#pragma unroll
    for (int j = 0; j < 4; j++) acc[i][j] = (f4){0.f, 0.f, 0.f, 0.f};

  const int arow = row0 + w * 16 + (l >> 2);
  const int brow = col0 + w * 16 + (l >> 2);
  const int kcol = (((l & 3) ^ ((l >> 2) & 3)) * 8);  // swizzled chunk
  const int qs = (quad ^ (l16 & 3)) * 8;              // fragment chunk

  for (int k0 = 0; k0 < K; k0 += 32) {
#pragma unroll
    for (int r = 0; r < 2; r++) {
      gld_lds16(A + (size_t)(arow + r * 64) * K + k0 + kcol,
                (char*)As + r * 4096 + w * 1024);
      gld_lds16(Bt + (size_t)(brow + r * 64) * K + k0 + kcol,
                (char*)Bs + r * 4096 + w * 1024);
    }
    __syncthreads();
    bfrag af[4], bf[4];
#pragma unroll
    for (int i = 0; i < 4; i++)
      af[i] = *(const bfrag*)(const void*)(As + (wrow + i * 16 + l16) * 32 + qs);
#pragma unroll
    for (int j = 0; j < 4; j++)
      bf[j] = *(const bfrag*)(const void*)(Bs + (wcol + j * 16 + l16) * 32 + qs);
#pragma unroll
    for (int i = 0; i < 4; i++)
#pragma unroll
      for (int j = 0; j < 4; j++)
        acc[i][j] = __builtin_amdgcn_mfma_f32_16x16x32_bf16(af[i], bf[j], acc[i][j], 0, 0, 0);
    __syncthreads();
  }

  if (MODE == 0) {
    float* C0 = (float*)C0v;
    const int ccol = col0 + wcol + l16;
#pragma unroll
    for (int i = 0; i < 4; i++) {
      const int rb = row0 + wrow + i * 16 + quad * 4;
#pragma unroll
      for (int j = 0; j < 4; j++)
#pragma unroll
        for (int r = 0; r < 4; r++)
          C0[(size_t)(rb + r) * ldc + ccol + j * 16] = acc[i][j][r];
    }
  } else {
    const bool is_z = (col0 >= DIN);
    unsigned short* dst = is_z ? (unsigned short*)C1v : (unsigned short*)C0v;
    const int cbase = col0 + wcol + l16 - (is_z ? DIN : 0);
#pragma unroll
    for (int i = 0; i < 4; i++) {
      const int rb = row0 + wrow + i * 16 + quad * 4;
#pragma unroll
      for (int j = 0; j < 4; j++)
#pragma unroll
        for (int r = 0; r < 4; r++) {
          float v = acc[i][j][r];
          if (is_z) v = v / (1.f + __expf(-v));
          dst[(size_t)(rb + r) * DIN + cbase + j * 16] = f2bf(v);
        }
    }
  }
}

// ------------------- prep1 (1024 thr): sched (block 0) + all flat casts
// SLOT_PACK[slot] = node | ((pnode+1)<<12); SLOTINV[node] = slot.
__global__ __launch_bounds__(1024) void prep1_kernel(
    const int* __restrict__ sidx, const int* __restrict__ spar,
    int* __restrict__ SLOT_PACK, int* __restrict__ SLOTINV,
    int* __restrict__ LSTART, int* __restrict__ NLEV,
    const float* __restrict__ x, unsigned short* __restrict__ Xbf,
    const float* __restrict__ xpw, unsigned short* __restrict__ XPW,
    const float* __restrict__ dtw, unsigned short* __restrict__ DTWb,
    const float* __restrict__ A_log, float* __restrict__ negA) {
  const int bi = blockIdx.x;
  const int tid = threadIdx.x;
  if (bi == 0) {
    __shared__ int par[2048], idx[2048], ancA[2048], ancB[2048], rnkA[2048], rnkB[2048];
    __shared__ int dmax;
    for (int i = tid; i < 2048; i += 1024) {
      const int p = spar[i];
      par[i] = p;
      idx[i] = sidx[i];
      ancA[i] = (p < 0) ? -1 : p;
      rnkA[i] = (p < 0) ? 0 : 1;
    }
    if (tid == 0) dmax = 0;
    __syncthreads();
    for (int r = 0; r < 11; r++) {
      int* ca = (r & 1) ? ancB : ancA;
      int* cr = (r & 1) ? rnkB : rnkA;
      int* na = (r & 1) ? ancA : ancB;
      int* nr = (r & 1) ? rnkA : rnkB;
      for (int i = tid; i < 2048; i += 1024) {
        const int a = ca[i], rv = cr[i];
        if (a >= 0) {
          nr[i] = rv + cr[a];
          na[i] = ca[a];
        } else {
          nr[i] = rv;
          na[i] = a;
        }
      }
      __syncthreads();
    }
    for (int i = tid; i < 2048; i += 1024) ancA[i] = 0;
    __syncthreads();
    for (int i = tid; i < 2048; i += 1024) {
      atomicAdd(&ancA[rnkB[i]], 1);
      atomicMax(&dmax, rnkB[i]);
    }
    __syncthreads();
    for (int s = 0; s < 11; s++) {
      const int off = 1 << s;
      int* cur = (s & 1) ? ancB : ancA;
      int* nxt = (s & 1) ? ancA : ancB;
      for (int i = tid; i < 2048; i += 1024) {
        int v = cur[i];
        if (i >= off) v += cur[i - off];
        nxt[i] = v;
      }
      __syncthreads();
    }
    for (int i = tid; i < 2049; i += 1024) {
      const int v = (i == 0) ? 0 : ancB[i - 1];
      LSTART[i] = v;
      if (i < 2048) rnkA[i] = v;
    }
    if (tid == 0) NLEV[0] = dmax + 1;
    __syncthreads();
    for (int i = tid; i < 2048; i += 1024) {
      const int d = rnkB[i];
      const int slot = atomicAdd(&rnkA[d], 1);
      const int node = idx[i];
      const int p = par[i];
      const int pn = (p < 0) ? -1 : idx[p];
      SLOT_PACK[slot] = node | ((pn + 1) << 12);
      SLOTINV[node] = slot;
    }
  } else if (bi < 1 + 1536) {
    const int i = ((bi - 1) * 1024 + tid) * 4;
    const float4 v = *(const float4*)(x + i);
    union { unsigned short h[4]; uint2 u; } pk;
    pk.h[0] = f2bf(v.x);
    pk.h[1] = f2bf(v.y);
    pk.h[2] = f2bf(v.z);
    pk.h[3] = f2bf(v.w);
    *(uint2*)(Xbf + i) = pk.u;
  } else if (bi < 1 + 1536 + 96) {
    const int i = (bi - 1537) * 1024 + tid;  // 64*1536
    const int c = i / 1536, k = i % 1536;
    XPW[i] = (c < 50) ? f2bf(xpw[(size_t)k * 50 + c]) : (unsigned short)0;
  } else if (bi < 1 + 1536 + 96 + 96) {
    const int i = (bi - 1633) * 1024 + tid;  // 1536*64
    const int d = i >> 6, k = i & 63;
    DTWb[i] = (k < 48) ? f2bf(dtw[(size_t)k * DIN + d]) : (unsigned short)0;
  } else {
    const int i = (bi - 1729) * 1024 + tid;
    if (i < DIN) negA[i] = -__expf(A_log[i]);
  }
}

// ------------------- prep2 (256 thr): both weight transposes, fp32 -> bf16^T
__global__ __launch_bounds__(256) void prep2_kernel(
    const float* __restrict__ W1, unsigned short* __restrict__ W1t,
    const float* __restrict__ W2, unsigned short* __restrict__ W2t) {
  __shared__ float t[32][33];
  int idx = blockIdx.x;
  const float* W;
  unsigned short* Wt;
  int K, N, n0, k0;
  if (idx < 2304) {  // in_proj: K=768, N=3072 -> 96x24 tiles
    W = W1; Wt = W1t; K = DMOD; N = 2 * DIN;
    n0 = (idx % 96) * 32; k0 = (idx / 96) * 32;
  } else {           // out_proj: K=1536, N=768 -> 24x48 tiles
    idx -= 2304;
    W = W2; Wt = W2t; K = DIN; N = DMOD;
    n0 = (idx % 24) * 32; k0 = (idx / 24) * 32;
  }
  const int tx = threadIdx.x & 31, ty = threadIdx.x >> 5;
  for (int i = ty; i < 32; i += 8) t[i][tx] = W[(size_t)(k0 + i) * N + n0 + tx];
  __syncthreads();
  for (int i = ty; i < 32; i += 8)
    Wt[(size_t)(n0 + i) * K + k0 + tx] = f2bf(t[tx][i]);
}

// ------------------------------------------------- x_dbl: split-K bf16 MFMA
__global__ __launch_bounds__(256) void xdbl_mfma(
    const unsigned short* __restrict__ XI, const unsigned short* __restrict__ XPW,
    float* __restrict__ XP) {
  __shared__ unsigned short As[128 * 32];
  __shared__ unsigned short Bs[64 * 32];
  const int tid = threadIdx.x;
  const int w = tid >> 6, l = tid & 63;
  const int quad = l >> 4, l16 = l & 15;
  // XCD swizzle: 256 blocks; XCD k gets y in [8k,8k+8) with all 4 splits.
  const int h = blockIdx.x + 4 * blockIdx.y;
  const int swz = (h & 7) * 32 + (h >> 3);
  const int split = swz & 3;
  const int row0 = (swz >> 2) * 128;
  const int kbase = split * (DIN / NSPLIT);  // 384

  f4 acc[2][4];
#pragma unroll
  for (int i = 0; i < 2; i++)
#pragma unroll
    for (int j = 0; j < 4; j++) acc[i][j] = (f4){0.f, 0.f, 0.f, 0.f};

  const int srow = w * 16 + (l >> 2);
  const int kcol = (((l & 3) ^ ((l >> 2) & 3)) * 8);
  const int qs = (quad ^ (l16 & 3)) * 8;

  for (int c = 0; c < 12; c++) {
    const int k0 = kbase + c * 32;
#pragma unroll
    for (int r = 0; r < 2; r++) {
      gld_lds16(XI + (size_t)(row0 + srow + r * 64) * DIN + k0 + kcol,
                (char*)As + r * 4096 + w * 1024);
    }
    gld_lds16(XPW + (size_t)srow * DIN + k0 + kcol, (char*)Bs + w * 1024);
    __syncthreads();
    bfrag af[2], bf[4];
#pragma unroll
    for (int i = 0; i < 2; i++)
      af[i] = *(const bfrag*)(const void*)(As + (w * 32 + i * 16 + l16) * 32 + qs);
#pragma unroll
    for (int j = 0; j < 4; j++)
      bf[j] = *(const bfrag*)(const void*)(Bs + (j * 16 + l16) * 32 + qs);
#pragma unroll
    for (int i = 0; i < 2; i++)
#pragma unroll
      for (int j = 0; j < 4; j++)
        acc[i][j] = __builtin_amdgcn_mfma_f32_16x16x32_bf16(af[i], bf[j], acc[i][j], 0, 0, 0);
    __syncthreads();
  }

  float* dst = XP + (size_t)split * ROWS * 64 + (size_t)row0 * 64;
#pragma unroll
  for (int i = 0; i < 2; i++) {
    const int rb = w * 32 + i * 16 + quad * 4;
#pragma unroll
    for (int j = 0; j < 4; j++) {
      const int col = j * 16 + l16;
#pragma unroll
      for (int r = 0; r < 4; r++) dst[(size_t)(rb + r) * 64 + col] = acc[i][j][r];
    }
  }
}

// -------------------------- reduce XP partials -> DTLRb bf16 + BC/CC fp32
__global__ __launch_bounds__(256) void xp_reduce(
    const float* __restrict__ XP, unsigned short* __restrict__ DTLRb,
    float* __restrict__ BCv, float* __restrict__ CCv) {
  const int i = blockIdx.x * 256 + threadIdx.x;  // 8192*16
  const int row = i >> 4, c4 = (i & 15) * 4;
  const float* p = XP + (size_t)row * 64 + c4;
  float4 s = make_float4(0.f, 0.f, 0.f, 0.f);
#pragma unroll
  for (int sp = 0; sp < NSPLIT; sp++) {
    const float4 v = *(const float4*)(p + (size_t)sp * ROWS * 64);
    s.x += v.x;
    s.y += v.y;
    s.z += v.z;
    s.w += v.w;
  }
  if (c4 == 48) {
    BCv[row] = s.x;
    CCv[row] = s.y;
  }
  union { unsigned short h[4]; uint2 u; } pk;
  pk.h[0] = f2bf(s.x);
  pk.h[1] = f2bf(s.y);
  pk.h[2] = f2bf(s.z);
  pk.h[3] = f2bf(s.w);
  *(uint2*)(DTLRb + (size_t)row * 64 + c4) = pk.u;
}

// ------- dt GEMM (K=64) -> dA/dBx bf16, rows permuted to slot order.
// grid (12, 128). 64 rows x 128 cols per block.
__global__ __launch_bounds__(256) void dt_gemm(
    const unsigned short* __restrict__ DTLRb, const unsigned short* __restrict__ DTWb,
    const float* __restrict__ bias, const float* __restrict__ negA,
    const float* __restrict__ BCv, const unsigned short* __restrict__ XI,
    const int* __restrict__ SLOTINV,
    unsigned short* __restrict__ DAp, unsigned short* __restrict__ DBXp) {
  __shared__ unsigned short As[2][64 * 32];
  __shared__ unsigned short Bs[2][128 * 32];
  __shared__ int sinv[64];
  __shared__ float bcs[64];
  const int tid = threadIdx.x;
  const int w = tid >> 6, l = tid & 63;
  const int quad = l >> 4, l16 = l & 15;
  const int wrow = (w >> 1) * 32, wcol = (w & 1) * 64;
  const int row0 = blockIdx.y * 64, col0 = blockIdx.x * 128;
  const int p0 = row0 & (NSEQ - 1);       // position base (batch-local)
  const int bbase = row0 & ~(NSEQ - 1);   // b*2048
  const int srow = w * 16 + (l >> 2);
  const int koff = (((l & 3) ^ ((l >> 2) & 3)) * 8);
  const int qs = (quad ^ (l16 & 3)) * 8;

#pragma unroll
  for (int c = 0; c < 2; c++) {
    gld_lds16(DTLRb + (size_t)(row0 + srow) * 64 + c * 32 + koff,
              (char*)As[c] + w * 1024);
#pragma unroll
    for (int r = 0; r < 2; r++)
      gld_lds16(DTWb + (size_t)(col0 + srow + r * 64) * 64 + c * 32 + koff,
                (char*)Bs[c] + r * 4096 + w * 1024);
  }
  if (tid < 64) {
    sinv[tid] = SLOTINV[p0 + tid];
    bcs[tid] = BCv[row0 + tid];
  }
  __syncthreads();

  f4 acc[2][4];
#pragma unroll
  for (int i = 0; i < 2; i++)
#pragma unroll
    for (int j = 0; j < 4; j++) acc[i][j] = (f4){0.f, 0.f, 0.f, 0.f};

#pragma unroll
  for (int c = 0; c < 2; c++) {
    bfrag af[2], bf[4];
#pragma unroll
    for (int i = 0; i < 2; i++)
      af[i] = *(const bfrag*)(const void*)(As[c] + (wrow + i * 16 + l16) * 32 + qs);
#pragma unroll
    for (int j = 0; j < 4; j++)
      bf[j] = *(const bfrag*)(const void*)(Bs[c] + (wcol + j * 16 + l16) * 32 + qs);
#pragma unroll
    for (int i = 0; i < 2; i++)
#pragma unroll
      for (int j = 0; j < 4; j++)
        acc[i][j] = __builtin_amdgcn_mfma_f32_16x16x32_bf16(af[i], bf[j], acc[i][j], 0, 0, 0);
  }

  float bj[4], aj[4];
#pragma unroll
  for (int j = 0; j < 4; j++) {
    const int d = col0 + wcol + j * 16 + l16;
    bj[j] = bias[d];
    aj[j] = negA[d];
  }
#pragma unroll
  for (int i = 0; i < 2; i++) {
#pragma unroll
    for (int r = 0; r < 4; r++) {
      const int row_l = wrow + i * 16 + quad * 4 + r;
      const int row = row0 + row_l;
      const float bc = bcs[row_l];
      const size_t rp = (size_t)(bbase + sinv[row_l]) * DIN;
#pragma unroll
      for (int j = 0; j < 4; j++) {
        const int d = col0 + wcol + j * 16 + l16;
        const float s = acc[i][j][r] + bj[j];
        const float sp = fmaxf(s, 0.f) + __logf(1.f + __expf(-fabsf(s)));
        const float xi = bf2f(XI[(size_t)row * DIN + d]);
        DAp[rp + d] = f2bf(__expf(sp * aj[j]));
        DBXp[rp + d] = f2bf(sp * bc * xi);
      }
    }
  }
}

// ----------------- tree recurrence: h resident in LDS, slot-ordered loads
// block owns 16 bf16 columns (2 chunks of 8); h[node][16] in LDS (64KB).
__global__ __launch_bounds__(256) void recur_kernel(
    const unsigned short* __restrict__ DAp, const unsigned short* __restrict__ DBXp,
    unsigned short* __restrict__ Hb,
    const int* __restrict__ SLOT_PACK, const int* __restrict__ LSTART,
    const int* __restrict__ NLEV) {
  __shared__ unsigned short hl[NSEQ * 16];  // 64 KB
  __shared__ int spack[NSEQ];               // 8 KB
  __shared__ int lst[258];                  // ~1 KB
  const int tid = threadIdx.x;
  const int c8a = blockIdx.x * 2;           // both chunks in same batch
  const int b = c8a / 192;
  const int d8a = c8a % 192;
  const int nlev = NLEV[0];
  for (int i = tid; i < NSEQ; i += 256) spack[i] = SLOT_PACK[i];
  const int nl = (nlev + 1 < 258) ? nlev + 1 : 258;
  for (int i = tid; i < nl; i += 256) lst[i] = LSTART[i];
  __syncthreads();

  for (int L = 0; L < nlev; L++) {
    const int s0 = (L < 257) ? lst[L] : LSTART[L];
    const int s1 = (L + 1 < 258) ? lst[L + 1] : LSTART[L + 1];
    const int items = (s1 - s0) * 2;
    for (int it = tid; it < items; it += 256) {
      const int s = s0 + (it >> 1);
      const int ch = it & 1;
      const size_t goff = (size_t)(b * NSEQ + s) * DIN + (d8a + ch) * 8;
      union { uint4 u; unsigned short h[8]; } da, dbx, hpu, hvu;
      da.u = *(const uint4*)(DAp + goff);
      dbx.u = *(const uint4*)(DBXp + goff);
      const int pk = spack[s];
      const int node = pk & 4095;
      const int pn = (pk >> 12) - 1;
      float hp[8];
      if (pn >= 0) {
        hpu.u = *(const uint4*)(hl + pn * 16 + ch * 8);
#pragma unroll
        for (int e = 0; e < 8; e++) hp[e] = bf2f(hpu.h[e]);
      } else {
#pragma unroll
        for (int e = 0; e < 8; e++) hp[e] = 0.f;
      }
#pragma unroll
      for (int e = 0; e < 8; e++) {
        const float hv = fmaf(bf2f(da.h[e]), hp[e], bf2f(dbx.h[e]));
        hvu.h[e] = f2bf(hv);
      }
      *(uint4*)(hl + node * 16 + ch * 8) = hvu.u;
    }
    __syncthreads();
  }

  // flush h to global (node-major for ln)
  for (int i = tid; i < NSEQ * 2; i += 256) {
    const int node = i >> 1, ch = i & 1;
    *(uint4*)(Hb + (size_t)(b * NSEQ + node) * DIN + (d8a + ch) * 8) =
        *(const uint4*)(hl + node * 16 + ch * 8);
  }
}

// --------------------------------------------- y, layernorm, z-gate -> bf16
__global__ __launch_bounds__(256) void ln_kernel(
    const unsigned short* __restrict__ Hb, const float* __restrict__ CCv,
    const unsigned short* __restrict__ XI, const float* __restrict__ Dp,
    const float* __restrict__ gamma, const float* __restrict__ beta,
    const unsigned short* __restrict__ Z, unsigned short* __restrict__ YLN) {
  const int row = blockIdx.x;
  const int tid = threadIdx.x;
  const float C = CCv[row];
  const unsigned short* hrow = Hb + (size_t)row * DIN;
  const unsigned short* xrow = XI + (size_t)row * DIN;
  float y[6];
  float s = 0.f, s2 = 0.f;
#pragma unroll
  for (int i = 0; i < 6; i++) {
    const int d = tid + i * 256;
    const float v = fmaf(bf2f(hrow[d]), C, Dp[d] * bf2f(xrow[d]));
    y[i] = v;
    s += v;
    s2 = fmaf(v, v, s2);
  }
#pragma unroll
  for (int off = 32; off >= 1; off >>= 1) {
    s += __shfl_down(s, off);
    s2 += __shfl_down(s2, off);
  }
  __shared__ float rs[4], rs2[4];
  const int w = tid >> 6;
  if ((tid & 63) == 0) {
    rs[w] = s;
    rs2[w] = s2;
  }
  __syncthreads();
  const float ts = rs[0] + rs[1] + rs[2] + rs[3];
  const float ts2 = rs2[0] + rs2[1] + rs2[2] + rs2[3];
  const float mu = ts * (1.f / 1536.f);
  const float var = ts2 * (1.f / 1536.f) - mu * mu;
  const float inv = rsqrtf(var + 1e-5f);
  unsigned short* yrow = YLN + (size_t)row * DIN;
  const unsigned short* zrow = Z + (size_t)row * DIN;
#pragma unroll
  for (int i = 0; i < 6; i++) {
    const int d = tid + i * 256;
    const float o = (y[i] - mu) * inv * gamma[d] + beta[d];
    yrow[d] = f2bf(o * bf2f(zrow[d]));
  }
}

// ---------------------------------------------------------------------- launch
extern "C" void kernel_launch(void* const* d_in, const int* in_sizes, int n_in,
                              void* d_out, int out_size, void* d_ws, size_t ws_size,
                              hipStream_t stream) {
  const float* x = (const float*)d_in[0];
  const int* sidx = (const int*)d_in[1];
  const int* spar = (const int*)d_in[2];
  const float* in_proj = (const float*)d_in[3];
  const float* x_proj = (const float*)d_in[4];
  const float* dt_proj = (const float*)d_in[5];
  const float* dt_b = (const float*)d_in[6];
  const float* A_log = (const float*)d_in[7];
  const float* Dp = (const float*)d_in[8];
  const float* gamma = (const float*)d_in[9];
  const float* beta = (const float*)d_in[10];
  const float* out_proj = (const float*)d_in[11];
  float* out = (float*)d_out;

  char* p = (char*)d_ws;
  const size_t RC = (size_t)ROWS * DIN;
  unsigned short* XI = (unsigned short*)p;   p += RC * 2;   // 25.2 MB
  unsigned short* Z = (unsigned short*)p;    p += RC * 2;   // 25.2 MB
  unsigned short* DAp = (unsigned short*)p;  p += RC * 2;   // 25.2 MB
  unsigned short* DBXp = (unsigned short*)p; p += RC * 2;   // 25.2 MB
  unsigned short* Hb = (unsigned short*)p;   p += RC * 2;   // 25.2 MB
  float* XP = (float*)p;                     p += (size_t)NSPLIT * ROWS * 64 * 4;  // 8.4 MB
  unsigned short* DTLRb = (unsigned short*)p; p += (size_t)ROWS * 64 * 2;          // 1 MB
  float* BCv = (float*)p;                    p += ROWS * 4;
  float* CCv = (float*)p;                    p += ROWS * 4;
  float* negA = (float*)p;                   p += DIN * 4;
  unsigned short* Xbf = (unsigned short*)p;  p += (size_t)ROWS * DMOD * 2;         // 12.6 MB
  unsigned short* W1t = (unsigned short*)p;  p += (size_t)2 * DIN * DMOD * 2;      // 4.7 MB
  unsigned short* W2t = (unsigned short*)p;  p += (size_t)DMOD * DIN * 2;          // 2.4 MB
  unsigned short* XPW = (unsigned short*)p;  p += (size_t)64 * DIN * 2;
  unsigned short* DTWb = (unsigned short*)p; p += (size_t)DIN * 64 * 2;
  int* ipart = (int*)p;
  int* SLOT_PACK = ipart;
  int* SLOTINV = ipart + 2048;
  int* LSTART = ipart + 4096;
  int* NLEV = ipart + 4096 + 2049;
  unsigned short* YLN = DAp;  // DAp dead after recur; reuse for LN output

  prep1_kernel<<<1731, 1024, 0, stream>>>(sidx, spar, SLOT_PACK, SLOTINV,
                                          LSTART, NLEV, x, Xbf, x_proj, XPW,
                                          dt_proj, DTWb, A_log, negA);
  prep2_kernel<<<3456, 256, 0, stream>>>(in_proj, W1t, out_proj, W2t);
  gemm256_silu<<<dim3(16, 32), 512, 0, stream>>>(Xbf, W1t, XI, Z, DMOD);
  xdbl_mfma<<<dim3(NSPLIT, 64), 256, 0, stream>>>(XI, XPW, XP);
  xp_reduce<<<ROWS * 16 / 256, 256, 0, stream>>>(XP, DTLRb, BCv, CCv);
  dt_gemm<<<dim3(12, 128), 256, 0, stream>>>(DTLRb, DTWb, dt_b, negA, BCv, XI,
                                             SLOTINV, DAp, DBXp);
  recur_kernel<<<384, 256, 0, stream>>>(DAp, DBXp, Hb, SLOT_PACK, LSTART, NLEV);
  ln_kernel<<<ROWS, 256, 0, stream>>>(Hb, CCv, XI, Dp, gamma, beta, Z, YLN);
  mfma_gemm<0><<<dim3(6, 64), 256, 0, stream>>>(YLN, W2t, out, nullptr, DIN, DMOD);
}

// Round 7
// 305.261 us; speedup vs baseline: 1.0724x; 1.0156x over previous
//
#include <hip/hip_runtime.h>
#include <math.h>

// TreeMambaLayer: B=4, N=2048, D_MODEL=768, D_INNER=1536, DT_RANK=48
// Round 15: gemm256 -> revert LDS epilogue (R6: WRITE was already ideal,
// staging cost +2us); merge 4 phases -> 2 (8 -> 4 barriers/tile, same
// staging liveness, vmcnt(7) unchanged); + XCD swizzle on dt_gemm.

#define ROWS 8192
#define DIN 1536
#define DMOD 768
#define NSEQ 2048
#define DTR 48
#define NSPLIT 4

typedef __bf16 bfrag __attribute__((ext_vector_type(8)));
typedef float f4 __attribute__((ext_vector_type(4)));

__device__ __forceinline__ unsigned short f2bf(float f) {
  unsigned int u = __float_as_uint(f);
  unsigned int r = (u + 0x7fffu + ((u >> 16) & 1u)) >> 16;
  return (unsigned short)r;
}
__device__ __forceinline__ float bf2f(unsigned short h) {
  return __uint_as_float(((unsigned int)h) << 16);
}

__device__ __forceinline__ void gld_lds16(const void* g, void* l) {
  __builtin_amdgcn_global_load_lds((const __attribute__((address_space(1))) void*)g,
                                   (__attribute__((address_space(3))) void*)l, 16, 0, 0);
}

// raw barrier: no vmcnt drain; compiler-level memory fence only.
__device__ __forceinline__ void barx() {
  asm volatile("" ::: "memory");
  __builtin_amdgcn_s_barrier();
  asm volatile("" ::: "memory");
}

// ---------------- 256x192 2-phase bf16 GEMM, C = A(MxK) * Bt(NxK)^T
// cols < DIN -> XI bf16; cols >= DIN -> Z = silu, bf16.
// 8 waves (2M x 4N), per-wave 128x48 out. BK=64, LDS 112KB dbuf.
// P0: read A-lo + all B -> MFMA m-lo x n0-2 (24/wave).
// P1: read A-hi, stage t+2 {A-Q0,Q2,B-Q0..2} -> bar -> stage {A-Q1,Q3}
//     -> MFMA m-hi x n0-2 -> vmcnt(7) -> bar.
// Liveness: A-Q0/Q2 + all B consumed in P0; A-Q1/Q3 consumed by P1 reads
// (mid-barrier guards them). vmcnt(7): waits only tile t+1's 7 loads.
__global__ __launch_bounds__(512, 1) void gemm256_silu(
    const unsigned short* __restrict__ A, const unsigned short* __restrict__ Bt,
    unsigned short* __restrict__ XI, unsigned short* __restrict__ Z, int K) {
  __shared__ unsigned short lds[2][(256 + 192) * 64];  // 112KB
  const int tid = threadIdx.x;
  const int w = tid >> 6, l = tid & 63;
  const int quad = l >> 4, l16 = l & 15;
  const int wr = w >> 2, wc = w & 3;
  // XCD swizzle: 512 blocks, XCD k owns logical ids [64k,64k+64) = 4 full
  // A-row-panels (16 col-sharers each -> same XCD L2).
  const int h = blockIdx.x + 16 * blockIdx.y;
  const int swz = (h & 7) * 64 + (h >> 3);
  const int row0 = (swz >> 4) * 256, col0 = (swz & 15) * 192;
  const int nt = K >> 6;

  const int srow = tid >> 3;
  const int schunk = ((tid & 7) ^ (srow & 7)) * 8;
  const unsigned short* aS = A + (size_t)(row0 + srow) * K + schunk;
  const unsigned short* bS = Bt + (size_t)(col0 + srow) * K + schunk;

#define STG_A(bufi, q, kt)                                     \
  gld_lds16(aS + (size_t)((q) * 64) * K + (size_t)(kt) * 64,   \
            (char*)&lds[bufi][(q) * 4096] + w * 1024)
#define STG_B(bufi, q, kt)                                     \
  gld_lds16(bS + (size_t)((q) * 64) * K + (size_t)(kt) * 64,   \
            (char*)&lds[bufi][16384 + (q) * 4096] + w * 1024)

  const int arow = (wr * 128 + l16) * 64;
  const int brow = (wc * 48 + l16) * 64;
  int cs[2];
  cs[0] = (quad ^ (l16 & 7)) * 8;
  cs[1] = ((4 + quad) ^ (l16 & 7)) * 8;

#define RDA(m, ks) (*(const bfrag*)(const void*)(LA + arow + (m) * 1024 + cs[ks]))
#define RDB(n, ks) (*(const bfrag*)(const void*)(LB + brow + (n) * 1024 + cs[ks]))

  f4 acc[8][3];
#pragma unroll
  for (int m = 0; m < 8; m++)
#pragma unroll
    for (int n = 0; n < 3; n++) acc[m][n] = (f4){0.f, 0.f, 0.f, 0.f};

  const int kt1 = (nt > 1) ? 1 : 0;
#pragma unroll
  for (int q = 0; q < 4; q++) STG_A(0, q, 0);
#pragma unroll
  for (int q = 0; q < 3; q++) STG_B(0, q, 0);
#pragma unroll
  for (int q = 0; q < 4; q++) STG_A(1, q, kt1);
#pragma unroll
  for (int q = 0; q < 3; q++) STG_B(1, q, kt1);
  asm volatile("s_waitcnt vmcnt(7)" ::: "memory");
  barx();

  for (int t = 0; t < nt; ++t) {
    const int b = t & 1;
    const unsigned short* LA = &lds[b][0];
    const unsigned short* LB = &lds[b][16384];
    const int kA = (t + 2 < nt) ? (t + 2) : (nt - 1);
    bfrag af[4][2], bfr[3][2];

    // ---- P0: read A m0-3 + B n0-2; MFMA (m-lo, all n)
#pragma unroll
    for (int m = 0; m < 4; m++) {
      af[m][0] = RDA(m, 0);
      af[m][1] = RDA(m, 1);
    }
#pragma unroll
    for (int n = 0; n < 3; n++) {
      bfr[n][0] = RDB(n, 0);
      bfr[n][1] = RDB(n, 1);
    }
    barx();
    __builtin_amdgcn_s_setprio(1);
#pragma unroll
    for (int m = 0; m < 4; m++)
#pragma unroll
      for (int n = 0; n < 3; n++) {
        acc[m][n] = __builtin_amdgcn_mfma_f32_16x16x32_bf16(af[m][0], bfr[n][0], acc[m][n], 0, 0, 0);
        acc[m][n] = __builtin_amdgcn_mfma_f32_16x16x32_bf16(af[m][1], bfr[n][1], acc[m][n], 0, 0, 0);
      }
    __builtin_amdgcn_s_setprio(0);
    barx();

    // ---- P1: read A m4-7; stage t+2 A-Q0,Q2 + B (consumed in P0)
#pragma unroll
    for (int m = 0; m < 4; m++) {
      af[m][0] = RDA(m + 4, 0);
      af[m][1] = RDA(m + 4, 1);
    }
    STG_A(b, 0, kA);
    STG_A(b, 2, kA);
    STG_B(b, 0, kA);
    STG_B(b, 1, kA);
    STG_B(b, 2, kA);
    barx();  // all waves' A-hi reads done -> Q1/Q3 stage safe
    STG_A(b, 1, kA);
    STG_A(b, 3, kA);
    __builtin_amdgcn_s_setprio(1);
#pragma unroll
    for (int m = 0; m < 4; m++)
#pragma unroll
      for (int n = 0; n < 3; n++) {
        acc[m + 4][n] = __builtin_amdgcn_mfma_f32_16x16x32_bf16(af[m][0], bfr[n][0], acc[m + 4][n], 0, 0, 0);
        acc[m + 4][n] = __builtin_amdgcn_mfma_f32_16x16x32_bf16(af[m][1], bfr[n][1], acc[m + 4][n], 0, 0, 0);
      }
    __builtin_amdgcn_s_setprio(0);
    // tile t+1's 7 loads (issued one full tile ago) must be landed;
    // tile t+2's 7 (issued this tile) stay in flight.
    asm volatile("s_waitcnt vmcnt(7)" ::: "memory");
    barx();
  }
  asm volatile("s_waitcnt vmcnt(0)" ::: "memory");

#undef STG_A
#undef STG_B
#undef RDA
#undef RDB

  // epilogue: direct stores (WRITE_SIZE already ideal; R6's LDS staging
  // regressed -2us + bank conflicts)
  const bool is_z = (col0 >= DIN);
  unsigned short* dst = is_z ? Z : XI;
  const int cb = col0 + wc * 48 + l16 - (is_z ? DIN : 0);
#pragma unroll
  for (int m = 0; m < 8; m++) {
    const int rb = row0 + wr * 128 + m * 16 + quad * 4;
#pragma unroll
    for (int n = 0; n < 3; n++)
#pragma unroll
      for (int r = 0; r < 4; r++) {
        float v = acc[m][n][r];
        if (is_z) v = v / (1.f + __expf(-v));
        dst[(size_t)(rb + r) * DIN + cb + n * 16] = f2bf(v);
      }
  }
}

// ------------------------------------------------------------- bf16 MFMA GEMM
// BK=32, 128x128 tile, swizzled LDS. MODE 0: fp32 C. XCD-swizzled grid.
template <int MODE>
__global__ __launch_bounds__(256) void mfma_gemm(
    const unsigned short* __restrict__ A, const unsigned short* __restrict__ Bt,
    void* __restrict__ C0v, void* __restrict__ C1v, int K, int ldc) {
  __shared__ unsigned short As[128 * 32];
  __shared__ unsigned short Bs[128 * 32];
  const int tid = threadIdx.x;
  const int w = tid >> 6, l = tid & 63;
  const int quad = l >> 4, l16 = l & 15;
  const int wrow = (w >> 1) * 64, wcol = (w & 1) * 64;
  const int h = blockIdx.x + gridDim.x * blockIdx.y;
  const int nb = gridDim.x * gridDim.y;
  int swz = h;
  if ((nb & 7) == 0) swz = (h & 7) * (nb >> 3) + (h >> 3);
  const int row0 = (swz / gridDim.x) * 128, col0 = (swz % gridDim.x) * 128;

  f4 acc[4][4];
#pragma unroll
  for (int i = 0; i < 4; i++)
#pragma unroll
    for (int j = 0; j < 4; j++) acc[i][j] = (f4){0.f, 0.f, 0.f, 0.f};

  const int arow = row0 + w * 16 + (l >> 2);
  const int brow = col0 + w * 16 + (l >> 2);
  const int kcol = (((l & 3) ^ ((l >> 2) & 3)) * 8);  // swizzled chunk
  const int qs = (quad ^ (l16 & 3)) * 8;              // fragment chunk

  for (int k0 = 0; k0 < K; k0 += 32) {
#pragma unroll
    for (int r = 0; r < 2; r++) {
      gld_lds16(A + (size_t)(arow + r * 64) * K + k0 + kcol,
                (char*)As + r * 4096 + w * 1024);
      gld_lds16(Bt + (size_t)(brow + r * 64) * K + k0 + kcol,
                (char*)Bs + r * 4096 + w * 1024);
    }
    __syncthreads();
    bfrag af[4], bf[4];
#pragma unroll
    for (int i = 0; i < 4; i++)
      af[i] = *(const bfrag*)(const void*)(As + (wrow + i * 16 + l16) * 32 + qs);
#pragma unroll
    for (int j = 0; j < 4; j++)
      bf[j] = *(const bfrag*)(const void*)(Bs + (wcol + j * 16 + l16) * 32 + qs);
#pragma unroll
    for (int i = 0; i < 4; i++)
#pragma unroll
      for (int j = 0; j < 4; j++)
        acc[i][j] = __builtin_amdgcn_mfma_f32_16x16x32_bf16(af[i], bf[j], acc[i][j], 0, 0, 0);
    __syncthreads();
  }

  if (MODE == 0) {
    float* C0 = (float*)C0v;
    const int ccol = col0 + wcol + l16;
#pragma unroll
    for (int i = 0; i < 4; i++) {
      const int rb = row0 + wrow + i * 16 + quad * 4;
#pragma unroll
      for (int j = 0; j < 4; j++)
#pragma unroll
        for (int r = 0; r < 4; r++)
          C0[(size_t)(rb + r) * ldc + ccol + j * 16] = acc[i][j][r];
    }
  } else {
    const bool is_z = (col0 >= DIN);
    unsigned short* dst = is_z ? (unsigned short*)C1v : (unsigned short*)C0v;
    const int cbase = col0 + wcol + l16 - (is_z ? DIN : 0);
#pragma unroll
    for (int i = 0; i < 4; i++) {
      const int rb = row0 + wrow + i * 16 + quad * 4;
#pragma unroll
      for (int j = 0; j < 4; j++)
#pragma unroll
        for (int r = 0; r < 4; r++) {
          float v = acc[i][j][r];
          if (is_z) v = v / (1.f + __expf(-v));
          dst[(size_t)(rb + r) * DIN + cbase + j * 16] = f2bf(v);
        }
    }
  }
}

// ------------------- prep1 (1024 thr): sched (block 0) + all flat casts
// SLOT_PACK[slot] = node | ((pnode+1)<<12); SLOTINV[node] = slot.
__global__ __launch_bounds__(1024) void prep1_kernel(
    const int* __restrict__ sidx, const int* __restrict__ spar,
    int* __restrict__ SLOT_PACK, int* __restrict__ SLOTINV,
    int* __restrict__ LSTART, int* __restrict__ NLEV,
    const float* __restrict__ x, unsigned short* __restrict__ Xbf,
    const float* __restrict__ xpw, unsigned short* __restrict__ XPW,
    const float* __restrict__ dtw, unsigned short* __restrict__ DTWb,
    const float* __restrict__ A_log, float* __restrict__ negA) {
  const int bi = blockIdx.x;
  const int tid = threadIdx.x;
  if (bi == 0) {
    __shared__ int par[2048], idx[2048], ancA[2048], ancB[2048], rnkA[2048], rnkB[2048];
    __shared__ int dmax;
    for (int i = tid; i < 2048; i += 1024) {
      const int p = spar[i];
      par[i] = p;
      idx[i] = sidx[i];
      ancA[i] = (p < 0) ? -1 : p;
      rnkA[i] = (p < 0) ? 0 : 1;
    }
    if (tid == 0) dmax = 0;
    __syncthreads();
    for (int r = 0; r < 11; r++) {
      int* ca = (r & 1) ? ancB : ancA;
      int* cr = (r & 1) ? rnkB : rnkA;
      int* na = (r & 1) ? ancA : ancB;
      int* nr = (r & 1) ? rnkA : rnkB;
      for (int i = tid; i < 2048; i += 1024) {
        const int a = ca[i], rv = cr[i];
        if (a >= 0) {
          nr[i] = rv + cr[a];
          na[i] = ca[a];
        } else {
          nr[i] = rv;
          na[i] = a;
        }
      }
      __syncthreads();
    }
    for (int i = tid; i < 2048; i += 1024) ancA[i] = 0;
    __syncthreads();
    for (int i = tid; i < 2048; i += 1024) {
      atomicAdd(&ancA[rnkB[i]], 1);
      atomicMax(&dmax, rnkB[i]);
    }
    __syncthreads();
    for (int s = 0; s < 11; s++) {
      const int off = 1 << s;
      int* cur = (s & 1) ? ancB : ancA;
      int* nxt = (s & 1) ? ancA : ancB;
      for (int i = tid; i < 2048; i += 1024) {
        int v = cur[i];
        if (i >= off) v += cur[i - off];
        nxt[i] = v;
      }
      __syncthreads();
    }
    for (int i = tid; i < 2049; i += 1024) {
      const int v = (i == 0) ? 0 : ancB[i - 1];
      LSTART[i] = v;
      if (i < 2048) rnkA[i] = v;
    }
    if (tid == 0) NLEV[0] = dmax + 1;
    __syncthreads();
    for (int i = tid; i < 2048; i += 1024) {
      const int d = rnkB[i];
      const int slot = atomicAdd(&rnkA[d], 1);
      const int node = idx[i];
      const int p = par[i];
      const int pn = (p < 0) ? -1 : idx[p];
      SLOT_PACK[slot] = node | ((pn + 1) << 12);
      SLOTINV[node] = slot;
    }
  } else if (bi < 1 + 1536) {
    const int i = ((bi - 1) * 1024 + tid) * 4;
    const float4 v = *(const float4*)(x + i);
    union { unsigned short h[4]; uint2 u; } pk;
    pk.h[0] = f2bf(v.x);
    pk.h[1] = f2bf(v.y);
    pk.h[2] = f2bf(v.z);
    pk.h[3] = f2bf(v.w);
    *(uint2*)(Xbf + i) = pk.u;
  } else if (bi < 1 + 1536 + 96) {
    const int i = (bi - 1537) * 1024 + tid;  // 64*1536
    const int c = i / 1536, k = i % 1536;
    XPW[i] = (c < 50) ? f2bf(xpw[(size_t)k * 50 + c]) : (unsigned short)0;
  } else if (bi < 1 + 1536 + 96 + 96) {
    const int i = (bi - 1633) * 1024 + tid;  // 1536*64
    const int d = i >> 6, k = i & 63;
    DTWb[i] = (k < 48) ? f2bf(dtw[(size_t)k * DIN + d]) : (unsigned short)0;
  } else {
    const int i = (bi - 1729) * 1024 + tid;
    if (i < DIN) negA[i] = -__expf(A_log[i]);
  }
}

// ------------------- prep2 (256 thr): both weight transposes, fp32 -> bf16^T
__global__ __launch_bounds__(256) void prep2_kernel(
    const float* __restrict__ W1, unsigned short* __restrict__ W1t,
    const float* __restrict__ W2, unsigned short* __restrict__ W2t) {
  __shared__ float t[32][33];
  int idx = blockIdx.x;
  const float* W;
  unsigned short* Wt;
  int K, N, n0, k0;
  if (idx < 2304) {  // in_proj: K=768, N=3072 -> 96x24 tiles
    W = W1; Wt = W1t; K = DMOD; N = 2 * DIN;
    n0 = (idx % 96) * 32; k0 = (idx / 96) * 32;
  } else {           // out_proj: K=1536, N=768 -> 24x48 tiles
    idx -= 2304;
    W = W2; Wt = W2t; K = DIN; N = DMOD;
    n0 = (idx % 24) * 32; k0 = (idx / 24) * 32;
  }
  const int tx = threadIdx.x & 31, ty = threadIdx.x >> 5;
  for (int i = ty; i < 32; i += 8) t[i][tx] = W[(size_t)(k0 + i) * N + n0 + tx];
  __syncthreads();
  for (int i = ty; i < 32; i += 8)
    Wt[(size_t)(n0 + i) * K + k0 + tx] = f2bf(t[tx][i]);
}

// ------------------------------------------------- x_dbl: split-K bf16 MFMA
__global__ __launch_bounds__(256) void xdbl_mfma(
    const unsigned short* __restrict__ XI, const unsigned short* __restrict__ XPW,
    float* __restrict__ XP) {
  __shared__ unsigned short As[128 * 32];
  __shared__ unsigned short Bs[64 * 32];
  const int tid = threadIdx.x;
  const int w = tid >> 6, l = tid & 63;
  const int quad = l >> 4, l16 = l & 15;
  // XCD swizzle: 256 blocks; XCD k gets y in [8k,8k+8) with all 4 splits.
  const int h = blockIdx.x + 4 * blockIdx.y;
  const int swz = (h & 7) * 32 + (h >> 3);
  const int split = swz & 3;
  const int row0 = (swz >> 2) * 128;
  const int kbase = split * (DIN / NSPLIT);  // 384

  f4 acc[2][4];
#pragma unroll
  for (int i = 0; i < 2; i++)
#pragma unroll
    for (int j = 0; j < 4; j++) acc[i][j] = (f4){0.f, 0.f, 0.f, 0.f};

  const int srow = w * 16 + (l >> 2);
  const int kcol = (((l & 3) ^ ((l >> 2) & 3)) * 8);
  const int qs = (quad ^ (l16 & 3)) * 8;

  for (int c = 0; c < 12; c++) {
    const int k0 = kbase + c * 32;
#pragma unroll
    for (int r = 0; r < 2; r++) {
      gld_lds16(XI + (size_t)(row0 + srow + r * 64) * DIN + k0 + kcol,
                (char*)As + r * 4096 + w * 1024);
    }
    gld_lds16(XPW + (size_t)srow * DIN + k0 + kcol, (char*)Bs + w * 1024);
    __syncthreads();
    bfrag af[2], bf[4];
#pragma unroll
    for (int i = 0; i < 2; i++)
      af[i] = *(const bfrag*)(const void*)(As + (w * 32 + i * 16 + l16) * 32 + qs);
#pragma unroll
    for (int j = 0; j < 4; j++)
      bf[j] = *(const bfrag*)(const void*)(Bs + (j * 16 + l16) * 32 + qs);
#pragma unroll
    for (int i = 0; i < 2; i++)
#pragma unroll
      for (int j = 0; j < 4; j++)
        acc[i][j] = __builtin_amdgcn_mfma_f32_16x16x32_bf16(af[i], bf[j], acc[i][j], 0, 0, 0);
    __syncthreads();
  }

  float* dst = XP + (size_t)split * ROWS * 64 + (size_t)row0 * 64;
#pragma unroll
  for (int i = 0; i < 2; i++) {
    const int rb = w * 32 + i * 16 + quad * 4;
#pragma unroll
    for (int j = 0; j < 4; j++) {
      const int col = j * 16 + l16;
#pragma unroll
      for (int r = 0; r < 4; r++) dst[(size_t)(rb + r) * 64 + col] = acc[i][j][r];
    }
  }
}

// -------------------------- reduce XP partials -> DTLRb bf16 + BC/CC fp32
__global__ __launch_bounds__(256) void xp_reduce(
    const float* __restrict__ XP, unsigned short* __restrict__ DTLRb,
    float* __restrict__ BCv, float* __restrict__ CCv) {
  const int i = blockIdx.x * 256 + threadIdx.x;  // 8192*16
  const int row = i >> 4, c4 = (i & 15) * 4;
  const float* p = XP + (size_t)row * 64 + c4;
  float4 s = make_float4(0.f, 0.f, 0.f, 0.f);
#pragma unroll
  for (int sp = 0; sp < NSPLIT; sp++) {
    const float4 v = *(const float4*)(p + (size_t)sp * ROWS * 64);
    s.x += v.x;
    s.y += v.y;
    s.z += v.z;
    s.w += v.w;
  }
  if (c4 == 48) {
    BCv[row] = s.x;
    CCv[row] = s.y;
  }
  union { unsigned short h[4]; uint2 u; } pk;
  pk.h[0] = f2bf(s.x);
  pk.h[1] = f2bf(s.y);
  pk.h[2] = f2bf(s.z);
  pk.h[3] = f2bf(s.w);
  *(uint2*)(DTLRb + (size_t)row * 64 + c4) = pk.u;
}

// ------- dt GEMM (K=64) -> dA/dBx bf16, rows permuted to slot order.
// grid (12, 128). 64 rows x 128 cols per block. XCD-swizzled.
__global__ __launch_bounds__(256) void dt_gemm(
    const unsigned short* __restrict__ DTLRb, const unsigned short* __restrict__ DTWb,
    const float* __restrict__ bias, const float* __restrict__ negA,
    const float* __restrict__ BCv, const unsigned short* __restrict__ XI,
    const int* __restrict__ SLOTINV,
    unsigned short* __restrict__ DAp, unsigned short* __restrict__ DBXp) {
  __shared__ unsigned short As[2][64 * 32];
  __shared__ unsigned short Bs[2][128 * 32];
  __shared__ int sinv[64];
  __shared__ float bcs[64];
  const int tid = threadIdx.x;
  const int w = tid >> 6, l = tid & 63;
  const int quad = l >> 4, l16 = l & 15;
  const int wrow = (w >> 1) * 32, wcol = (w & 1) * 64;
  // XCD swizzle: 1536 blocks = 8 x 192 (bijective).
  const int h = blockIdx.x + 12 * blockIdx.y;
  const int swz = (h & 7) * 192 + (h >> 3);
  const int row0 = (swz / 12) * 64, col0 = (swz % 12) * 128;
  const int p0 = row0 & (NSEQ - 1);       // position base (batch-local)
  const int bbase = row0 & ~(NSEQ - 1);   // b*2048
  const int srow = w * 16 + (l >> 2);
  const int koff = (((l & 3) ^ ((l >> 2) & 3)) * 8);
  const int qs = (quad ^ (l16 & 3)) * 8;

#pragma unroll
  for (int c = 0; c < 2; c++) {
    gld_lds16(DTLRb + (size_t)(row0 + srow) * 64 + c * 32 + koff,
              (char*)As[c] + w * 1024);
#pragma unroll
    for (int r = 0; r < 2; r++)
      gld_lds16(DTWb + (size_t)(col0 + srow + r * 64) * 64 + c * 32 + koff,
                (char*)Bs[c] + r * 4096 + w * 1024);
  }
  if (tid < 64) {
    sinv[tid] = SLOTINV[p0 + tid];
    bcs[tid] = BCv[row0 + tid];
  }
  __syncthreads();

  f4 acc[2][4];
#pragma unroll
  for (int i = 0; i < 2; i++)
#pragma unroll
    for (int j = 0; j < 4; j++) acc[i][j] = (f4){0.f, 0.f, 0.f, 0.f};

#pragma unroll
  for (int c = 0; c < 2; c++) {
    bfrag af[2], bf[4];
#pragma unroll
    for (int i = 0; i < 2; i++)
      af[i] = *(const bfrag*)(const void*)(As[c] + (wrow + i * 16 + l16) * 32 + qs);
#pragma unroll
    for (int j = 0; j < 4; j++)
      bf[j] = *(const bfrag*)(const void*)(Bs[c] + (wcol + j * 16 + l16) * 32 + qs);
#pragma unroll
    for (int i = 0; i < 2; i++)
#pragma unroll
      for (int j = 0; j < 4; j++)
        acc[i][j] = __builtin_amdgcn_mfma_f32_16x16x32_bf16(af[i], bf[j], acc[i][j], 0, 0, 0);
  }

  float bj[4], aj[4];
#pragma unroll
  for (int j = 0; j < 4; j++) {
    const int d = col0 + wcol + j * 16 + l16;
    bj[j] = bias[d];
    aj[j] = negA[d];
  }
#pragma unroll
  for (int i = 0; i < 2; i++) {
#pragma unroll
    for (int r = 0; r < 4; r++) {
      const int row_l = wrow + i * 16 + quad * 4 + r;
      const int row = row0 + row_l;
      const float bc = bcs[row_l];
      const size_t rp = (size_t)(bbase + sinv[row_l]) * DIN;
#pragma unroll
      for (int j = 0; j < 4; j++) {
        const int d = col0 + wcol + j * 16 + l16;
        const float s = acc[i][j][r] + bj[j];
        const float sp = fmaxf(s, 0.f) + __logf(1.f + __expf(-fabsf(s)));
        const float xi = bf2f(XI[(size_t)row * DIN + d]);
        DAp[rp + d] = f2bf(__expf(sp * aj[j]));
        DBXp[rp + d] = f2bf(sp * bc * xi);
      }
    }
  }
}

// ----------------- tree recurrence: h resident in LDS, slot-ordered loads
// block owns 16 bf16 columns (2 chunks of 8); h[node][16] in LDS (64KB).
__global__ __launch_bounds__(256) void recur_kernel(
    const unsigned short* __restrict__ DAp, const unsigned short* __restrict__ DBXp,
    unsigned short* __restrict__ Hb,
    const int* __restrict__ SLOT_PACK, const int* __restrict__ LSTART,
    const int* __restrict__ NLEV) {
  __shared__ unsigned short hl[NSEQ * 16];  // 64 KB
  __shared__ int spack[NSEQ];               // 8 KB
  __shared__ int lst[258];                  // ~1 KB
  const int tid = threadIdx.x;
  const int c8a = blockIdx.x * 2;           // both chunks in same batch
  const int b = c8a / 192;
  const int d8a = c8a % 192;
  const int nlev = NLEV[0];
  for (int i = tid; i < NSEQ; i += 256) spack[i] = SLOT_PACK[i];
  const int nl = (nlev + 1 < 258) ? nlev + 1 : 258;
  for (int i = tid; i < nl; i += 256) lst[i] = LSTART[i];
  __syncthreads();

  for (int L = 0; L < nlev; L++) {
    const int s0 = (L < 257) ? lst[L] : LSTART[L];
    const int s1 = (L + 1 < 258) ? lst[L + 1] : LSTART[L + 1];
    const int items = (s1 - s0) * 2;
    for (int it = tid; it < items; it += 256) {
      const int s = s0 + (it >> 1);
      const int ch = it & 1;
      const size_t goff = (size_t)(b * NSEQ + s) * DIN + (d8a + ch) * 8;
      union { uint4 u; unsigned short h[8]; } da, dbx, hpu, hvu;
      da.u = *(const uint4*)(DAp + goff);
      dbx.u = *(const uint4*)(DBXp + goff);
      const int pk = spack[s];
      const int node = pk & 4095;
      const int pn = (pk >> 12) - 1;
      float hp[8];
      if (pn >= 0) {
        hpu.u = *(const uint4*)(hl + pn * 16 + ch * 8);
#pragma unroll
        for (int e = 0; e < 8; e++) hp[e] = bf2f(hpu.h[e]);
      } else {
#pragma unroll
        for (int e = 0; e < 8; e++) hp[e] = 0.f;
      }
#pragma unroll
      for (int e = 0; e < 8; e++) {
        const float hv = fmaf(bf2f(da.h[e]), hp[e], bf2f(dbx.h[e]));
        hvu.h[e] = f2bf(hv);
      }
      *(uint4*)(hl + node * 16 + ch * 8) = hvu.u;
    }
    __syncthreads();
  }

  // flush h to global (node-major for ln)
  for (int i = tid; i < NSEQ * 2; i += 256) {
    const int node = i >> 1, ch = i & 1;
    *(uint4*)(Hb + (size_t)(b * NSEQ + node) * DIN + (d8a + ch) * 8) =
        *(const uint4*)(hl + node * 16 + ch * 8);
  }
}

// --------------------------------------------- y, layernorm, z-gate -> bf16
__global__ __launch_bounds__(256) void ln_kernel(
    const unsigned short* __restrict__ Hb, const float* __restrict__ CCv,
    const unsigned short* __restrict__ XI, const float* __restrict__ Dp,
    const float* __restrict__ gamma, const float* __restrict__ beta,
    const unsigned short* __restrict__ Z, unsigned short* __restrict__ YLN) {
  const int row = blockIdx.x;
  const int tid = threadIdx.x;
  const float C = CCv[row];
  const unsigned short* hrow = Hb + (size_t)row * DIN;
  const unsigned short* xrow = XI + (size_t)row * DIN;
  float y[6];
  float s = 0.f, s2 = 0.f;
#pragma unroll
  for (int i = 0; i < 6; i++) {
    const int d = tid + i * 256;
    const float v = fmaf(bf2f(hrow[d]), C, Dp[d] * bf2f(xrow[d]));
    y[i] = v;
    s += v;
    s2 = fmaf(v, v, s2);
  }
#pragma unroll
  for (int off = 32; off >= 1; off >>= 1) {
    s += __shfl_down(s, off);
    s2 += __shfl_down(s2, off);
  }
  __shared__ float rs[4], rs2[4];
  const int w = tid >> 6;
  if ((tid & 63) == 0) {
    rs[w] = s;
    rs2[w] = s2;
  }
  __syncthreads();
  const float ts = rs[0] + rs[1] + rs[2] + rs[3];
  const float ts2 = rs2[0] + rs2[1] + rs2[2] + rs2[3];
  const float mu = ts * (1.f / 1536.f);
  const float var = ts2 * (1.f / 1536.f) - mu * mu;
  const float inv = rsqrtf(var + 1e-5f);
  unsigned short* yrow = YLN + (size_t)row * DIN;
  const unsigned short* zrow = Z + (size_t)row * DIN;
#pragma unroll
  for (int i = 0; i < 6; i++) {
    const int d = tid + i * 256;
    const float o = (y[i] - mu) * inv * gamma[d] + beta[d];
    yrow[d] = f2bf(o * bf2f(zrow[d]));
  }
}

// ---------------------------------------------------------------------- launch
extern "C" void kernel_launch(void* const* d_in, const int* in_sizes, int n_in,
                              void* d_out, int out_size, void* d_ws, size_t ws_size,
                              hipStream_t stream) {
  const float* x = (const float*)d_in[0];
  const int* sidx = (const int*)d_in[1];
  const int* spar = (const int*)d_in[2];
  const float* in_proj = (const float*)d_in[3];
  const float* x_proj = (const float*)d_in[4];
  const float* dt_proj = (const float*)d_in[5];
  const float* dt_b = (const float*)d_in[6];
  const float* A_log = (const float*)d_in[7];
  const float* Dp = (const float*)d_in[8];
  const float* gamma = (const float*)d_in[9];
  const float* beta = (const float*)d_in[10];
  const float* out_proj = (const float*)d_in[11];
  float* out = (float*)d_out;

  char* p = (char*)d_ws;
  const size_t RC = (size_t)ROWS * DIN;
  unsigned short* XI = (unsigned short*)p;   p += RC * 2;   // 25.2 MB
  unsigned short* Z = (unsigned short*)p;    p += RC * 2;   // 25.2 MB
  unsigned short* DAp = (unsigned short*)p;  p += RC * 2;   // 25.2 MB
  unsigned short* DBXp = (unsigned short*)p; p += RC * 2;   // 25.2 MB
  unsigned short* Hb = (unsigned short*)p;   p += RC * 2;   // 25.2 MB
  float* XP = (float*)p;                     p += (size_t)NSPLIT * ROWS * 64 * 4;  // 8.4 MB
  unsigned short* DTLRb = (unsigned short*)p; p += (size_t)ROWS * 64 * 2;          // 1 MB
  float* BCv = (float*)p;                    p += ROWS * 4;
  float* CCv = (float*)p;                    p += ROWS * 4;
  float* negA = (float*)p;                   p += DIN * 4;
  unsigned short* Xbf = (unsigned short*)p;  p += (size_t)ROWS * DMOD * 2;         // 12.6 MB
  unsigned short* W1t = (unsigned short*)p;  p += (size_t)2 * DIN * DMOD * 2;      // 4.7 MB
  unsigned short* W2t = (unsigned short*)p;  p += (size_t)DMOD * DIN * 2;          // 2.4 MB
  unsigned short* XPW = (unsigned short*)p;  p += (size_t)64 * DIN * 2;
  unsigned short* DTWb = (unsigned short*)p; p += (size_t)DIN * 64 * 2;
  int* ipart = (int*)p;
  int* SLOT_PACK = ipart;
  int* SLOTINV = ipart + 2048;
  int* LSTART = ipart + 4096;
  int* NLEV = ipart + 4096 + 2049;
  unsigned short* YLN = DAp;  // DAp dead after recur; reuse for LN output

  prep1_kernel<<<1731, 1024, 0, stream>>>(sidx, spar, SLOT_PACK, SLOTINV,
                                          LSTART, NLEV, x, Xbf, x_proj, XPW,
                                          dt_proj, DTWb, A_log, negA);
  prep2_kernel<<<3456, 256, 0, stream>>>(in_proj, W1t, out_proj, W2t);
  gemm256_silu<<<dim3(16, 32), 512, 0, stream>>>(Xbf, W1t, XI, Z, DMOD);
  xdbl_mfma<<<dim3(NSPLIT, 64), 256, 0, stream>>>(XI, XPW, XP);
  xp_reduce<<<ROWS * 16 / 256, 256, 0, stream>>>(XP, DTLRb, BCv, CCv);
  dt_gemm<<<dim3(12, 128), 256, 0, stream>>>(DTLRb, DTWb, dt_b, negA, BCv, XI,
                                             SLOTINV, DAp, DBXp);
  recur_kernel<<<384, 256, 0, stream>>>(DAp, DBXp, Hb, SLOT_PACK, LSTART, NLEV);
  ln_kernel<<<ROWS, 256, 0, stream>>>(Hb, CCv, XI, Dp, gamma, beta, Z, YLN);
  mfma_gemm<0><<<dim3(6, 64), 256, 0, stream>>>(YLN, W2t, out, nullptr, DIN, DMOD);
}

// Round 8
// 293.629 us; speedup vs baseline: 1.1149x; 1.0396x over previous
//
#include <hip/hip_runtime.h>
#include <math.h>

// TreeMambaLayer: B=4, N=2048, D_MODEL=768, D_INNER=1536, DT_RANK=48
// Round 16: out_proj -> new gemm_out (128x192 tile, grid (4,64)=256 blocks,
// 80KB LDS dbuf -> 2 blocks/CU, 8-chunk XOR swizzle, global_load_lds deep
// pipeline, counted vmcnt(5)). Replaces R1-structure mfma_gemm<0> (~4-way
// LDS conflicts, 1-round-unbalanced). Rest frozen from R15.

#define ROWS 8192
#define DIN 1536
#define DMOD 768
#define NSEQ 2048
#define DTR 48
#define NSPLIT 4

typedef __bf16 bfrag __attribute__((ext_vector_type(8)));
typedef float f4 __attribute__((ext_vector_type(4)));

__device__ __forceinline__ unsigned short f2bf(float f) {
  unsigned int u = __float_as_uint(f);
  unsigned int r = (u + 0x7fffu + ((u >> 16) & 1u)) >> 16;
  return (unsigned short)r;
}
__device__ __forceinline__ float bf2f(unsigned short h) {
  return __uint_as_float(((unsigned int)h) << 16);
}

__device__ __forceinline__ void gld_lds16(const void* g, void* l) {
  __builtin_amdgcn_global_load_lds((const __attribute__((address_space(1))) void*)g,
                                   (__attribute__((address_space(3))) void*)l, 16, 0, 0);
}

// raw barrier: no vmcnt drain; compiler-level memory fence only.
__device__ __forceinline__ void barx() {
  asm volatile("" ::: "memory");
  __builtin_amdgcn_s_barrier();
  asm volatile("" ::: "memory");
}

// ---------------- 256x192 2-phase bf16 GEMM, C = A(MxK) * Bt(NxK)^T
// cols < DIN -> XI bf16; cols >= DIN -> Z = silu, bf16.
// 8 waves (2M x 4N), per-wave 128x48 out. BK=64, LDS 112KB dbuf.
__global__ __launch_bounds__(512, 1) void gemm256_silu(
    const unsigned short* __restrict__ A, const unsigned short* __restrict__ Bt,
    unsigned short* __restrict__ XI, unsigned short* __restrict__ Z, int K) {
  __shared__ unsigned short lds[2][(256 + 192) * 64];  // 112KB
  const int tid = threadIdx.x;
  const int w = tid >> 6, l = tid & 63;
  const int quad = l >> 4, l16 = l & 15;
  const int wr = w >> 2, wc = w & 3;
  // XCD swizzle: 512 blocks, XCD k owns logical ids [64k,64k+64) = 4 full
  // A-row-panels (16 col-sharers each -> same XCD L2).
  const int h = blockIdx.x + 16 * blockIdx.y;
  const int swz = (h & 7) * 64 + (h >> 3);
  const int row0 = (swz >> 4) * 256, col0 = (swz & 15) * 192;
  const int nt = K >> 6;

  const int srow = tid >> 3;
  const int schunk = ((tid & 7) ^ (srow & 7)) * 8;
  const unsigned short* aS = A + (size_t)(row0 + srow) * K + schunk;
  const unsigned short* bS = Bt + (size_t)(col0 + srow) * K + schunk;

#define STG_A(bufi, q, kt)                                     \
  gld_lds16(aS + (size_t)((q) * 64) * K + (size_t)(kt) * 64,   \
            (char*)&lds[bufi][(q) * 4096] + w * 1024)
#define STG_B(bufi, q, kt)                                     \
  gld_lds16(bS + (size_t)((q) * 64) * K + (size_t)(kt) * 64,   \
            (char*)&lds[bufi][16384 + (q) * 4096] + w * 1024)

  const int arow = (wr * 128 + l16) * 64;
  const int brow = (wc * 48 + l16) * 64;
  int cs[2];
  cs[0] = (quad ^ (l16 & 7)) * 8;
  cs[1] = ((4 + quad) ^ (l16 & 7)) * 8;

#define RDA(m, ks) (*(const bfrag*)(const void*)(LA + arow + (m) * 1024 + cs[ks]))
#define RDB(n, ks) (*(const bfrag*)(const void*)(LB + brow + (n) * 1024 + cs[ks]))

  f4 acc[8][3];
#pragma unroll
  for (int m = 0; m < 8; m++)
#pragma unroll
    for (int n = 0; n < 3; n++) acc[m][n] = (f4){0.f, 0.f, 0.f, 0.f};

  const int kt1 = (nt > 1) ? 1 : 0;
#pragma unroll
  for (int q = 0; q < 4; q++) STG_A(0, q, 0);
#pragma unroll
  for (int q = 0; q < 3; q++) STG_B(0, q, 0);
#pragma unroll
  for (int q = 0; q < 4; q++) STG_A(1, q, kt1);
#pragma unroll
  for (int q = 0; q < 3; q++) STG_B(1, q, kt1);
  asm volatile("s_waitcnt vmcnt(7)" ::: "memory");
  barx();

  for (int t = 0; t < nt; ++t) {
    const int b = t & 1;
    const unsigned short* LA = &lds[b][0];
    const unsigned short* LB = &lds[b][16384];
    const int kA = (t + 2 < nt) ? (t + 2) : (nt - 1);
    bfrag af[4][2], bfr[3][2];

    // ---- P0: read A m0-3 + B n0-2; MFMA (m-lo, all n)
#pragma unroll
    for (int m = 0; m < 4; m++) {
      af[m][0] = RDA(m, 0);
      af[m][1] = RDA(m, 1);
    }
#pragma unroll
    for (int n = 0; n < 3; n++) {
      bfr[n][0] = RDB(n, 0);
      bfr[n][1] = RDB(n, 1);
    }
    barx();
    __builtin_amdgcn_s_setprio(1);
#pragma unroll
    for (int m = 0; m < 4; m++)
#pragma unroll
      for (int n = 0; n < 3; n++) {
        acc[m][n] = __builtin_amdgcn_mfma_f32_16x16x32_bf16(af[m][0], bfr[n][0], acc[m][n], 0, 0, 0);
        acc[m][n] = __builtin_amdgcn_mfma_f32_16x16x32_bf16(af[m][1], bfr[n][1], acc[m][n], 0, 0, 0);
      }
    __builtin_amdgcn_s_setprio(0);
    barx();

    // ---- P1: read A m4-7; stage t+2 A-Q0,Q2 + B (consumed in P0)
#pragma unroll
    for (int m = 0; m < 4; m++) {
      af[m][0] = RDA(m + 4, 0);
      af[m][1] = RDA(m + 4, 1);
    }
    STG_A(b, 0, kA);
    STG_A(b, 2, kA);
    STG_B(b, 0, kA);
    STG_B(b, 1, kA);
    STG_B(b, 2, kA);
    barx();  // all waves' A-hi reads done -> Q1/Q3 stage safe
    STG_A(b, 1, kA);
    STG_A(b, 3, kA);
    __builtin_amdgcn_s_setprio(1);
#pragma unroll
    for (int m = 0; m < 4; m++)
#pragma unroll
      for (int n = 0; n < 3; n++) {
        acc[m + 4][n] = __builtin_amdgcn_mfma_f32_16x16x32_bf16(af[m][0], bfr[n][0], acc[m + 4][n], 0, 0, 0);
        acc[m + 4][n] = __builtin_amdgcn_mfma_f32_16x16x32_bf16(af[m][1], bfr[n][1], acc[m + 4][n], 0, 0, 0);
      }
    __builtin_amdgcn_s_setprio(0);
    asm volatile("s_waitcnt vmcnt(7)" ::: "memory");
    barx();
  }
  asm volatile("s_waitcnt vmcnt(0)" ::: "memory");

#undef STG_A
#undef STG_B
#undef RDA
#undef RDB

  // epilogue: direct stores (WRITE_SIZE already ideal)
  const bool is_z = (col0 >= DIN);
  unsigned short* dst = is_z ? Z : XI;
  const int cb = col0 + wc * 48 + l16 - (is_z ? DIN : 0);
#pragma unroll
  for (int m = 0; m < 8; m++) {
    const int rb = row0 + wr * 128 + m * 16 + quad * 4;
#pragma unroll
    for (int n = 0; n < 3; n++)
#pragma unroll
      for (int r = 0; r < 4; r++) {
        float v = acc[m][n][r];
        if (is_z) v = v / (1.f + __expf(-v));
        dst[(size_t)(rb + r) * DIN + cb + n * 16] = f2bf(v);
      }
  }
}

// ---------------- 128x192 out_proj GEMM, C(fp32) = A(MxK) * Bt(NxK)^T
// grid (4, 64) = 256 blocks (perfect 1-round balance), 8 waves (2M x 4N),
// per-wave 64x48 out. BK=64, LDS 80KB dbuf -> 2 blocks/CU (4 waves/SIMD).
// Single compute phase: read all -> lgkm(0) -> bar -> stage t+2 (5 loads)
// -> MFMA 24 -> vmcnt(5) -> bar.
__global__ __launch_bounds__(512, 2) void gemm_out(
    const unsigned short* __restrict__ A, const unsigned short* __restrict__ Bt,
    float* __restrict__ C0, int K, int ldc) {
  __shared__ unsigned short lds[2][(128 + 192) * 64];  // 80KB
  const int tid = threadIdx.x;
  const int w = tid >> 6, l = tid & 63;
  const int quad = l >> 4, l16 = l & 15;
  const int wr = w >> 2, wc = w & 3;
  // XCD swizzle: 256 blocks; XCD k owns swz [32k,32k+32) = 8 row-panels.
  const int h = blockIdx.x + 4 * blockIdx.y;
  const int swz = (h & 7) * 32 + (h >> 3);
  const int row0 = (swz >> 2) * 128, col0 = (swz & 3) * 192;
  const int nt = K >> 6;  // 24

  const int srow = tid >> 3;
  const int schunk = ((tid & 7) ^ (srow & 7)) * 8;
  const unsigned short* aS = A + (size_t)(row0 + srow) * K + schunk;
  const unsigned short* bS = Bt + (size_t)(col0 + srow) * K + schunk;

#define STG_A(bufi, q, kt)                                     \
  gld_lds16(aS + (size_t)((q) * 64) * K + (size_t)(kt) * 64,   \
            (char*)&lds[bufi][(q) * 4096] + w * 1024)
#define STG_B(bufi, q, kt)                                     \
  gld_lds16(bS + (size_t)((q) * 64) * K + (size_t)(kt) * 64,   \
            (char*)&lds[bufi][8192 + (q) * 4096] + w * 1024)

  const int arow = (wr * 64 + l16) * 64;
  const int brow = (wc * 48 + l16) * 64;
  int cs[2];
  cs[0] = (quad ^ (l16 & 7)) * 8;
  cs[1] = ((4 + quad) ^ (l16 & 7)) * 8;

#define RDA(m, ks) (*(const bfrag*)(const void*)(LA + arow + (m) * 1024 + cs[ks]))
#define RDB(n, ks) (*(const bfrag*)(const void*)(LB + brow + (n) * 1024 + cs[ks]))

  f4 acc[4][3];
#pragma unroll
  for (int m = 0; m < 4; m++)
#pragma unroll
    for (int n = 0; n < 3; n++) acc[m][n] = (f4){0.f, 0.f, 0.f, 0.f};

  // prologue: stage t0 (5) + t1 (5); wait until t0's 5 landed.
  const int kt1 = (nt > 1) ? 1 : 0;
#pragma unroll
  for (int q = 0; q < 2; q++) STG_A(0, q, 0);
#pragma unroll
  for (int q = 0; q < 3; q++) STG_B(0, q, 0);
#pragma unroll
  for (int q = 0; q < 2; q++) STG_A(1, q, kt1);
#pragma unroll
  for (int q = 0; q < 3; q++) STG_B(1, q, kt1);
  asm volatile("s_waitcnt vmcnt(5)" ::: "memory");
  barx();

  for (int t = 0; t < nt; ++t) {
    const int b = t & 1;
    const unsigned short* LA = &lds[b][0];
    const unsigned short* LB = &lds[b][8192];
    const int kA = (t + 2 < nt) ? (t + 2) : (nt - 1);
    bfrag af[4][2], bfr[3][2];

    // read all fragments for this tile
#pragma unroll
    for (int m = 0; m < 4; m++) {
      af[m][0] = RDA(m, 0);
      af[m][1] = RDA(m, 1);
    }
#pragma unroll
    for (int n = 0; n < 3; n++) {
      bfr[n][0] = RDB(n, 0);
      bfr[n][1] = RDB(n, 1);
    }
    asm volatile("s_waitcnt lgkmcnt(0)" ::: "memory");
    barx();  // all waves' reads landed -> safe to DMA-overwrite buf b
    // stage t+2 into current buffer
    STG_A(b, 0, kA);
    STG_A(b, 1, kA);
    STG_B(b, 0, kA);
    STG_B(b, 1, kA);
    STG_B(b, 2, kA);
    __builtin_amdgcn_s_setprio(1);
#pragma unroll
    for (int m = 0; m < 4; m++)
#pragma unroll
      for (int n = 0; n < 3; n++) {
        acc[m][n] = __builtin_amdgcn_mfma_f32_16x16x32_bf16(af[m][0], bfr[n][0], acc[m][n], 0, 0, 0);
        acc[m][n] = __builtin_amdgcn_mfma_f32_16x16x32_bf16(af[m][1], bfr[n][1], acc[m][n], 0, 0, 0);
      }
    __builtin_amdgcn_s_setprio(0);
    // tile t+1's 5 loads (issued last tile) landed; t+2's 5 in flight.
    asm volatile("s_waitcnt vmcnt(5)" ::: "memory");
    barx();
  }
  asm volatile("s_waitcnt vmcnt(0)" ::: "memory");

#undef STG_A
#undef STG_B
#undef RDA
#undef RDB

  const int cb = col0 + wc * 48 + l16;
#pragma unroll
  for (int m = 0; m < 4; m++) {
    const int rb = row0 + wr * 64 + m * 16 + quad * 4;
#pragma unroll
    for (int n = 0; n < 3; n++)
#pragma unroll
      for (int r = 0; r < 4; r++)
        C0[(size_t)(rb + r) * ldc + cb + n * 16] = acc[m][n][r];
  }
}

// ------------------- prep1 (1024 thr): sched (block 0) + all flat casts
// SLOT_PACK[slot] = node | ((pnode+1)<<12); SLOTINV[node] = slot.
__global__ __launch_bounds__(1024) void prep1_kernel(
    const int* __restrict__ sidx, const int* __restrict__ spar,
    int* __restrict__ SLOT_PACK, int* __restrict__ SLOTINV,
    int* __restrict__ LSTART, int* __restrict__ NLEV,
    const float* __restrict__ x, unsigned short* __restrict__ Xbf,
    const float* __restrict__ xpw, unsigned short* __restrict__ XPW,
    const float* __restrict__ dtw, unsigned short* __restrict__ DTWb,
    const float* __restrict__ A_log, float* __restrict__ negA) {
  const int bi = blockIdx.x;
  const int tid = threadIdx.x;
  if (bi == 0) {
    __shared__ int par[2048], idx[2048], ancA[2048], ancB[2048], rnkA[2048], rnkB[2048];
    __shared__ int dmax;
    for (int i = tid; i < 2048; i += 1024) {
      const int p = spar[i];
      par[i] = p;
      idx[i] = sidx[i];
      ancA[i] = (p < 0) ? -1 : p;
      rnkA[i] = (p < 0) ? 0 : 1;
    }
    if (tid == 0) dmax = 0;
    __syncthreads();
    for (int r = 0; r < 11; r++) {
      int* ca = (r & 1) ? ancB : ancA;
      int* cr = (r & 1) ? rnkB : rnkA;
      int* na = (r & 1) ? ancA : ancB;
      int* nr = (r & 1) ? rnkA : rnkB;
      for (int i = tid; i < 2048; i += 1024) {
        const int a = ca[i], rv = cr[i];
        if (a >= 0) {
          nr[i] = rv + cr[a];
          na[i] = ca[a];
        } else {
          nr[i] = rv;
          na[i] = a;
        }
      }
      __syncthreads();
    }
    for (int i = tid; i < 2048; i += 1024) ancA[i] = 0;
    __syncthreads();
    for (int i = tid; i < 2048; i += 1024) {
      atomicAdd(&ancA[rnkB[i]], 1);
      atomicMax(&dmax, rnkB[i]);
    }
    __syncthreads();
    for (int s = 0; s < 11; s++) {
      const int off = 1 << s;
      int* cur = (s & 1) ? ancB : ancA;
      int* nxt = (s & 1) ? ancA : ancB;
      for (int i = tid; i < 2048; i += 1024) {
        int v = cur[i];
        if (i >= off) v += cur[i - off];
        nxt[i] = v;
      }
      __syncthreads();
    }
    for (int i = tid; i < 2049; i += 1024) {
      const int v = (i == 0) ? 0 : ancB[i - 1];
      LSTART[i] = v;
      if (i < 2048) rnkA[i] = v;
    }
    if (tid == 0) NLEV[0] = dmax + 1;
    __syncthreads();
    for (int i = tid; i < 2048; i += 1024) {
      const int d = rnkB[i];
      const int slot = atomicAdd(&rnkA[d], 1);
      const int node = idx[i];
      const int p = par[i];
      const int pn = (p < 0) ? -1 : idx[p];
      SLOT_PACK[slot] = node | ((pn + 1) << 12);
      SLOTINV[node] = slot;
    }
  } else if (bi < 1 + 1536) {
    const int i = ((bi - 1) * 1024 + tid) * 4;
    const float4 v = *(const float4*)(x + i);
    union { unsigned short h[4]; uint2 u; } pk;
    pk.h[0] = f2bf(v.x);
    pk.h[1] = f2bf(v.y);
    pk.h[2] = f2bf(v.z);
    pk.h[3] = f2bf(v.w);
    *(uint2*)(Xbf + i) = pk.u;
  } else if (bi < 1 + 1536 + 96) {
    const int i = (bi - 1537) * 1024 + tid;  // 64*1536
    const int c = i / 1536, k = i % 1536;
    XPW[i] = (c < 50) ? f2bf(xpw[(size_t)k * 50 + c]) : (unsigned short)0;
  } else if (bi < 1 + 1536 + 96 + 96) {
    const int i = (bi - 1633) * 1024 + tid;  // 1536*64
    const int d = i >> 6, k = i & 63;
    DTWb[i] = (k < 48) ? f2bf(dtw[(size_t)k * DIN + d]) : (unsigned short)0;
  } else {
    const int i = (bi - 1729) * 1024 + tid;
    if (i < DIN) negA[i] = -__expf(A_log[i]);
  }
}

// ------------------- prep2 (256 thr): both weight transposes, fp32 -> bf16^T
__global__ __launch_bounds__(256) void prep2_kernel(
    const float* __restrict__ W1, unsigned short* __restrict__ W1t,
    const float* __restrict__ W2, unsigned short* __restrict__ W2t) {
  __shared__ float t[32][33];
  int idx = blockIdx.x;
  const float* W;
  unsigned short* Wt;
  int K, N, n0, k0;
  if (idx < 2304) {  // in_proj: K=768, N=3072 -> 96x24 tiles
    W = W1; Wt = W1t; K = DMOD; N = 2 * DIN;
    n0 = (idx % 96) * 32; k0 = (idx / 96) * 32;
  } else {           // out_proj: K=1536, N=768 -> 24x48 tiles
    idx -= 2304;
    W = W2; Wt = W2t; K = DIN; N = DMOD;
    n0 = (idx % 24) * 32; k0 = (idx / 24) * 32;
  }
  const int tx = threadIdx.x & 31, ty = threadIdx.x >> 5;
  for (int i = ty; i < 32; i += 8) t[i][tx] = W[(size_t)(k0 + i) * N + n0 + tx];
  __syncthreads();
  for (int i = ty; i < 32; i += 8)
    Wt[(size_t)(n0 + i) * K + k0 + tx] = f2bf(t[tx][i]);
}

// ------------------------------------------------- x_dbl: split-K bf16 MFMA
__global__ __launch_bounds__(256) void xdbl_mfma(
    const unsigned short* __restrict__ XI, const unsigned short* __restrict__ XPW,
    float* __restrict__ XP) {
  __shared__ unsigned short As[128 * 32];
  __shared__ unsigned short Bs[64 * 32];
  const int tid = threadIdx.x;
  const int w = tid >> 6, l = tid & 63;
  const int quad = l >> 4, l16 = l & 15;
  // XCD swizzle: 256 blocks; XCD k gets y in [8k,8k+8) with all 4 splits.
  const int h = blockIdx.x + 4 * blockIdx.y;
  const int swz = (h & 7) * 32 + (h >> 3);
  const int split = swz & 3;
  const int row0 = (swz >> 2) * 128;
  const int kbase = split * (DIN / NSPLIT);  // 384

  f4 acc[2][4];
#pragma unroll
  for (int i = 0; i < 2; i++)
#pragma unroll
    for (int j = 0; j < 4; j++) acc[i][j] = (f4){0.f, 0.f, 0.f, 0.f};

  const int srow = w * 16 + (l >> 2);
  const int kcol = (((l & 3) ^ ((l >> 2) & 3)) * 8);
  const int qs = (quad ^ (l16 & 3)) * 8;

  for (int c = 0; c < 12; c++) {
    const int k0 = kbase + c * 32;
#pragma unroll
    for (int r = 0; r < 2; r++) {
      gld_lds16(XI + (size_t)(row0 + srow + r * 64) * DIN + k0 + kcol,
                (char*)As + r * 4096 + w * 1024);
    }
    gld_lds16(XPW + (size_t)srow * DIN + k0 + kcol, (char*)Bs + w * 1024);
    __syncthreads();
    bfrag af[2], bf[4];
#pragma unroll
    for (int i = 0; i < 2; i++)
      af[i] = *(const bfrag*)(const void*)(As + (w * 32 + i * 16 + l16) * 32 + qs);
#pragma unroll
    for (int j = 0; j < 4; j++)
      bf[j] = *(const bfrag*)(const void*)(Bs + (j * 16 + l16) * 32 + qs);
#pragma unroll
    for (int i = 0; i < 2; i++)
#pragma unroll
      for (int j = 0; j < 4; j++)
        acc[i][j] = __builtin_amdgcn_mfma_f32_16x16x32_bf16(af[i], bf[j], acc[i][j], 0, 0, 0);
    __syncthreads();
  }

  float* dst = XP + (size_t)split * ROWS * 64 + (size_t)row0 * 64;
#pragma unroll
  for (int i = 0; i < 2; i++) {
    const int rb = w * 32 + i * 16 + quad * 4;
#pragma unroll
    for (int j = 0; j < 4; j++) {
      const int col = j * 16 + l16;
#pragma unroll
      for (int r = 0; r < 4; r++) dst[(size_t)(rb + r) * 64 + col] = acc[i][j][r];
    }
  }
}

// -------------------------- reduce XP partials -> DTLRb bf16 + BC/CC fp32
__global__ __launch_bounds__(256) void xp_reduce(
    const float* __restrict__ XP, unsigned short* __restrict__ DTLRb,
    float* __restrict__ BCv, float* __restrict__ CCv) {
  const int i = blockIdx.x * 256 + threadIdx.x;  // 8192*16
  const int row = i >> 4, c4 = (i & 15) * 4;
  const float* p = XP + (size_t)row * 64 + c4;
  float4 s = make_float4(0.f, 0.f, 0.f, 0.f);
#pragma unroll
  for (int sp = 0; sp < NSPLIT; sp++) {
    const float4 v = *(const float4*)(p + (size_t)sp * ROWS * 64);
    s.x += v.x;
    s.y += v.y;
    s.z += v.z;
    s.w += v.w;
  }
  if (c4 == 48) {
    BCv[row] = s.x;
    CCv[row] = s.y;
  }
  union { unsigned short h[4]; uint2 u; } pk;
  pk.h[0] = f2bf(s.x);
  pk.h[1] = f2bf(s.y);
  pk.h[2] = f2bf(s.z);
  pk.h[3] = f2bf(s.w);
  *(uint2*)(DTLRb + (size_t)row * 64 + c4) = pk.u;
}

// ------- dt GEMM (K=64) -> dA/dBx bf16, rows permuted to slot order.
// grid (12, 128). 64 rows x 128 cols per block. XCD-swizzled.
__global__ __launch_bounds__(256) void dt_gemm(
    const unsigned short* __restrict__ DTLRb, const unsigned short* __restrict__ DTWb,
    const float* __restrict__ bias, const float* __restrict__ negA,
    const float* __restrict__ BCv, const unsigned short* __restrict__ XI,
    const int* __restrict__ SLOTINV,
    unsigned short* __restrict__ DAp, unsigned short* __restrict__ DBXp) {
  __shared__ unsigned short As[2][64 * 32];
  __shared__ unsigned short Bs[2][128 * 32];
  __shared__ int sinv[64];
  __shared__ float bcs[64];
  const int tid = threadIdx.x;
  const int w = tid >> 6, l = tid & 63;
  const int quad = l >> 4, l16 = l & 15;
  const int wrow = (w >> 1) * 32, wcol = (w & 1) * 64;
  // XCD swizzle: 1536 blocks = 8 x 192 (bijective).
  const int h = blockIdx.x + 12 * blockIdx.y;
  const int swz = (h & 7) * 192 + (h >> 3);
  const int row0 = (swz / 12) * 64, col0 = (swz % 12) * 128;
  const int p0 = row0 & (NSEQ - 1);       // position base (batch-local)
  const int bbase = row0 & ~(NSEQ - 1);   // b*2048
  const int srow = w * 16 + (l >> 2);
  const int koff = (((l & 3) ^ ((l >> 2) & 3)) * 8);
  const int qs = (quad ^ (l16 & 3)) * 8;

#pragma unroll
  for (int c = 0; c < 2; c++) {
    gld_lds16(DTLRb + (size_t)(row0 + srow) * 64 + c * 32 + koff,
              (char*)As[c] + w * 1024);
#pragma unroll
    for (int r = 0; r < 2; r++)
      gld_lds16(DTWb + (size_t)(col0 + srow + r * 64) * 64 + c * 32 + koff,
                (char*)Bs[c] + r * 4096 + w * 1024);
  }
  if (tid < 64) {
    sinv[tid] = SLOTINV[p0 + tid];
    bcs[tid] = BCv[row0 + tid];
  }
  __syncthreads();

  f4 acc[2][4];
#pragma unroll
  for (int i = 0; i < 2; i++)
#pragma unroll
    for (int j = 0; j < 4; j++) acc[i][j] = (f4){0.f, 0.f, 0.f, 0.f};

#pragma unroll
  for (int c = 0; c < 2; c++) {
    bfrag af[2], bf[4];
#pragma unroll
    for (int i = 0; i < 2; i++)
      af[i] = *(const bfrag*)(const void*)(As[c] + (wrow + i * 16 + l16) * 32 + qs);
#pragma unroll
    for (int j = 0; j < 4; j++)
      bf[j] = *(const bfrag*)(const void*)(Bs[c] + (wcol + j * 16 + l16) * 32 + qs);
#pragma unroll
    for (int i = 0; i < 2; i++)
#pragma unroll
      for (int j = 0; j < 4; j++)
        acc[i][j] = __builtin_amdgcn_mfma_f32_16x16x32_bf16(af[i], bf[j], acc[i][j], 0, 0, 0);
  }

  float bj[4], aj[4];
#pragma unroll
  for (int j = 0; j < 4; j++) {
    const int d = col0 + wcol + j * 16 + l16;
    bj[j] = bias[d];
    aj[j] = negA[d];
  }
#pragma unroll
  for (int i = 0; i < 2; i++) {
#pragma unroll
    for (int r = 0; r < 4; r++) {
      const int row_l = wrow + i * 16 + quad * 4 + r;
      const int row = row0 + row_l;
      const float bc = bcs[row_l];
      const size_t rp = (size_t)(bbase + sinv[row_l]) * DIN;
#pragma unroll
      for (int j = 0; j < 4; j++) {
        const int d = col0 + wcol + j * 16 + l16;
        const float s = acc[i][j][r] + bj[j];
        const float sp = fmaxf(s, 0.f) + __logf(1.f + __expf(-fabsf(s)));
        const float xi = bf2f(XI[(size_t)row * DIN + d]);
        DAp[rp + d] = f2bf(__expf(sp * aj[j]));
        DBXp[rp + d] = f2bf(sp * bc * xi);
      }
    }
  }
}

// ----------------- tree recurrence: h resident in LDS, slot-ordered loads
// block owns 16 bf16 columns (2 chunks of 8); h[node][16] in LDS (64KB).
__global__ __launch_bounds__(256) void recur_kernel(
    const unsigned short* __restrict__ DAp, const unsigned short* __restrict__ DBXp,
    unsigned short* __restrict__ Hb,
    const int* __restrict__ SLOT_PACK, const int* __restrict__ LSTART,
    const int* __restrict__ NLEV) {
  __shared__ unsigned short hl[NSEQ * 16];  // 64 KB
  __shared__ int spack[NSEQ];               // 8 KB
  __shared__ int lst[258];                  // ~1 KB
  const int tid = threadIdx.x;
  const int c8a = blockIdx.x * 2;           // both chunks in same batch
  const int b = c8a / 192;
  const int d8a = c8a % 192;
  const int nlev = NLEV[0];
  for (int i = tid; i < NSEQ; i += 256) spack[i] = SLOT_PACK[i];
  const int nl = (nlev + 1 < 258) ? nlev + 1 : 258;
  for (int i = tid; i < nl; i += 256) lst[i] = LSTART[i];
  __syncthreads();

  for (int L = 0; L < nlev; L++) {
    const int s0 = (L < 257) ? lst[L] : LSTART[L];
    const int s1 = (L + 1 < 258) ? lst[L + 1] : LSTART[L + 1];
    const int items = (s1 - s0) * 2;
    for (int it = tid; it < items; it += 256) {
      const int s = s0 + (it >> 1);
      const int ch = it & 1;
      const size_t goff = (size_t)(b * NSEQ + s) * DIN + (d8a + ch) * 8;
      union { uint4 u; unsigned short h[8]; } da, dbx, hpu, hvu;
      da.u = *(const uint4*)(DAp + goff);
      dbx.u = *(const uint4*)(DBXp + goff);
      const int pk = spack[s];
      const int node = pk & 4095;
      const int pn = (pk >> 12) - 1;
      float hp[8];
      if (pn >= 0) {
        hpu.u = *(const uint4*)(hl + pn * 16 + ch * 8);
#pragma unroll
        for (int e = 0; e < 8; e++) hp[e] = bf2f(hpu.h[e]);
      } else {
#pragma unroll
        for (int e = 0; e < 8; e++) hp[e] = 0.f;
      }
#pragma unroll
      for (int e = 0; e < 8; e++) {
        const float hv = fmaf(bf2f(da.h[e]), hp[e], bf2f(dbx.h[e]));
        hvu.h[e] = f2bf(hv);
      }
      *(uint4*)(hl + node * 16 + ch * 8) = hvu.u;
    }
    __syncthreads();
  }

  // flush h to global (node-major for ln)
  for (int i = tid; i < NSEQ * 2; i += 256) {
    const int node = i >> 1, ch = i & 1;
    *(uint4*)(Hb + (size_t)(b * NSEQ + node) * DIN + (d8a + ch) * 8) =
        *(const uint4*)(hl + node * 16 + ch * 8);
  }
}

// --------------------------------------------- y, layernorm, z-gate -> bf16
__global__ __launch_bounds__(256) void ln_kernel(
    const unsigned short* __restrict__ Hb, const float* __restrict__ CCv,
    const unsigned short* __restrict__ XI, const float* __restrict__ Dp,
    const float* __restrict__ gamma, const float* __restrict__ beta,
    const unsigned short* __restrict__ Z, unsigned short* __restrict__ YLN) {
  const int row = blockIdx.x;
  const int tid = threadIdx.x;
  const float C = CCv[row];
  const unsigned short* hrow = Hb + (size_t)row * DIN;
  const unsigned short* xrow = XI + (size_t)row * DIN;
  float y[6];
  float s = 0.f, s2 = 0.f;
#pragma unroll
  for (int i = 0; i < 6; i++) {
    const int d = tid + i * 256;
    const float v = fmaf(bf2f(hrow[d]), C, Dp[d] * bf2f(xrow[d]));
    y[i] = v;
    s += v;
    s2 = fmaf(v, v, s2);
  }
#pragma unroll
  for (int off = 32; off >= 1; off >>= 1) {
    s += __shfl_down(s, off);
    s2 += __shfl_down(s2, off);
  }
  __shared__ float rs[4], rs2[4];
  const int w = tid >> 6;
  if ((tid & 63) == 0) {
    rs[w] = s;
    rs2[w] = s2;
  }
  __syncthreads();
  const float ts = rs[0] + rs[1] + rs[2] + rs[3];
  const float ts2 = rs2[0] + rs2[1] + rs2[2] + rs2[3];
  const float mu = ts * (1.f / 1536.f);
  const float var = ts2 * (1.f / 1536.f) - mu * mu;
  const float inv = rsqrtf(var + 1e-5f);
  unsigned short* yrow = YLN + (size_t)row * DIN;
  const unsigned short* zrow = Z + (size_t)row * DIN;
#pragma unroll
  for (int i = 0; i < 6; i++) {
    const int d = tid + i * 256;
    const float o = (y[i] - mu) * inv * gamma[d] + beta[d];
    yrow[d] = f2bf(o * bf2f(zrow[d]));
  }
}

// ---------------------------------------------------------------------- launch
extern "C" void kernel_launch(void* const* d_in, const int* in_sizes, int n_in,
                              void* d_out, int out_size, void* d_ws, size_t ws_size,
                              hipStream_t stream) {
  const float* x = (const float*)d_in[0];
  const int* sidx = (const int*)d_in[1];
  const int* spar = (const int*)d_in[2];
  const float* in_proj = (const float*)d_in[3];
  const float* x_proj = (const float*)d_in[4];
  const float* dt_proj = (const float*)d_in[5];
  const float* dt_b = (const float*)d_in[6];
  const float* A_log = (const float*)d_in[7];
  const float* Dp = (const float*)d_in[8];
  const float* gamma = (const float*)d_in[9];
  const float* beta = (const float*)d_in[10];
  const float* out_proj = (const float*)d_in[11];
  float* out = (float*)d_out;

  char* p = (char*)d_ws;
  const size_t RC = (size_t)ROWS * DIN;
  unsigned short* XI = (unsigned short*)p;   p += RC * 2;   // 25.2 MB
  unsigned short* Z = (unsigned short*)p;    p += RC * 2;   // 25.2 MB
  unsigned short* DAp = (unsigned short*)p;  p += RC * 2;   // 25.2 MB
  unsigned short* DBXp = (unsigned short*)p; p += RC * 2;   // 25.2 MB
  unsigned short* Hb = (unsigned short*)p;   p += RC * 2;   // 25.2 MB
  float* XP = (float*)p;                     p += (size_t)NSPLIT * ROWS * 64 * 4;  // 8.4 MB
  unsigned short* DTLRb = (unsigned short*)p; p += (size_t)ROWS * 64 * 2;          // 1 MB
  float* BCv = (float*)p;                    p += ROWS * 4;
  float* CCv = (float*)p;                    p += ROWS * 4;
  float* negA = (float*)p;                   p += DIN * 4;
  unsigned short* Xbf = (unsigned short*)p;  p += (size_t)ROWS * DMOD * 2;         // 12.6 MB
  unsigned short* W1t = (unsigned short*)p;  p += (size_t)2 * DIN * DMOD * 2;      // 4.7 MB
  unsigned short* W2t = (unsigned short*)p;  p += (size_t)DMOD * DIN * 2;          // 2.4 MB
  unsigned short* XPW = (unsigned short*)p;  p += (size_t)64 * DIN * 2;
  unsigned short* DTWb = (unsigned short*)p; p += (size_t)DIN * 64 * 2;
  int* ipart = (int*)p;
  int* SLOT_PACK = ipart;
  int* SLOTINV = ipart + 2048;
  int* LSTART = ipart + 4096;
  int* NLEV = ipart + 4096 + 2049;
  unsigned short* YLN = DAp;  // DAp dead after recur; reuse for LN output

  prep1_kernel<<<1731, 1024, 0, stream>>>(sidx, spar, SLOT_PACK, SLOTINV,
                                          LSTART, NLEV, x, Xbf, x_proj, XPW,
                                          dt_proj, DTWb, A_log, negA);
  prep2_kernel<<<3456, 256, 0, stream>>>(in_proj, W1t, out_proj, W2t);
  gemm256_silu<<<dim3(16, 32), 512, 0, stream>>>(Xbf, W1t, XI, Z, DMOD);
  xdbl_mfma<<<dim3(NSPLIT, 64), 256, 0, stream>>>(XI, XPW, XP);
  xp_reduce<<<ROWS * 16 / 256, 256, 0, stream>>>(XP, DTLRb, BCv, CCv);
  dt_gemm<<<dim3(12, 128), 256, 0, stream>>>(DTLRb, DTWb, dt_b, negA, BCv, XI,
                                             SLOTINV, DAp, DBXp);
  recur_kernel<<<384, 256, 0, stream>>>(DAp, DBXp, Hb, SLOT_PACK, LSTART, NLEV);
  ln_kernel<<<ROWS, 256, 0, stream>>>(Hb, CCv, XI, Dp, gamma, beta, Z, YLN);
  gemm_out<<<dim3(4, 64), 512, 0, stream>>>(YLN, W2t, out, DIN, DMOD);
}

// Round 9
// 272.856 us; speedup vs baseline: 1.1997x; 1.0761x over previous
//
#include <hip/hip_runtime.h>
#include <math.h>

// TreeMambaLayer: B=4, N=2048, D_MODEL=768, D_INNER=1536, DT_RANK=48
// Round 17: (a) ln_kernel -> vectorized uint4 loads (192 thr/row, 8 bf16
// per thread; was 2B/lane scalar on 100MB traffic); (b) recur -> XCD-
// contiguous block remap (col-adjacent blocks share 64B lines; keep them
// on one XCD's L2). GEMMs frozen from R16.

#define ROWS 8192
#define DIN 1536
#define DMOD 768
#define NSEQ 2048
#define DTR 48
#define NSPLIT 4

typedef __bf16 bfrag __attribute__((ext_vector_type(8)));
typedef float f4 __attribute__((ext_vector_type(4)));

__device__ __forceinline__ unsigned short f2bf(float f) {
  unsigned int u = __float_as_uint(f);
  unsigned int r = (u + 0x7fffu + ((u >> 16) & 1u)) >> 16;
  return (unsigned short)r;
}
__device__ __forceinline__ float bf2f(unsigned short h) {
  return __uint_as_float(((unsigned int)h) << 16);
}

__device__ __forceinline__ void gld_lds16(const void* g, void* l) {
  __builtin_amdgcn_global_load_lds((const __attribute__((address_space(1))) void*)g,
                                   (__attribute__((address_space(3))) void*)l, 16, 0, 0);
}

// raw barrier: no vmcnt drain; compiler-level memory fence only.
__device__ __forceinline__ void barx() {
  asm volatile("" ::: "memory");
  __builtin_amdgcn_s_barrier();
  asm volatile("" ::: "memory");
}

// ---------------- 256x192 2-phase bf16 GEMM, C = A(MxK) * Bt(NxK)^T
// cols < DIN -> XI bf16; cols >= DIN -> Z = silu, bf16.
// 8 waves (2M x 4N), per-wave 128x48 out. BK=64, LDS 112KB dbuf.
__global__ __launch_bounds__(512, 1) void gemm256_silu(
    const unsigned short* __restrict__ A, const unsigned short* __restrict__ Bt,
    unsigned short* __restrict__ XI, unsigned short* __restrict__ Z, int K) {
  __shared__ unsigned short lds[2][(256 + 192) * 64];  // 112KB
  const int tid = threadIdx.x;
  const int w = tid >> 6, l = tid & 63;
  const int quad = l >> 4, l16 = l & 15;
  const int wr = w >> 2, wc = w & 3;
  // XCD swizzle: 512 blocks, XCD k owns logical ids [64k,64k+64) = 4 full
  // A-row-panels (16 col-sharers each -> same XCD L2).
  const int h = blockIdx.x + 16 * blockIdx.y;
  const int swz = (h & 7) * 64 + (h >> 3);
  const int row0 = (swz >> 4) * 256, col0 = (swz & 15) * 192;
  const int nt = K >> 6;

  const int srow = tid >> 3;
  const int schunk = ((tid & 7) ^ (srow & 7)) * 8;
  const unsigned short* aS = A + (size_t)(row0 + srow) * K + schunk;
  const unsigned short* bS = Bt + (size_t)(col0 + srow) * K + schunk;

#define STG_A(bufi, q, kt)                                     \
  gld_lds16(aS + (size_t)((q) * 64) * K + (size_t)(kt) * 64,   \
            (char*)&lds[bufi][(q) * 4096] + w * 1024)
#define STG_B(bufi, q, kt)                                     \
  gld_lds16(bS + (size_t)((q) * 64) * K + (size_t)(kt) * 64,   \
            (char*)&lds[bufi][16384 + (q) * 4096] + w * 1024)

  const int arow = (wr * 128 + l16) * 64;
  const int brow = (wc * 48 + l16) * 64;
  int cs[2];
  cs[0] = (quad ^ (l16 & 7)) * 8;
  cs[1] = ((4 + quad) ^ (l16 & 7)) * 8;

#define RDA(m, ks) (*(const bfrag*)(const void*)(LA + arow + (m) * 1024 + cs[ks]))
#define RDB(n, ks) (*(const bfrag*)(const void*)(LB + brow + (n) * 1024 + cs[ks]))

  f4 acc[8][3];
#pragma unroll
  for (int m = 0; m < 8; m++)
#pragma unroll
    for (int n = 0; n < 3; n++) acc[m][n] = (f4){0.f, 0.f, 0.f, 0.f};

  const int kt1 = (nt > 1) ? 1 : 0;
#pragma unroll
  for (int q = 0; q < 4; q++) STG_A(0, q, 0);
#pragma unroll
  for (int q = 0; q < 3; q++) STG_B(0, q, 0);
#pragma unroll
  for (int q = 0; q < 4; q++) STG_A(1, q, kt1);
#pragma unroll
  for (int q = 0; q < 3; q++) STG_B(1, q, kt1);
  asm volatile("s_waitcnt vmcnt(7)" ::: "memory");
  barx();

  for (int t = 0; t < nt; ++t) {
    const int b = t & 1;
    const unsigned short* LA = &lds[b][0];
    const unsigned short* LB = &lds[b][16384];
    const int kA = (t + 2 < nt) ? (t + 2) : (nt - 1);
    bfrag af[4][2], bfr[3][2];

    // ---- P0: read A m0-3 + B n0-2; MFMA (m-lo, all n)
#pragma unroll
    for (int m = 0; m < 4; m++) {
      af[m][0] = RDA(m, 0);
      af[m][1] = RDA(m, 1);
    }
#pragma unroll
    for (int n = 0; n < 3; n++) {
      bfr[n][0] = RDB(n, 0);
      bfr[n][1] = RDB(n, 1);
    }
    barx();
    __builtin_amdgcn_s_setprio(1);
#pragma unroll
    for (int m = 0; m < 4; m++)
#pragma unroll
      for (int n = 0; n < 3; n++) {
        acc[m][n] = __builtin_amdgcn_mfma_f32_16x16x32_bf16(af[m][0], bfr[n][0], acc[m][n], 0, 0, 0);
        acc[m][n] = __builtin_amdgcn_mfma_f32_16x16x32_bf16(af[m][1], bfr[n][1], acc[m][n], 0, 0, 0);
      }
    __builtin_amdgcn_s_setprio(0);
    barx();

    // ---- P1: read A m4-7; stage t+2 A-Q0,Q2 + B (consumed in P0)
#pragma unroll
    for (int m = 0; m < 4; m++) {
      af[m][0] = RDA(m + 4, 0);
      af[m][1] = RDA(m + 4, 1);
    }
    STG_A(b, 0, kA);
    STG_A(b, 2, kA);
    STG_B(b, 0, kA);
    STG_B(b, 1, kA);
    STG_B(b, 2, kA);
    barx();  // all waves' A-hi reads done -> Q1/Q3 stage safe
    STG_A(b, 1, kA);
    STG_A(b, 3, kA);
    __builtin_amdgcn_s_setprio(1);
#pragma unroll
    for (int m = 0; m < 4; m++)
#pragma unroll
      for (int n = 0; n < 3; n++) {
        acc[m + 4][n] = __builtin_amdgcn_mfma_f32_16x16x32_bf16(af[m][0], bfr[n][0], acc[m + 4][n], 0, 0, 0);
        acc[m + 4][n] = __builtin_amdgcn_mfma_f32_16x16x32_bf16(af[m][1], bfr[n][1], acc[m + 4][n], 0, 0, 0);
      }
    __builtin_amdgcn_s_setprio(0);
    asm volatile("s_waitcnt vmcnt(7)" ::: "memory");
    barx();
  }
  asm volatile("s_waitcnt vmcnt(0)" ::: "memory");

#undef STG_A
#undef STG_B
#undef RDA
#undef RDB

  // epilogue: direct stores (WRITE_SIZE already ideal)
  const bool is_z = (col0 >= DIN);
  unsigned short* dst = is_z ? Z : XI;
  const int cb = col0 + wc * 48 + l16 - (is_z ? DIN : 0);
#pragma unroll
  for (int m = 0; m < 8; m++) {
    const int rb = row0 + wr * 128 + m * 16 + quad * 4;
#pragma unroll
    for (int n = 0; n < 3; n++)
#pragma unroll
      for (int r = 0; r < 4; r++) {
        float v = acc[m][n][r];
        if (is_z) v = v / (1.f + __expf(-v));
        dst[(size_t)(rb + r) * DIN + cb + n * 16] = f2bf(v);
      }
  }
}

// ---------------- 128x192 out_proj GEMM, C(fp32) = A(MxK) * Bt(NxK)^T
// grid (4, 64) = 256 blocks, 8 waves (2M x 4N), per-wave 64x48 out.
// BK=64, LDS 80KB dbuf -> 2 blocks/CU (4 waves/SIMD).
__global__ __launch_bounds__(512, 2) void gemm_out(
    const unsigned short* __restrict__ A, const unsigned short* __restrict__ Bt,
    float* __restrict__ C0, int K, int ldc) {
  __shared__ unsigned short lds[2][(128 + 192) * 64];  // 80KB
  const int tid = threadIdx.x;
  const int w = tid >> 6, l = tid & 63;
  const int quad = l >> 4, l16 = l & 15;
  const int wr = w >> 2, wc = w & 3;
  // XCD swizzle: 256 blocks; XCD k owns swz [32k,32k+32) = 8 row-panels.
  const int h = blockIdx.x + 4 * blockIdx.y;
  const int swz = (h & 7) * 32 + (h >> 3);
  const int row0 = (swz >> 2) * 128, col0 = (swz & 3) * 192;
  const int nt = K >> 6;  // 24

  const int srow = tid >> 3;
  const int schunk = ((tid & 7) ^ (srow & 7)) * 8;
  const unsigned short* aS = A + (size_t)(row0 + srow) * K + schunk;
  const unsigned short* bS = Bt + (size_t)(col0 + srow) * K + schunk;

#define STG_A(bufi, q, kt)                                     \
  gld_lds16(aS + (size_t)((q) * 64) * K + (size_t)(kt) * 64,   \
            (char*)&lds[bufi][(q) * 4096] + w * 1024)
#define STG_B(bufi, q, kt)                                     \
  gld_lds16(bS + (size_t)((q) * 64) * K + (size_t)(kt) * 64,   \
            (char*)&lds[bufi][8192 + (q) * 4096] + w * 1024)

  const int arow = (wr * 64 + l16) * 64;
  const int brow = (wc * 48 + l16) * 64;
  int cs[2];
  cs[0] = (quad ^ (l16 & 7)) * 8;
  cs[1] = ((4 + quad) ^ (l16 & 7)) * 8;

#define RDA(m, ks) (*(const bfrag*)(const void*)(LA + arow + (m) * 1024 + cs[ks]))
#define RDB(n, ks) (*(const bfrag*)(const void*)(LB + brow + (n) * 1024 + cs[ks]))

  f4 acc[4][3];
#pragma unroll
  for (int m = 0; m < 4; m++)
#pragma unroll
    for (int n = 0; n < 3; n++) acc[m][n] = (f4){0.f, 0.f, 0.f, 0.f};

  const int kt1 = (nt > 1) ? 1 : 0;
#pragma unroll
  for (int q = 0; q < 2; q++) STG_A(0, q, 0);
#pragma unroll
  for (int q = 0; q < 3; q++) STG_B(0, q, 0);
#pragma unroll
  for (int q = 0; q < 2; q++) STG_A(1, q, kt1);
#pragma unroll
  for (int q = 0; q < 3; q++) STG_B(1, q, kt1);
  asm volatile("s_waitcnt vmcnt(5)" ::: "memory");
  barx();

  for (int t = 0; t < nt; ++t) {
    const int b = t & 1;
    const unsigned short* LA = &lds[b][0];
    const unsigned short* LB = &lds[b][8192];
    const int kA = (t + 2 < nt) ? (t + 2) : (nt - 1);
    bfrag af[4][2], bfr[3][2];

#pragma unroll
    for (int m = 0; m < 4; m++) {
      af[m][0] = RDA(m, 0);
      af[m][1] = RDA(m, 1);
    }
#pragma unroll
    for (int n = 0; n < 3; n++) {
      bfr[n][0] = RDB(n, 0);
      bfr[n][1] = RDB(n, 1);
    }
    asm volatile("s_waitcnt lgkmcnt(0)" ::: "memory");
    barx();  // all waves' reads landed -> safe to DMA-overwrite buf b
    STG_A(b, 0, kA);
    STG_A(b, 1, kA);
    STG_B(b, 0, kA);
    STG_B(b, 1, kA);
    STG_B(b, 2, kA);
    __builtin_amdgcn_s_setprio(1);
#pragma unroll
    for (int m = 0; m < 4; m++)
#pragma unroll
      for (int n = 0; n < 3; n++) {
        acc[m][n] = __builtin_amdgcn_mfma_f32_16x16x32_bf16(af[m][0], bfr[n][0], acc[m][n], 0, 0, 0);
        acc[m][n] = __builtin_amdgcn_mfma_f32_16x16x32_bf16(af[m][1], bfr[n][1], acc[m][n], 0, 0, 0);
      }
    __builtin_amdgcn_s_setprio(0);
    asm volatile("s_waitcnt vmcnt(5)" ::: "memory");
    barx();
  }
  asm volatile("s_waitcnt vmcnt(0)" ::: "memory");

#undef STG_A
#undef STG_B
#undef RDA
#undef RDB

  const int cb = col0 + wc * 48 + l16;
#pragma unroll
  for (int m = 0; m < 4; m++) {
    const int rb = row0 + wr * 64 + m * 16 + quad * 4;
#pragma unroll
    for (int n = 0; n < 3; n++)
#pragma unroll
      for (int r = 0; r < 4; r++)
        C0[(size_t)(rb + r) * ldc + cb + n * 16] = acc[m][n][r];
  }
}

// ------------------- prep1 (1024 thr): sched (block 0) + all flat casts
// SLOT_PACK[slot] = node | ((pnode+1)<<12); SLOTINV[node] = slot.
__global__ __launch_bounds__(1024) void prep1_kernel(
    const int* __restrict__ sidx, const int* __restrict__ spar,
    int* __restrict__ SLOT_PACK, int* __restrict__ SLOTINV,
    int* __restrict__ LSTART, int* __restrict__ NLEV,
    const float* __restrict__ x, unsigned short* __restrict__ Xbf,
    const float* __restrict__ xpw, unsigned short* __restrict__ XPW,
    const float* __restrict__ dtw, unsigned short* __restrict__ DTWb,
    const float* __restrict__ A_log, float* __restrict__ negA) {
  const int bi = blockIdx.x;
  const int tid = threadIdx.x;
  if (bi == 0) {
    __shared__ int par[2048], idx[2048], ancA[2048], ancB[2048], rnkA[2048], rnkB[2048];
    __shared__ int dmax;
    for (int i = tid; i < 2048; i += 1024) {
      const int p = spar[i];
      par[i] = p;
      idx[i] = sidx[i];
      ancA[i] = (p < 0) ? -1 : p;
      rnkA[i] = (p < 0) ? 0 : 1;
    }
    if (tid == 0) dmax = 0;
    __syncthreads();
    for (int r = 0; r < 11; r++) {
      int* ca = (r & 1) ? ancB : ancA;
      int* cr = (r & 1) ? rnkB : rnkA;
      int* na = (r & 1) ? ancA : ancB;
      int* nr = (r & 1) ? rnkA : rnkB;
      for (int i = tid; i < 2048; i += 1024) {
        const int a = ca[i], rv = cr[i];
        if (a >= 0) {
          nr[i] = rv + cr[a];
          na[i] = ca[a];
        } else {
          nr[i] = rv;
          na[i] = a;
        }
      }
      __syncthreads();
    }
    for (int i = tid; i < 2048; i += 1024) ancA[i] = 0;
    __syncthreads();
    for (int i = tid; i < 2048; i += 1024) {
      atomicAdd(&ancA[rnkB[i]], 1);
      atomicMax(&dmax, rnkB[i]);
    }
    __syncthreads();
    for (int s = 0; s < 11; s++) {
      const int off = 1 << s;
      int* cur = (s & 1) ? ancB : ancA;
      int* nxt = (s & 1) ? ancA : ancB;
      for (int i = tid; i < 2048; i += 1024) {
        int v = cur[i];
        if (i >= off) v += cur[i - off];
        nxt[i] = v;
      }
      __syncthreads();
    }
    for (int i = tid; i < 2049; i += 1024) {
      const int v = (i == 0) ? 0 : ancB[i - 1];
      LSTART[i] = v;
      if (i < 2048) rnkA[i] = v;
    }
    if (tid == 0) NLEV[0] = dmax + 1;
    __syncthreads();
    for (int i = tid; i < 2048; i += 1024) {
      const int d = rnkB[i];
      const int slot = atomicAdd(&rnkA[d], 1);
      const int node = idx[i];
      const int p = par[i];
      const int pn = (p < 0) ? -1 : idx[p];
      SLOT_PACK[slot] = node | ((pn + 1) << 12);
      SLOTINV[node] = slot;
    }
  } else if (bi < 1 + 1536) {
    const int i = ((bi - 1) * 1024 + tid) * 4;
    const float4 v = *(const float4*)(x + i);
    union { unsigned short h[4]; uint2 u; } pk;
    pk.h[0] = f2bf(v.x);
    pk.h[1] = f2bf(v.y);
    pk.h[2] = f2bf(v.z);
    pk.h[3] = f2bf(v.w);
    *(uint2*)(Xbf + i) = pk.u;
  } else if (bi < 1 + 1536 + 96) {
    const int i = (bi - 1537) * 1024 + tid;  // 64*1536
    const int c = i / 1536, k = i % 1536;
    XPW[i] = (c < 50) ? f2bf(xpw[(size_t)k * 50 + c]) : (unsigned short)0;
  } else if (bi < 1 + 1536 + 96 + 96) {
    const int i = (bi - 1633) * 1024 + tid;  // 1536*64
    const int d = i >> 6, k = i & 63;
    DTWb[i] = (k < 48) ? f2bf(dtw[(size_t)k * DIN + d]) : (unsigned short)0;
  } else {
    const int i = (bi - 1729) * 1024 + tid;
    if (i < DIN) negA[i] = -__expf(A_log[i]);
  }
}

// ------------------- prep2 (256 thr): both weight transposes, fp32 -> bf16^T
__global__ __launch_bounds__(256) void prep2_kernel(
    const float* __restrict__ W1, unsigned short* __restrict__ W1t,
    const float* __restrict__ W2, unsigned short* __restrict__ W2t) {
  __shared__ float t[32][33];
  int idx = blockIdx.x;
  const float* W;
  unsigned short* Wt;
  int K, N, n0, k0;
  if (idx < 2304) {  // in_proj: K=768, N=3072 -> 96x24 tiles
    W = W1; Wt = W1t; K = DMOD; N = 2 * DIN;
    n0 = (idx % 96) * 32; k0 = (idx / 96) * 32;
  } else {           // out_proj: K=1536, N=768 -> 24x48 tiles
    idx -= 2304;
    W = W2; Wt = W2t; K = DIN; N = DMOD;
    n0 = (idx % 24) * 32; k0 = (idx / 24) * 32;
  }
  const int tx = threadIdx.x & 31, ty = threadIdx.x >> 5;
  for (int i = ty; i < 32; i += 8) t[i][tx] = W[(size_t)(k0 + i) * N + n0 + tx];
  __syncthreads();
  for (int i = ty; i < 32; i += 8)
    Wt[(size_t)(n0 + i) * K + k0 + tx] = f2bf(t[tx][i]);
}

// ------------------------------------------------- x_dbl: split-K bf16 MFMA
__global__ __launch_bounds__(256) void xdbl_mfma(
    const unsigned short* __restrict__ XI, const unsigned short* __restrict__ XPW,
    float* __restrict__ XP) {
  __shared__ unsigned short As[128 * 32];
  __shared__ unsigned short Bs[64 * 32];
  const int tid = threadIdx.x;
  const int w = tid >> 6, l = tid & 63;
  const int quad = l >> 4, l16 = l & 15;
  // XCD swizzle: 256 blocks; XCD k gets y in [8k,8k+8) with all 4 splits.
  const int h = blockIdx.x + 4 * blockIdx.y;
  const int swz = (h & 7) * 32 + (h >> 3);
  const int split = swz & 3;
  const int row0 = (swz >> 2) * 128;
  const int kbase = split * (DIN / NSPLIT);  // 384

  f4 acc[2][4];
#pragma unroll
  for (int i = 0; i < 2; i++)
#pragma unroll
    for (int j = 0; j < 4; j++) acc[i][j] = (f4){0.f, 0.f, 0.f, 0.f};

  const int srow = w * 16 + (l >> 2);
  const int kcol = (((l & 3) ^ ((l >> 2) & 3)) * 8);
  const int qs = (quad ^ (l16 & 3)) * 8;

  for (int c = 0; c < 12; c++) {
    const int k0 = kbase + c * 32;
#pragma unroll
    for (int r = 0; r < 2; r++) {
      gld_lds16(XI + (size_t)(row0 + srow + r * 64) * DIN + k0 + kcol,
                (char*)As + r * 4096 + w * 1024);
    }
    gld_lds16(XPW + (size_t)srow * DIN + k0 + kcol, (char*)Bs + w * 1024);
    __syncthreads();
    bfrag af[2], bf[4];
#pragma unroll
    for (int i = 0; i < 2; i++)
      af[i] = *(const bfrag*)(const void*)(As + (w * 32 + i * 16 + l16) * 32 + qs);
#pragma unroll
    for (int j = 0; j < 4; j++)
      bf[j] = *(const bfrag*)(const void*)(Bs + (j * 16 + l16) * 32 + qs);
#pragma unroll
    for (int i = 0; i < 2; i++)
#pragma unroll
      for (int j = 0; j < 4; j++)
        acc[i][j] = __builtin_amdgcn_mfma_f32_16x16x32_bf16(af[i], bf[j], acc[i][j], 0, 0, 0);
    __syncthreads();
  }

  float* dst = XP + (size_t)split * ROWS * 64 + (size_t)row0 * 64;
#pragma unroll
  for (int i = 0; i < 2; i++) {
    const int rb = w * 32 + i * 16 + quad * 4;
#pragma unroll
    for (int j = 0; j < 4; j++) {
      const int col = j * 16 + l16;
#pragma unroll
      for (int r = 0; r < 4; r++) dst[(size_t)(rb + r) * 64 + col] = acc[i][j][r];
    }
  }
}

// -------------------------- reduce XP partials -> DTLRb bf16 + BC/CC fp32
__global__ __launch_bounds__(256) void xp_reduce(
    const float* __restrict__ XP, unsigned short* __restrict__ DTLRb,
    float* __restrict__ BCv, float* __restrict__ CCv) {
  const int i = blockIdx.x * 256 + threadIdx.x;  // 8192*16
  const int row = i >> 4, c4 = (i & 15) * 4;
  const float* p = XP + (size_t)row * 64 + c4;
  float4 s = make_float4(0.f, 0.f, 0.f, 0.f);
#pragma unroll
  for (int sp = 0; sp < NSPLIT; sp++) {
    const float4 v = *(const float4*)(p + (size_t)sp * ROWS * 64);
    s.x += v.x;
    s.y += v.y;
    s.z += v.z;
    s.w += v.w;
  }
  if (c4 == 48) {
    BCv[row] = s.x;
    CCv[row] = s.y;
  }
  union { unsigned short h[4]; uint2 u; } pk;
  pk.h[0] = f2bf(s.x);
  pk.h[1] = f2bf(s.y);
  pk.h[2] = f2bf(s.z);
  pk.h[3] = f2bf(s.w);
  *(uint2*)(DTLRb + (size_t)row * 64 + c4) = pk.u;
}

// ------- dt GEMM (K=64) -> dA/dBx bf16, rows permuted to slot order.
// grid (12, 128). 64 rows x 128 cols per block. XCD-swizzled.
__global__ __launch_bounds__(256) void dt_gemm(
    const unsigned short* __restrict__ DTLRb, const unsigned short* __restrict__ DTWb,
    const float* __restrict__ bias, const float* __restrict__ negA,
    const float* __restrict__ BCv, const unsigned short* __restrict__ XI,
    const int* __restrict__ SLOTINV,
    unsigned short* __restrict__ DAp, unsigned short* __restrict__ DBXp) {
  __shared__ unsigned short As[2][64 * 32];
  __shared__ unsigned short Bs[2][128 * 32];
  __shared__ int sinv[64];
  __shared__ float bcs[64];
  const int tid = threadIdx.x;
  const int w = tid >> 6, l = tid & 63;
  const int quad = l >> 4, l16 = l & 15;
  const int wrow = (w >> 1) * 32, wcol = (w & 1) * 64;
  // XCD swizzle: 1536 blocks = 8 x 192 (bijective).
  const int h = blockIdx.x + 12 * blockIdx.y;
  const int swz = (h & 7) * 192 + (h >> 3);
  const int row0 = (swz / 12) * 64, col0 = (swz % 12) * 128;
  const int p0 = row0 & (NSEQ - 1);       // position base (batch-local)
  const int bbase = row0 & ~(NSEQ - 1);   // b*2048
  const int srow = w * 16 + (l >> 2);
  const int koff = (((l & 3) ^ ((l >> 2) & 3)) * 8);
  const int qs = (quad ^ (l16 & 3)) * 8;

#pragma unroll
  for (int c = 0; c < 2; c++) {
    gld_lds16(DTLRb + (size_t)(row0 + srow) * 64 + c * 32 + koff,
              (char*)As[c] + w * 1024);
#pragma unroll
    for (int r = 0; r < 2; r++)
      gld_lds16(DTWb + (size_t)(col0 + srow + r * 64) * 64 + c * 32 + koff,
                (char*)Bs[c] + r * 4096 + w * 1024);
  }
  if (tid < 64) {
    sinv[tid] = SLOTINV[p0 + tid];
    bcs[tid] = BCv[row0 + tid];
  }
  __syncthreads();

  f4 acc[2][4];
#pragma unroll
  for (int i = 0; i < 2; i++)
#pragma unroll
    for (int j = 0; j < 4; j++) acc[i][j] = (f4){0.f, 0.f, 0.f, 0.f};

#pragma unroll
  for (int c = 0; c < 2; c++) {
    bfrag af[2], bf[4];
#pragma unroll
    for (int i = 0; i < 2; i++)
      af[i] = *(const bfrag*)(const void*)(As[c] + (wrow + i * 16 + l16) * 32 + qs);
#pragma unroll
    for (int j = 0; j < 4; j++)
      bf[j] = *(const bfrag*)(const void*)(Bs[c] + (wcol + j * 16 + l16) * 32 + qs);
#pragma unroll
    for (int i = 0; i < 2; i++)
#pragma unroll
      for (int j = 0; j < 4; j++)
        acc[i][j] = __builtin_amdgcn_mfma_f32_16x16x32_bf16(af[i], bf[j], acc[i][j], 0, 0, 0);
  }

  float bj[4], aj[4];
#pragma unroll
  for (int j = 0; j < 4; j++) {
    const int d = col0 + wcol + j * 16 + l16;
    bj[j] = bias[d];
    aj[j] = negA[d];
  }
#pragma unroll
  for (int i = 0; i < 2; i++) {
#pragma unroll
    for (int r = 0; r < 4; r++) {
      const int row_l = wrow + i * 16 + quad * 4 + r;
      const int row = row0 + row_l;
      const float bc = bcs[row_l];
      const size_t rp = (size_t)(bbase + sinv[row_l]) * DIN;
#pragma unroll
      for (int j = 0; j < 4; j++) {
        const int d = col0 + wcol + j * 16 + l16;
        const float s = acc[i][j][r] + bj[j];
        const float sp = fmaxf(s, 0.f) + __logf(1.f + __expf(-fabsf(s)));
        const float xi = bf2f(XI[(size_t)row * DIN + d]);
        DAp[rp + d] = f2bf(__expf(sp * aj[j]));
        DBXp[rp + d] = f2bf(sp * bc * xi);
      }
    }
  }
}

// ----------------- tree recurrence: h resident in LDS, slot-ordered loads
// block owns 16 bf16 columns (2 chunks of 8); h[node][16] in LDS (64KB).
// XCD-contiguous remap: col-adjacent blocks (sharing 64B lines of
// DAp/DBXp/Hb rows) land on the same XCD's L2.
__global__ __launch_bounds__(256) void recur_kernel(
    const unsigned short* __restrict__ DAp, const unsigned short* __restrict__ DBXp,
    unsigned short* __restrict__ Hb,
    const int* __restrict__ SLOT_PACK, const int* __restrict__ LSTART,
    const int* __restrict__ NLEV) {
  __shared__ unsigned short hl[NSEQ * 16];  // 64 KB
  __shared__ int spack[NSEQ];               // 8 KB
  __shared__ int lst[258];                  // ~1 KB
  const int tid = threadIdx.x;
  const int bid = blockIdx.x;               // 384 = 8 x 48
  const int logical = (bid & 7) * 48 + (bid >> 3);
  const int c8a = logical * 2;              // both chunks in same batch
  const int b = c8a / 192;
  const int d8a = c8a % 192;
  const int nlev = NLEV[0];
  for (int i = tid; i < NSEQ; i += 256) spack[i] = SLOT_PACK[i];
  const int nl = (nlev + 1 < 258) ? nlev + 1 : 258;
  for (int i = tid; i < nl; i += 256) lst[i] = LSTART[i];
  __syncthreads();

  for (int L = 0; L < nlev; L++) {
    const int s0 = (L < 257) ? lst[L] : LSTART[L];
    const int s1 = (L + 1 < 258) ? lst[L + 1] : LSTART[L + 1];
    const int items = (s1 - s0) * 2;
    for (int it = tid; it < items; it += 256) {
      const int s = s0 + (it >> 1);
      const int ch = it & 1;
      const size_t goff = (size_t)(b * NSEQ + s) * DIN + (d8a + ch) * 8;
      union { uint4 u; unsigned short h[8]; } da, dbx, hpu, hvu;
      da.u = *(const uint4*)(DAp + goff);
      dbx.u = *(const uint4*)(DBXp + goff);
      const int pk = spack[s];
      const int node = pk & 4095;
      const int pn = (pk >> 12) - 1;
      float hp[8];
      if (pn >= 0) {
        hpu.u = *(const uint4*)(hl + pn * 16 + ch * 8);
#pragma unroll
        for (int e = 0; e < 8; e++) hp[e] = bf2f(hpu.h[e]);
      } else {
#pragma unroll
        for (int e = 0; e < 8; e++) hp[e] = 0.f;
      }
#pragma unroll
      for (int e = 0; e < 8; e++) {
        const float hv = fmaf(bf2f(da.h[e]), hp[e], bf2f(dbx.h[e]));
        hvu.h[e] = f2bf(hv);
      }
      *(uint4*)(hl + node * 16 + ch * 8) = hvu.u;
    }
    __syncthreads();
  }

  // flush h to global (node-major for ln)
  for (int i = tid; i < NSEQ * 2; i += 256) {
    const int node = i >> 1, ch = i & 1;
    *(uint4*)(Hb + (size_t)(b * NSEQ + node) * DIN + (d8a + ch) * 8) =
        *(const uint4*)(hl + node * 16 + ch * 8);
  }
}

// --------------- y, layernorm, z-gate -> bf16 (vectorized, 192 thr/row)
__global__ __launch_bounds__(192) void ln_kernel(
    const unsigned short* __restrict__ Hb, const float* __restrict__ CCv,
    const unsigned short* __restrict__ XI, const float* __restrict__ Dp,
    const float* __restrict__ gamma, const float* __restrict__ beta,
    const unsigned short* __restrict__ Z, unsigned short* __restrict__ YLN) {
  const int row = blockIdx.x;
  const int tid = threadIdx.x;   // 0..191
  const int d8 = tid * 8;        // 8 bf16 per thread, 192*8 = 1536
  const float C = CCv[row];
  const size_t base = (size_t)row * DIN + d8;
  union U { uint4 u; unsigned short h[8]; };
  U hu, xu;
  hu.u = *(const uint4*)(Hb + base);
  xu.u = *(const uint4*)(XI + base);
  float dp[8];
  *(float4*)(dp) = *(const float4*)(Dp + d8);
  *(float4*)(dp + 4) = *(const float4*)(Dp + d8 + 4);
  float y[8];
  float s = 0.f, s2 = 0.f;
#pragma unroll
  for (int e = 0; e < 8; e++) {
    const float v = fmaf(bf2f(hu.h[e]), C, dp[e] * bf2f(xu.h[e]));
    y[e] = v;
    s += v;
    s2 = fmaf(v, v, s2);
  }
#pragma unroll
  for (int off = 32; off >= 1; off >>= 1) {
    s += __shfl_down(s, off);
    s2 += __shfl_down(s2, off);
  }
  __shared__ float rs[3], rs2[3];
  const int w = tid >> 6;
  if ((tid & 63) == 0) {
    rs[w] = s;
    rs2[w] = s2;
  }
  __syncthreads();
  const float ts = rs[0] + rs[1] + rs[2];
  const float ts2 = rs2[0] + rs2[1] + rs2[2];
  const float mu = ts * (1.f / 1536.f);
  const float var = ts2 * (1.f / 1536.f) - mu * mu;
  const float inv = rsqrtf(var + 1e-5f);
  float g[8], bb[8];
  *(float4*)(g) = *(const float4*)(gamma + d8);
  *(float4*)(g + 4) = *(const float4*)(gamma + d8 + 4);
  *(float4*)(bb) = *(const float4*)(beta + d8);
  *(float4*)(bb + 4) = *(const float4*)(beta + d8 + 4);
  U zu, out;
  zu.u = *(const uint4*)(Z + base);
#pragma unroll
  for (int e = 0; e < 8; e++) {
    const float o = (y[e] - mu) * inv * g[e] + bb[e];
    out.h[e] = f2bf(o * bf2f(zu.h[e]));
  }
  *(uint4*)(YLN + base) = out.u;
}

// ---------------------------------------------------------------------- launch
extern "C" void kernel_launch(void* const* d_in, const int* in_sizes, int n_in,
                              void* d_out, int out_size, void* d_ws, size_t ws_size,
                              hipStream_t stream) {
  const float* x = (const float*)d_in[0];
  const int* sidx = (const int*)d_in[1];
  const int* spar = (const int*)d_in[2];
  const float* in_proj = (const float*)d_in[3];
  const float* x_proj = (const float*)d_in[4];
  const float* dt_proj = (const float*)d_in[5];
  const float* dt_b = (const float*)d_in[6];
  const float* A_log = (const float*)d_in[7];
  const float* Dp = (const float*)d_in[8];
  const float* gamma = (const float*)d_in[9];
  const float* beta = (const float*)d_in[10];
  const float* out_proj = (const float*)d_in[11];
  float* out = (float*)d_out;

  char* p = (char*)d_ws;
  const size_t RC = (size_t)ROWS * DIN;
  unsigned short* XI = (unsigned short*)p;   p += RC * 2;   // 25.2 MB
  unsigned short* Z = (unsigned short*)p;    p += RC * 2;   // 25.2 MB
  unsigned short* DAp = (unsigned short*)p;  p += RC * 2;   // 25.2 MB
  unsigned short* DBXp = (unsigned short*)p; p += RC * 2;   // 25.2 MB
  unsigned short* Hb = (unsigned short*)p;   p += RC * 2;   // 25.2 MB
  float* XP = (float*)p;                     p += (size_t)NSPLIT * ROWS * 64 * 4;  // 8.4 MB
  unsigned short* DTLRb = (unsigned short*)p; p += (size_t)ROWS * 64 * 2;          // 1 MB
  float* BCv = (float*)p;                    p += ROWS * 4;
  float* CCv = (float*)p;                    p += ROWS * 4;
  float* negA = (float*)p;                   p += DIN * 4;
  unsigned short* Xbf = (unsigned short*)p;  p += (size_t)ROWS * DMOD * 2;         // 12.6 MB
  unsigned short* W1t = (unsigned short*)p;  p += (size_t)2 * DIN * DMOD * 2;      // 4.7 MB
  unsigned short* W2t = (unsigned short*)p;  p += (size_t)DMOD * DIN * 2;          // 2.4 MB
  unsigned short* XPW = (unsigned short*)p;  p += (size_t)64 * DIN * 2;
  unsigned short* DTWb = (unsigned short*)p; p += (size_t)DIN * 64 * 2;
  int* ipart = (int*)p;
  int* SLOT_PACK = ipart;
  int* SLOTINV = ipart + 2048;
  int* LSTART = ipart + 4096;
  int* NLEV = ipart + 4096 + 2049;
  unsigned short* YLN = DAp;  // DAp dead after recur; reuse for LN output

  prep1_kernel<<<1731, 1024, 0, stream>>>(sidx, spar, SLOT_PACK, SLOTINV,
                                          LSTART, NLEV, x, Xbf, x_proj, XPW,
                                          dt_proj, DTWb, A_log, negA);
  prep2_kernel<<<3456, 256, 0, stream>>>(in_proj, W1t, out_proj, W2t);
  gemm256_silu<<<dim3(16, 32), 512, 0, stream>>>(Xbf, W1t, XI, Z, DMOD);
  xdbl_mfma<<<dim3(NSPLIT, 64), 256, 0, stream>>>(XI, XPW, XP);
  xp_reduce<<<ROWS * 16 / 256, 256, 0, stream>>>(XP, DTLRb, BCv, CCv);
  dt_gemm<<<dim3(12, 128), 256, 0, stream>>>(DTLRb, DTWb, dt_b, negA, BCv, XI,
                                             SLOTINV, DAp, DBXp);
  recur_kernel<<<384, 256, 0, stream>>>(DAp, DBXp, Hb, SLOT_PACK, LSTART, NLEV);
  ln_kernel<<<ROWS, 192, 0, stream>>>(Hb, CCv, XI, Dp, gamma, beta, Z, YLN);
  gemm_out<<<dim3(4, 64), 512, 0, stream>>>(YLN, W2t, out, DIN, DMOD);
}

// Round 10
// 267.187 us; speedup vs baseline: 1.2252x; 1.0212x over previous
//
#include <hip/hip_runtime.h>
#include <math.h>

// TreeMambaLayer: B=4, N=2048, D_MODEL=768, D_INNER=1536, DT_RANK=48
// Round 18: unify both big GEMMs on the gemm_out structure (measured ~840
// TF/FLOP vs gemm256's 660): 128x192 tile, 80KB LDS dbuf -> 2 blocks/CU
// (4 waves/SIMD cross-block overlap), single compute phase, counted
// vmcnt(5), XCD swizzle. in_proj grid (16,64)=1024 = 4 perfect rounds.
// Rest frozen from R17.

#define ROWS 8192
#define DIN 1536
#define DMOD 768
#define NSEQ 2048
#define DTR 48
#define NSPLIT 4

typedef __bf16 bfrag __attribute__((ext_vector_type(8)));
typedef float f4 __attribute__((ext_vector_type(4)));

__device__ __forceinline__ unsigned short f2bf(float f) {
  unsigned int u = __float_as_uint(f);
  unsigned int r = (u + 0x7fffu + ((u >> 16) & 1u)) >> 16;
  return (unsigned short)r;
}
__device__ __forceinline__ float bf2f(unsigned short h) {
  return __uint_as_float(((unsigned int)h) << 16);
}

__device__ __forceinline__ void gld_lds16(const void* g, void* l) {
  __builtin_amdgcn_global_load_lds((const __attribute__((address_space(1))) void*)g,
                                   (__attribute__((address_space(3))) void*)l, 16, 0, 0);
}

// raw barrier: no vmcnt drain; compiler-level memory fence only.
__device__ __forceinline__ void barx() {
  asm volatile("" ::: "memory");
  __builtin_amdgcn_s_barrier();
  asm volatile("" ::: "memory");
}

// ---------------- 128x192 deep-pipeline bf16 GEMM, C = A(MxK) * Bt(NxK)^T
// 8 waves (2M x 4N), per-wave 64x48 out. BK=64, LDS 80KB dbuf -> 2
// blocks/CU. Single compute phase per K-tile: read frags -> lgkm(0) -> bar
// -> stage t+2 (5 loads into current buf) -> MFMA 24 -> vmcnt(5) -> bar.
// MODE 0: fp32 C (ldc). MODE 1: cols<DIN -> XI bf16, cols>=DIN -> Z silu.
// NCOLS: grid col-blocks (192 each); XCD swizzle keeps a row-panel's
// col-sharers on one XCD.
template <int MODE, int NCOLS>
__global__ __launch_bounds__(512, 2) void gemm_dp(
    const unsigned short* __restrict__ A, const unsigned short* __restrict__ Bt,
    void* __restrict__ C0v, void* __restrict__ C1v, int K, int ldc) {
  __shared__ unsigned short lds[2][(128 + 192) * 64];  // 80KB
  const int tid = threadIdx.x;
  const int w = tid >> 6, l = tid & 63;
  const int quad = l >> 4, l16 = l & 15;
  const int wr = w >> 2, wc = w & 3;
  const int h = blockIdx.x + gridDim.x * blockIdx.y;
  const int chunk = (gridDim.x * gridDim.y) >> 3;
  const int swz = (h & 7) * chunk + (h >> 3);
  const int row0 = (swz / NCOLS) * 128, col0 = (swz % NCOLS) * 192;
  const int nt = K >> 6;

  const int srow = tid >> 3;
  const int schunk = ((tid & 7) ^ (srow & 7)) * 8;
  const unsigned short* aS = A + (size_t)(row0 + srow) * K + schunk;
  const unsigned short* bS = Bt + (size_t)(col0 + srow) * K + schunk;

#define STG_A(bufi, q, kt)                                     \
  gld_lds16(aS + (size_t)((q) * 64) * K + (size_t)(kt) * 64,   \
            (char*)&lds[bufi][(q) * 4096] + w * 1024)
#define STG_B(bufi, q, kt)                                     \
  gld_lds16(bS + (size_t)((q) * 64) * K + (size_t)(kt) * 64,   \
            (char*)&lds[bufi][8192 + (q) * 4096] + w * 1024)

  const int arow = (wr * 64 + l16) * 64;
  const int brow = (wc * 48 + l16) * 64;
  int cs[2];
  cs[0] = (quad ^ (l16 & 7)) * 8;
  cs[1] = ((4 + quad) ^ (l16 & 7)) * 8;

#define RDA(m, ks) (*(const bfrag*)(const void*)(LA + arow + (m) * 1024 + cs[ks]))
#define RDB(n, ks) (*(const bfrag*)(const void*)(LB + brow + (n) * 1024 + cs[ks]))

  f4 acc[4][3];
#pragma unroll
  for (int m = 0; m < 4; m++)
#pragma unroll
    for (int n = 0; n < 3; n++) acc[m][n] = (f4){0.f, 0.f, 0.f, 0.f};

  // prologue: stage t0 (5) + t1 (5); wait until t0's 5 landed.
  const int kt1 = (nt > 1) ? 1 : 0;
#pragma unroll
  for (int q = 0; q < 2; q++) STG_A(0, q, 0);
#pragma unroll
  for (int q = 0; q < 3; q++) STG_B(0, q, 0);
#pragma unroll
  for (int q = 0; q < 2; q++) STG_A(1, q, kt1);
#pragma unroll
  for (int q = 0; q < 3; q++) STG_B(1, q, kt1);
  asm volatile("s_waitcnt vmcnt(5)" ::: "memory");
  barx();

  for (int t = 0; t < nt; ++t) {
    const int b = t & 1;
    const unsigned short* LA = &lds[b][0];
    const unsigned short* LB = &lds[b][8192];
    const int kA = (t + 2 < nt) ? (t + 2) : (nt - 1);
    bfrag af[4][2], bfr[3][2];

#pragma unroll
    for (int m = 0; m < 4; m++) {
      af[m][0] = RDA(m, 0);
      af[m][1] = RDA(m, 1);
    }
#pragma unroll
    for (int n = 0; n < 3; n++) {
      bfr[n][0] = RDB(n, 0);
      bfr[n][1] = RDB(n, 1);
    }
    asm volatile("s_waitcnt lgkmcnt(0)" ::: "memory");
    barx();  // all waves' reads landed -> safe to DMA-overwrite buf b
    STG_A(b, 0, kA);
    STG_A(b, 1, kA);
    STG_B(b, 0, kA);
    STG_B(b, 1, kA);
    STG_B(b, 2, kA);
    __builtin_amdgcn_s_setprio(1);
#pragma unroll
    for (int m = 0; m < 4; m++)
#pragma unroll
      for (int n = 0; n < 3; n++) {
        acc[m][n] = __builtin_amdgcn_mfma_f32_16x16x32_bf16(af[m][0], bfr[n][0], acc[m][n], 0, 0, 0);
        acc[m][n] = __builtin_amdgcn_mfma_f32_16x16x32_bf16(af[m][1], bfr[n][1], acc[m][n], 0, 0, 0);
      }
    __builtin_amdgcn_s_setprio(0);
    // tile t+1's 5 loads (issued last tile) landed; t+2's 5 in flight.
    asm volatile("s_waitcnt vmcnt(5)" ::: "memory");
    barx();
  }
  asm volatile("s_waitcnt vmcnt(0)" ::: "memory");

#undef STG_A
#undef STG_B
#undef RDA
#undef RDB

  if (MODE == 0) {
    float* C0 = (float*)C0v;
    const int cb = col0 + wc * 48 + l16;
#pragma unroll
    for (int m = 0; m < 4; m++) {
      const int rb = row0 + wr * 64 + m * 16 + quad * 4;
#pragma unroll
      for (int n = 0; n < 3; n++)
#pragma unroll
        for (int r = 0; r < 4; r++)
          C0[(size_t)(rb + r) * ldc + cb + n * 16] = acc[m][n][r];
    }
  } else {
    const bool is_z = (col0 >= DIN);
    unsigned short* dst = is_z ? (unsigned short*)C1v : (unsigned short*)C0v;
    const int cb = col0 + wc * 48 + l16 - (is_z ? DIN : 0);
#pragma unroll
    for (int m = 0; m < 4; m++) {
      const int rb = row0 + wr * 64 + m * 16 + quad * 4;
#pragma unroll
      for (int n = 0; n < 3; n++)
#pragma unroll
        for (int r = 0; r < 4; r++) {
          float v = acc[m][n][r];
          if (is_z) v = v / (1.f + __expf(-v));
          dst[(size_t)(rb + r) * DIN + cb + n * 16] = f2bf(v);
        }
    }
  }
}

// ------------------- prep1 (1024 thr): sched (block 0) + all flat casts
// SLOT_PACK[slot] = node | ((pnode+1)<<12); SLOTINV[node] = slot.
__global__ __launch_bounds__(1024) void prep1_kernel(
    const int* __restrict__ sidx, const int* __restrict__ spar,
    int* __restrict__ SLOT_PACK, int* __restrict__ SLOTINV,
    int* __restrict__ LSTART, int* __restrict__ NLEV,
    const float* __restrict__ x, unsigned short* __restrict__ Xbf,
    const float* __restrict__ xpw, unsigned short* __restrict__ XPW,
    const float* __restrict__ dtw, unsigned short* __restrict__ DTWb,
    const float* __restrict__ A_log, float* __restrict__ negA) {
  const int bi = blockIdx.x;
  const int tid = threadIdx.x;
  if (bi == 0) {
    __shared__ int par[2048], idx[2048], ancA[2048], ancB[2048], rnkA[2048], rnkB[2048];
    __shared__ int dmax;
    for (int i = tid; i < 2048; i += 1024) {
      const int p = spar[i];
      par[i] = p;
      idx[i] = sidx[i];
      ancA[i] = (p < 0) ? -1 : p;
      rnkA[i] = (p < 0) ? 0 : 1;
    }
    if (tid == 0) dmax = 0;
    __syncthreads();
    for (int r = 0; r < 11; r++) {
      int* ca = (r & 1) ? ancB : ancA;
      int* cr = (r & 1) ? rnkB : rnkA;
      int* na = (r & 1) ? ancA : ancB;
      int* nr = (r & 1) ? rnkA : rnkB;
      for (int i = tid; i < 2048; i += 1024) {
        const int a = ca[i], rv = cr[i];
        if (a >= 0) {
          nr[i] = rv + cr[a];
          na[i] = ca[a];
        } else {
          nr[i] = rv;
          na[i] = a;
        }
      }
      __syncthreads();
    }
    for (int i = tid; i < 2048; i += 1024) ancA[i] = 0;
    __syncthreads();
    for (int i = tid; i < 2048; i += 1024) {
      atomicAdd(&ancA[rnkB[i]], 1);
      atomicMax(&dmax, rnkB[i]);
    }
    __syncthreads();
    for (int s = 0; s < 11; s++) {
      const int off = 1 << s;
      int* cur = (s & 1) ? ancB : ancA;
      int* nxt = (s & 1) ? ancA : ancB;
      for (int i = tid; i < 2048; i += 1024) {
        int v = cur[i];
        if (i >= off) v += cur[i - off];
        nxt[i] = v;
      }
      __syncthreads();
    }
    for (int i = tid; i < 2049; i += 1024) {
      const int v = (i == 0) ? 0 : ancB[i - 1];
      LSTART[i] = v;
      if (i < 2048) rnkA[i] = v;
    }
    if (tid == 0) NLEV[0] = dmax + 1;
    __syncthreads();
    for (int i = tid; i < 2048; i += 1024) {
      const int d = rnkB[i];
      const int slot = atomicAdd(&rnkA[d], 1);
      const int node = idx[i];
      const int p = par[i];
      const int pn = (p < 0) ? -1 : idx[p];
      SLOT_PACK[slot] = node | ((pn + 1) << 12);
      SLOTINV[node] = slot;
    }
  } else if (bi < 1 + 1536) {
    const int i = ((bi - 1) * 1024 + tid) * 4;
    const float4 v = *(const float4*)(x + i);
    union { unsigned short h[4]; uint2 u; } pk;
    pk.h[0] = f2bf(v.x);
    pk.h[1] = f2bf(v.y);
    pk.h[2] = f2bf(v.z);
    pk.h[3] = f2bf(v.w);
    *(uint2*)(Xbf + i) = pk.u;
  } else if (bi < 1 + 1536 + 96) {
    const int i = (bi - 1537) * 1024 + tid;  // 64*1536
    const int c = i / 1536, k = i % 1536;
    XPW[i] = (c < 50) ? f2bf(xpw[(size_t)k * 50 + c]) : (unsigned short)0;
  } else if (bi < 1 + 1536 + 96 + 96) {
    const int i = (bi - 1633) * 1024 + tid;  // 1536*64
    const int d = i >> 6, k = i & 63;
    DTWb[i] = (k < 48) ? f2bf(dtw[(size_t)k * DIN + d]) : (unsigned short)0;
  } else {
    const int i = (bi - 1729) * 1024 + tid;
    if (i < DIN) negA[i] = -__expf(A_log[i]);
  }
}

// ------------------- prep2 (256 thr): both weight transposes, fp32 -> bf16^T
__global__ __launch_bounds__(256) void prep2_kernel(
    const float* __restrict__ W1, unsigned short* __restrict__ W1t,
    const float* __restrict__ W2, unsigned short* __restrict__ W2t) {
  __shared__ float t[32][33];
  int idx = blockIdx.x;
  const float* W;
  unsigned short* Wt;
  int K, N, n0, k0;
  if (idx < 2304) {  // in_proj: K=768, N=3072 -> 96x24 tiles
    W = W1; Wt = W1t; K = DMOD; N = 2 * DIN;
    n0 = (idx % 96) * 32; k0 = (idx / 96) * 32;
  } else {           // out_proj: K=1536, N=768 -> 24x48 tiles
    idx -= 2304;
    W = W2; Wt = W2t; K = DIN; N = DMOD;
    n0 = (idx % 24) * 32; k0 = (idx / 24) * 32;
  }
  const int tx = threadIdx.x & 31, ty = threadIdx.x >> 5;
  for (int i = ty; i < 32; i += 8) t[i][tx] = W[(size_t)(k0 + i) * N + n0 + tx];
  __syncthreads();
  for (int i = ty; i < 32; i += 8)
    Wt[(size_t)(n0 + i) * K + k0 + tx] = f2bf(t[tx][i]);
}

// ------------------------------------------------- x_dbl: split-K bf16 MFMA
__global__ __launch_bounds__(256) void xdbl_mfma(
    const unsigned short* __restrict__ XI, const unsigned short* __restrict__ XPW,
    float* __restrict__ XP) {
  __shared__ unsigned short As[128 * 32];
  __shared__ unsigned short Bs[64 * 32];
  const int tid = threadIdx.x;
  const int w = tid >> 6, l = tid & 63;
  const int quad = l >> 4, l16 = l & 15;
  // XCD swizzle: 256 blocks; XCD k gets y in [8k,8k+8) with all 4 splits.
  const int h = blockIdx.x + 4 * blockIdx.y;
  const int swz = (h & 7) * 32 + (h >> 3);
  const int split = swz & 3;
  const int row0 = (swz >> 2) * 128;
  const int kbase = split * (DIN / NSPLIT);  // 384

  f4 acc[2][4];
#pragma unroll
  for (int i = 0; i < 2; i++)
#pragma unroll
    for (int j = 0; j < 4; j++) acc[i][j] = (f4){0.f, 0.f, 0.f, 0.f};

  const int srow = w * 16 + (l >> 2);
  const int kcol = (((l & 3) ^ ((l >> 2) & 3)) * 8);
  const int qs = (quad ^ (l16 & 3)) * 8;

  for (int c = 0; c < 12; c++) {
    const int k0 = kbase + c * 32;
#pragma unroll
    for (int r = 0; r < 2; r++) {
      gld_lds16(XI + (size_t)(row0 + srow + r * 64) * DIN + k0 + kcol,
                (char*)As + r * 4096 + w * 1024);
    }
    gld_lds16(XPW + (size_t)srow * DIN + k0 + kcol, (char*)Bs + w * 1024);
    __syncthreads();
    bfrag af[2], bf[4];
#pragma unroll
    for (int i = 0; i < 2; i++)
      af[i] = *(const bfrag*)(const void*)(As + (w * 32 + i * 16 + l16) * 32 + qs);
#pragma unroll
    for (int j = 0; j < 4; j++)
      bf[j] = *(const bfrag*)(const void*)(Bs + (j * 16 + l16) * 32 + qs);
#pragma unroll
    for (int i = 0; i < 2; i++)
#pragma unroll
      for (int j = 0; j < 4; j++)
        acc[i][j] = __builtin_amdgcn_mfma_f32_16x16x32_bf16(af[i], bf[j], acc[i][j], 0, 0, 0);
    __syncthreads();
  }

  float* dst = XP + (size_t)split * ROWS * 64 + (size_t)row0 * 64;
#pragma unroll
  for (int i = 0; i < 2; i++) {
    const int rb = w * 32 + i * 16 + quad * 4;
#pragma unroll
    for (int j = 0; j < 4; j++) {
      const int col = j * 16 + l16;
#pragma unroll
      for (int r = 0; r < 4; r++) dst[(size_t)(rb + r) * 64 + col] = acc[i][j][r];
    }
  }
}

// -------------------------- reduce XP partials -> DTLRb bf16 + BC/CC fp32
__global__ __launch_bounds__(256) void xp_reduce(
    const float* __restrict__ XP, unsigned short* __restrict__ DTLRb,
    float* __restrict__ BCv, float* __restrict__ CCv) {
  const int i = blockIdx.x * 256 + threadIdx.x;  // 8192*16
  const int row = i >> 4, c4 = (i & 15) * 4;
  const float* p = XP + (size_t)row * 64 + c4;
  float4 s = make_float4(0.f, 0.f, 0.f, 0.f);
#pragma unroll
  for (int sp = 0; sp < NSPLIT; sp++) {
    const float4 v = *(const float4*)(p + (size_t)sp * ROWS * 64);
    s.x += v.x;
    s.y += v.y;
    s.z += v.z;
    s.w += v.w;
  }
  if (c4 == 48) {
    BCv[row] = s.x;
    CCv[row] = s.y;
  }
  union { unsigned short h[4]; uint2 u; } pk;
  pk.h[0] = f2bf(s.x);
  pk.h[1] = f2bf(s.y);
  pk.h[2] = f2bf(s.z);
  pk.h[3] = f2bf(s.w);
  *(uint2*)(DTLRb + (size_t)row * 64 + c4) = pk.u;
}

// ------- dt GEMM (K=64) -> dA/dBx bf16, rows permuted to slot order.
// grid (12, 128). 64 rows x 128 cols per block. XCD-swizzled.
__global__ __launch_bounds__(256) void dt_gemm(
    const unsigned short* __restrict__ DTLRb, const unsigned short* __restrict__ DTWb,
    const float* __restrict__ bias, const float* __restrict__ negA,
    const float* __restrict__ BCv, const unsigned short* __restrict__ XI,
    const int* __restrict__ SLOTINV,
    unsigned short* __restrict__ DAp, unsigned short* __restrict__ DBXp) {
  __shared__ unsigned short As[2][64 * 32];
  __shared__ unsigned short Bs[2][128 * 32];
  __shared__ int sinv[64];
  __shared__ float bcs[64];
  const int tid = threadIdx.x;
  const int w = tid >> 6, l = tid & 63;
  const int quad = l >> 4, l16 = l & 15;
  const int wrow = (w >> 1) * 32, wcol = (w & 1) * 64;
  // XCD swizzle: 1536 blocks = 8 x 192 (bijective).
  const int h = blockIdx.x + 12 * blockIdx.y;
  const int swz = (h & 7) * 192 + (h >> 3);
  const int row0 = (swz / 12) * 64, col0 = (swz % 12) * 128;
  const int p0 = row0 & (NSEQ - 1);       // position base (batch-local)
  const int bbase = row0 & ~(NSEQ - 1);   // b*2048
  const int srow = w * 16 + (l >> 2);
  const int koff = (((l & 3) ^ ((l >> 2) & 3)) * 8);
  const int qs = (quad ^ (l16 & 3)) * 8;

#pragma unroll
  for (int c = 0; c < 2; c++) {
    gld_lds16(DTLRb + (size_t)(row0 + srow) * 64 + c * 32 + koff,
              (char*)As[c] + w * 1024);
#pragma unroll
    for (int r = 0; r < 2; r++)
      gld_lds16(DTWb + (size_t)(col0 + srow + r * 64) * 64 + c * 32 + koff,
                (char*)Bs[c] + r * 4096 + w * 1024);
  }
  if (tid < 64) {
    sinv[tid] = SLOTINV[p0 + tid];
    bcs[tid] = BCv[row0 + tid];
  }
  __syncthreads();

  f4 acc[2][4];
#pragma unroll
  for (int i = 0; i < 2; i++)
#pragma unroll
    for (int j = 0; j < 4; j++) acc[i][j] = (f4){0.f, 0.f, 0.f, 0.f};

#pragma unroll
  for (int c = 0; c < 2; c++) {
    bfrag af[2], bf[4];
#pragma unroll
    for (int i = 0; i < 2; i++)
      af[i] = *(const bfrag*)(const void*)(As[c] + (wrow + i * 16 + l16) * 32 + qs);
#pragma unroll
    for (int j = 0; j < 4; j++)
      bf[j] = *(const bfrag*)(const void*)(Bs[c] + (wcol + j * 16 + l16) * 32 + qs);
#pragma unroll
    for (int i = 0; i < 2; i++)
#pragma unroll
      for (int j = 0; j < 4; j++)
        acc[i][j] = __builtin_amdgcn_mfma_f32_16x16x32_bf16(af[i], bf[j], acc[i][j], 0, 0, 0);
  }

  float bj[4], aj[4];
#pragma unroll
  for (int j = 0; j < 4; j++) {
    const int d = col0 + wcol + j * 16 + l16;
    bj[j] = bias[d];
    aj[j] = negA[d];
  }
#pragma unroll
  for (int i = 0; i < 2; i++) {
#pragma unroll
    for (int r = 0; r < 4; r++) {
      const int row_l = wrow + i * 16 + quad * 4 + r;
      const int row = row0 + row_l;
      const float bc = bcs[row_l];
      const size_t rp = (size_t)(bbase + sinv[row_l]) * DIN;
#pragma unroll
      for (int j = 0; j < 4; j++) {
        const int d = col0 + wcol + j * 16 + l16;
        const float s = acc[i][j][r] + bj[j];
        const float sp = fmaxf(s, 0.f) + __logf(1.f + __expf(-fabsf(s)));
        const float xi = bf2f(XI[(size_t)row * DIN + d]);
        DAp[rp + d] = f2bf(__expf(sp * aj[j]));
        DBXp[rp + d] = f2bf(sp * bc * xi);
      }
    }
  }
}

// ----------------- tree recurrence: h resident in LDS, slot-ordered loads
// block owns 16 bf16 columns (2 chunks of 8); h[node][16] in LDS (64KB).
// XCD-contiguous remap: col-adjacent blocks share 64B lines on one XCD L2.
__global__ __launch_bounds__(256) void recur_kernel(
    const unsigned short* __restrict__ DAp, const unsigned short* __restrict__ DBXp,
    unsigned short* __restrict__ Hb,
    const int* __restrict__ SLOT_PACK, const int* __restrict__ LSTART,
    const int* __restrict__ NLEV) {
  __shared__ unsigned short hl[NSEQ * 16];  // 64 KB
  __shared__ int spack[NSEQ];               // 8 KB
  __shared__ int lst[258];                  // ~1 KB
  const int tid = threadIdx.x;
  const int bid = blockIdx.x;               // 384 = 8 x 48
  const int logical = (bid & 7) * 48 + (bid >> 3);
  const int c8a = logical * 2;              // both chunks in same batch
  const int b = c8a / 192;
  const int d8a = c8a % 192;
  const int nlev = NLEV[0];
  for (int i = tid; i < NSEQ; i += 256) spack[i] = SLOT_PACK[i];
  const int nl = (nlev + 1 < 258) ? nlev + 1 : 258;
  for (int i = tid; i < nl; i += 256) lst[i] = LSTART[i];
  __syncthreads();

  for (int L = 0; L < nlev; L++) {
    const int s0 = (L < 257) ? lst[L] : LSTART[L];
    const int s1 = (L + 1 < 258) ? lst[L + 1] : LSTART[L + 1];
    const int items = (s1 - s0) * 2;
    for (int it = tid; it < items; it += 256) {
      const int s = s0 + (it >> 1);
      const int ch = it & 1;
      const size_t goff = (size_t)(b * NSEQ + s) * DIN + (d8a + ch) * 8;
      union { uint4 u; unsigned short h[8]; } da, dbx, hpu, hvu;
      da.u = *(const uint4*)(DAp + goff);
      dbx.u = *(const uint4*)(DBXp + goff);
      const int pk = spack[s];
      const int node = pk & 4095;
      const int pn = (pk >> 12) - 1;
      float hp[8];
      if (pn >= 0) {
        hpu.u = *(const uint4*)(hl + pn * 16 + ch * 8);
#pragma unroll
        for (int e = 0; e < 8; e++) hp[e] = bf2f(hpu.h[e]);
      } else {
#pragma unroll
        for (int e = 0; e < 8; e++) hp[e] = 0.f;
      }
#pragma unroll
      for (int e = 0; e < 8; e++) {
        const float hv = fmaf(bf2f(da.h[e]), hp[e], bf2f(dbx.h[e]));
        hvu.h[e] = f2bf(hv);
      }
      *(uint4*)(hl + node * 16 + ch * 8) = hvu.u;
    }
    __syncthreads();
  }

  // flush h to global (node-major for ln)
  for (int i = tid; i < NSEQ * 2; i += 256) {
    const int node = i >> 1, ch = i & 1;
    *(uint4*)(Hb + (size_t)(b * NSEQ + node) * DIN + (d8a + ch) * 8) =
        *(const uint4*)(hl + node * 16 + ch * 8);
  }
}

// --------------- y, layernorm, z-gate -> bf16 (vectorized, 192 thr/row)
__global__ __launch_bounds__(192) void ln_kernel(
    const unsigned short* __restrict__ Hb, const float* __restrict__ CCv,
    const unsigned short* __restrict__ XI, const float* __restrict__ Dp,
    const float* __restrict__ gamma, const float* __restrict__ beta,
    const unsigned short* __restrict__ Z, unsigned short* __restrict__ YLN) {
  const int row = blockIdx.x;
  const int tid = threadIdx.x;   // 0..191
  const int d8 = tid * 8;        // 8 bf16 per thread, 192*8 = 1536
  const float C = CCv[row];
  const size_t base = (size_t)row * DIN + d8;
  union U { uint4 u; unsigned short h[8]; };
  U hu, xu;
  hu.u = *(const uint4*)(Hb + base);
  xu.u = *(const uint4*)(XI + base);
  float dp[8];
  *(float4*)(dp) = *(const float4*)(Dp + d8);
  *(float4*)(dp + 4) = *(const float4*)(Dp + d8 + 4);
  float y[8];
  float s = 0.f, s2 = 0.f;
#pragma unroll
  for (int e = 0; e < 8; e++) {
    const float v = fmaf(bf2f(hu.h[e]), C, dp[e] * bf2f(xu.h[e]));
    y[e] = v;
    s += v;
    s2 = fmaf(v, v, s2);
  }
#pragma unroll
  for (int off = 32; off >= 1; off >>= 1) {
    s += __shfl_down(s, off);
    s2 += __shfl_down(s2, off);
  }
  __shared__ float rs[3], rs2[3];
  const int w = tid >> 6;
  if ((tid & 63) == 0) {
    rs[w] = s;
    rs2[w] = s2;
  }
  __syncthreads();
  const float ts = rs[0] + rs[1] + rs[2];
  const float ts2 = rs2[0] + rs2[1] + rs2[2];
  const float mu = ts * (1.f / 1536.f);
  const float var = ts2 * (1.f / 1536.f) - mu * mu;
  const float inv = rsqrtf(var + 1e-5f);
  float g[8], bb[8];
  *(float4*)(g) = *(const float4*)(gamma + d8);
  *(float4*)(g + 4) = *(const float4*)(gamma + d8 + 4);
  *(float4*)(bb) = *(const float4*)(beta + d8);
  *(float4*)(bb + 4) = *(const float4*)(beta + d8 + 4);
  U zu, out;
  zu.u = *(const uint4*)(Z + base);
#pragma unroll
  for (int e = 0; e < 8; e++) {
    const float o = (y[e] - mu) * inv * g[e] + bb[e];
    out.h[e] = f2bf(o * bf2f(zu.h[e]));
  }
  *(uint4*)(YLN + base) = out.u;
}

// ---------------------------------------------------------------------- launch
extern "C" void kernel_launch(void* const* d_in, const int* in_sizes, int n_in,
                              void* d_out, int out_size, void* d_ws, size_t ws_size,
                              hipStream_t stream) {
  const float* x = (const float*)d_in[0];
  const int* sidx = (const int*)d_in[1];
  const int* spar = (const int*)d_in[2];
  const float* in_proj = (const float*)d_in[3];
  const float* x_proj = (const float*)d_in[4];
  const float* dt_proj = (const float*)d_in[5];
  const float* dt_b = (const float*)d_in[6];
  const float* A_log = (const float*)d_in[7];
  const float* Dp = (const float*)d_in[8];
  const float* gamma = (const float*)d_in[9];
  const float* beta = (const float*)d_in[10];
  const float* out_proj = (const float*)d_in[11];
  float* out = (float*)d_out;

  char* p = (char*)d_ws;
  const size_t RC = (size_t)ROWS * DIN;
  unsigned short* XI = (unsigned short*)p;   p += RC * 2;   // 25.2 MB
  unsigned short* Z = (unsigned short*)p;    p += RC * 2;   // 25.2 MB
  unsigned short* DAp = (unsigned short*)p;  p += RC * 2;   // 25.2 MB
  unsigned short* DBXp = (unsigned short*)p; p += RC * 2;   // 25.2 MB
  unsigned short* Hb = (unsigned short*)p;   p += RC * 2;   // 25.2 MB
  float* XP = (float*)p;                     p += (size_t)NSPLIT * ROWS * 64 * 4;  // 8.4 MB
  unsigned short* DTLRb = (unsigned short*)p; p += (size_t)ROWS * 64 * 2;          // 1 MB
  float* BCv = (float*)p;                    p += ROWS * 4;
  float* CCv = (float*)p;                    p += ROWS * 4;
  float* negA = (float*)p;                   p += DIN * 4;
  unsigned short* Xbf = (unsigned short*)p;  p += (size_t)ROWS * DMOD * 2;         // 12.6 MB
  unsigned short* W1t = (unsigned short*)p;  p += (size_t)2 * DIN * DMOD * 2;      // 4.7 MB
  unsigned short* W2t = (unsigned short*)p;  p += (size_t)DMOD * DIN * 2;          // 2.4 MB
  unsigned short* XPW = (unsigned short*)p;  p += (size_t)64 * DIN * 2;
  unsigned short* DTWb = (unsigned short*)p; p += (size_t)DIN * 64 * 2;
  int* ipart = (int*)p;
  int* SLOT_PACK = ipart;
  int* SLOTINV = ipart + 2048;
  int* LSTART = ipart + 4096;
  int* NLEV = ipart + 4096 + 2049;
  unsigned short* YLN = DAp;  // DAp dead after recur; reuse for LN output

  prep1_kernel<<<1731, 1024, 0, stream>>>(sidx, spar, SLOT_PACK, SLOTINV,
                                          LSTART, NLEV, x, Xbf, x_proj, XPW,
                                          dt_proj, DTWb, A_log, negA);
  prep2_kernel<<<3456, 256, 0, stream>>>(in_proj, W1t, out_proj, W2t);
  gemm_dp<1, 16><<<dim3(16, 64), 512, 0, stream>>>(Xbf, W1t, XI, Z, DMOD, 0);
  xdbl_mfma<<<dim3(NSPLIT, 64), 256, 0, stream>>>(XI, XPW, XP);
  xp_reduce<<<ROWS * 16 / 256, 256, 0, stream>>>(XP, DTLRb, BCv, CCv);
  dt_gemm<<<dim3(12, 128), 256, 0, stream>>>(DTLRb, DTWb, dt_b, negA, BCv, XI,
                                             SLOTINV, DAp, DBXp);
  recur_kernel<<<384, 256, 0, stream>>>(DAp, DBXp, Hb, SLOT_PACK, LSTART, NLEV);
  ln_kernel<<<ROWS, 192, 0, stream>>>(Hb, CCv, XI, Dp, gamma, beta, Z, YLN);
  gemm_dp<0, 4><<<dim3(4, 64), 512, 0, stream>>>(YLN, W2t, out, nullptr, DIN, DMOD);
}